// Round 5
// baseline (1043.623 us; speedup 1.0000x reference)
//
#include <hip/hip_runtime.h>

#define NB 32
#define PP 8192
#define OPP 2048

typedef _Float16 f16;
typedef f16 half8 __attribute__((ext_vector_type(8)));
typedef f16 half4 __attribute__((ext_vector_type(4)));
typedef float f32x4 __attribute__((ext_vector_type(4)));

#define MFMA16(a, b, c) __builtin_amdgcn_mfma_f32_16x16x32_f16(a, b, c, 0, 0, 0)

// ======================= generic tiled transpose (fp32) =======================
__global__ void transpose_k(const float* __restrict__ in, float* __restrict__ out,
                            int R, int C, int es, int eo) {
  __shared__ float tile[32][33];
  int jb = blockIdx.x * 32, ib = blockIdx.y * 32;
  int tx = threadIdx.x, ty = threadIdx.y;
  for (int yy = ty; yy < 32; yy += 8) {
    int i = ib + yy, j = jb + tx;
    if (i < R && j < C) tile[yy][tx] = in[((size_t)i * C + j) * (size_t)es + eo];
  }
  __syncthreads();
  for (int yy = ty; yy < 32; yy += 8) {
    int j = jb + yy, i = ib + tx;
    if (j < C && i < R) out[(size_t)j * R + i] = tile[tx][yy];
  }
}

// ======================= conv weight prep (coalesced): [co][ci][9] -> [k][co][ci] fp16 ====
template <int CO, int CI>
__global__ __launch_bounds__(256) void wprep2_k(const float* __restrict__ wsrc,
                                                f16* __restrict__ wdst) {
  __shared__ float tile[CI * 9];
  int co = blockIdx.x, t = threadIdx.x;
  const float* src = wsrc + (size_t)co * CI * 9;
  for (int i = t; i < CI * 9; i += 256) tile[i] = src[i];
  __syncthreads();
  for (int i = t; i < CI * 9; i += 256) {
    int k = i / CI, ci = i - k * CI;
    wdst[((size_t)k * CO + co) * CI + ci] = (f16)tile[ci * 9 + k];
  }
}

__global__ void cvt16_k(const float* __restrict__ in, f16* __restrict__ out, int n4) {
  int idx = blockIdx.x * 256 + threadIdx.x;
  if (idx >= n4) return;
  float4 v = ((const float4*)in)[idx];
  half4 h; h.x = (f16)v.x; h.y = (f16)v.y; h.z = (f16)v.z; h.w = (f16)v.w;
  ((half4*)out)[idx] = h;
}

// cls_w1 scene part [1024][1538] -> [1024][1024] fp16
__global__ void cw1prep_k(const float* __restrict__ w, f16* __restrict__ out) {
  int idx = blockIdx.x * 256 + threadIdx.x;
  if (idx >= 1024 * 1024) return;
  int co = idx >> 10, k = idx & 1023;
  out[idx] = (f16)w[(size_t)co * 1538 + k];
}

// convt_w [o][i][a'][b'] -> ctwh[(p*512+o)*1024+i] = w[o][i][3-p] fp16
__global__ void ctprep_k(const float* __restrict__ w, f16* __restrict__ out) {
  int idx = blockIdx.x * 256 + threadIdx.x;
  if (idx >= 2048 * 1024) return;
  int np = idx >> 10, i = idx & 1023;
  int p = np >> 9, o = np & 511;
  out[idx] = (f16)w[((size_t)o * 1024 + i) * 4 + (3 - p)];
}

// ======================= object-cloud mean =======================
__global__ void ocmean_k(const float* __restrict__ oc, float* __restrict__ ocm) {
  int n = blockIdx.x, t = threadIdx.x;
  __shared__ float sx[256], sy[256];
  float ax = 0.f, ay = 0.f;
  for (int p = t; p < OPP; p += 256) {
    ax += oc[((size_t)n * OPP + p) * 2 + 0];
    ay += oc[((size_t)n * OPP + p) * 2 + 1];
  }
  sx[t] = ax; sy[t] = ay;
  __syncthreads();
  for (int s = 128; s > 0; s >>= 1) {
    if (t < s) { sx[t] += sx[t + s]; sy[t] += sy[t + s]; }
    __syncthreads();
  }
  if (t == 0) {
    ocm[n * 2 + 0] = sx[0] / (float)OPP;
    ocm[n * 2 + 1] = sy[0] / (float)OPP;
  }
}

// ======================= voxel PointNet: LDS scatter-max, fp16 out =======================
// Grid: 256 = 32 images x 8 channel-groups (32 ch). LDS vox slice [400][33] fp32.
// Output voxh [n][400][256] fp16 written once per block (no global atomics, no memset).
__global__ __launch_bounds__(256) void pointnet_lds_k(
    const float* __restrict__ sc, const float* __restrict__ w1, const float* __restrict__ b1,
    const f16* __restrict__ w2h, const float* __restrict__ b2, f16* __restrict__ voxh) {
  __shared__ float voxl[400 * 33];         // 52,800 B, pad 33 breaks bank collisions
  __shared__ f16 hA[32 * 136];             // [pt][K=128], stride 136 halves
  __shared__ float pcx[32], pcy[32];
  __shared__ int binl[32];
  int t = threadIdx.x, lane = t & 63, w = t >> 6;
  int quad = lane >> 4, l16 = lane & 15;
  int b = blockIdx.x;
  int cg = b & 7, n = b >> 3;
  // h-layer params (fixed channel per thread)
  int hc = t & 127, pg = t >> 7;
  float wx = w1[hc * 2], wy = w1[hc * 2 + 1], hb = b1[hc];
  // MFMA wave params: wave covers (m-tile mt, n-tile nt)
  int mt = w & 1, nt = w >> 1;
  int lc = nt * 16 + l16;                  // local channel 0..31
  float bias = b2[cg * 32 + lc];
  const f16* wB = w2h + (size_t)(cg * 32 + lc) * 128;
  for (int i = t; i < 400 * 33; i += 256) voxl[i] = 0.0f;
  __syncthreads();
  for (int it = 0; it < 256; ++it) {
    int pb = it * 32;
    if (t < 32) {
      float x = sc[((size_t)n * PP + pb + t) * 2 + 0];
      float y = sc[((size_t)n * PP + pb + t) * 2 + 1];
      float bif = fminf(fmaxf(ceilf((x + 0.5f) * 20.0f) - 1.0f, 0.0f), 19.0f);
      float bjf = fminf(fmaxf(ceilf((y + 0.5f) * 20.0f) - 1.0f, 0.0f), 19.0f);
      bool valid = (x > -0.5f) && (x <= 0.5f) && (y > -0.5f) && (y <= 0.5f);
      float ci = -0.5f + (bif + 0.5f) / 20.0f;
      float cj = -0.5f + (bjf + 0.5f) / 20.0f;
      pcx[t] = x - ci; pcy[t] = y - cj;
      binl[t] = valid ? ((int)bif * 20 + (int)bjf) : -1;
    }
    __syncthreads();
#pragma unroll
    for (int j = 0; j < 16; ++j) {         // h layer 2->128 for 32 points
      int p = pg * 16 + j;
      hA[p * 136 + hc] = (f16)fmaxf(wx * pcx[p] + wy * pcy[p] + hb, 0.0f);
    }
    __syncthreads();
    f32x4 acc = {};
#pragma unroll
    for (int ks = 0; ks < 4; ++ks) {
      half8 a = *(const half8*)(hA + (mt * 16 + l16) * 136 + ks * 32 + quad * 8);
      half8 bf = *(const half8*)(wB + ks * 32 + quad * 8);
      acc = MFMA16(a, bf, acc);
    }
#pragma unroll
    for (int r = 0; r < 4; ++r) {
      int p = mt * 16 + quad * 4 + r;
      int bn = binl[p];
      if (bn >= 0) {
        float v = fmaxf(acc[r] + bias, 0.0f);
        atomicMax((int*)voxl + bn * 33 + lc, __float_as_int(v));
      }
    }
    __syncthreads();
  }
  // write out 400 bins x 32 ch as fp16 (half2 packed)
  for (int i = t; i < 400 * 16; i += 256) {
    int bin = i >> 4, cp = i & 15;
    union { f16 h[2]; unsigned u; } pk;
    pk.h[0] = (f16)voxl[bin * 33 + cp * 2];
    pk.h[1] = (f16)voxl[bin * 33 + cp * 2 + 1];
    *(unsigned*)(voxh + ((size_t)n * 400 + bin) * 256 + cg * 32 + cp * 2) = pk.u;
  }
}

// ======================= MFMA implicit-GEMM conv 3x3 pad1 + relu =======================
template <int H, int W, int CI, int CO, int MSPLIT>
__global__ __launch_bounds__(256, 2) void convmfma_k(
    const f16* __restrict__ inh, const f16* __restrict__ wh,
    const float* __restrict__ bias, f16* __restrict__ outh) {
  constexpr int HS = H / MSPLIT;
  constexpr int Mpix = HS * W;
  constexpr int MT = (Mpix + 15) / 16;
  constexpr int PR = HS + 2, PC = W + 2;
  constexpr int NCIC = CI / 32;
  constexpr int COG = CO / 128;
  extern __shared__ char smem[];
  f16* Ap = (f16*)smem;                          // [PR*PC][40]
  f16* Bp = (f16*)(smem + PR * PC * 80);         // [3*128][40]
  int b = blockIdx.x;
  int cog = b % COG;
  int ms = (b / COG) % MSPLIT;
  int n = b / (COG * MSPLIT);
  int co0 = cog * 128;
  int r0 = ms * HS;
  int t = threadIdx.x, lane = t & 63, w = t >> 6;
  int quad = lane >> 4, l16 = lane & 15;

  int abase[MT];
#pragma unroll
  for (int mi = 0; mi < MT; ++mi) {
    int pl = mi * 16 + l16; if (pl > Mpix - 1) pl = Mpix - 1;
    int y = pl / W, x = pl - y * W;
    abase[mi] = (y * PC + x) * 40 + quad * 8;    // halves
  }
  f32x4 acc[MT][2] = {};

  const f16* inbase = inh + (size_t)n * H * W * CI;
  int nl = w * 32;

  for (int cic = 0; cic < NCIC; ++cic) {
    for (int cell = t; cell < PR * PC; cell += 256) {
      int pr = cell / PC, pc = cell - pr * PC;
      int yin = r0 - 1 + pr, xin = pc - 1;
      uint4 d0 = {0,0,0,0}, d1 = {0,0,0,0}, d2 = {0,0,0,0}, d3 = {0,0,0,0};
      if (yin >= 0 && yin < H && xin >= 0 && xin < W) {
        const uint4* src = (const uint4*)(inbase + ((size_t)yin * W + xin) * CI + cic * 32);
        d0 = src[0]; d1 = src[1]; d2 = src[2]; d3 = src[3];
      }
      uint4* dst = (uint4*)(Ap + cell * 40);
      dst[0] = d0; dst[1] = d1; dst[2] = d2; dst[3] = d3;
    }
    for (int ky = 0; ky < 3; ++ky) {
      for (int idx = t; idx < 3 * 128; idx += 256) {
        int kx = idx >> 7, cr = idx & 127;
        int k = ky * 3 + kx;
        const uint4* src = (const uint4*)(wh + ((size_t)k * CO + co0 + cr) * CI + cic * 32);
        uint4* dst = (uint4*)(Bp + idx * 40);
        dst[0] = src[0]; dst[1] = src[1]; dst[2] = src[2]; dst[3] = src[3];
      }
      __syncthreads();
#pragma unroll
      for (int kx = 0; kx < 3; ++kx) {
        int shift = (ky * PC + kx) * 40;
        half8 bf0 = *(const half8*)(Bp + (kx * 128 + nl + l16) * 40 + quad * 8);
        half8 bf1 = *(const half8*)(Bp + (kx * 128 + nl + 16 + l16) * 40 + quad * 8);
#pragma unroll
        for (int mi = 0; mi < MT; ++mi) {
          half8 af = *(const half8*)(Ap + abase[mi] + shift);
          acc[mi][0] = MFMA16(af, bf0, acc[mi][0]);
          acc[mi][1] = MFMA16(af, bf1, acc[mi][1]);
        }
      }
      __syncthreads();
    }
  }
  int co_w = co0 + nl;
  float bv0 = bias[co_w + l16];
  float bv1 = bias[co_w + 16 + l16];
  f16* ob = outh + ((size_t)n * H * W + (size_t)ms * Mpix) * CO;
#pragma unroll
  for (int mi = 0; mi < MT; ++mi) {
#pragma unroll
    for (int r = 0; r < 4; ++r) {
      int p = mi * 16 + quad * 4 + r;
      if (p < Mpix) {
        float v0 = acc[mi][0][r] + bv0; v0 = v0 > 0.f ? v0 : 0.f;
        float v1 = acc[mi][1][r] + bv1; v1 = v1 > 0.f ? v1 : 0.f;
        ob[(size_t)p * CO + co_w + l16] = (f16)v0;
        ob[(size_t)p * CO + co_w + 16 + l16] = (f16)v1;
      }
    }
  }
}

// ======================= maxpool 2x2 =======================
__global__ void pool1_k(const f16* __restrict__ g1, f16* __restrict__ f1h) {
  int idx = blockIdx.x * 256 + threadIdx.x;
  if (idx >= 32 * 100 * 256) return;
  int c2 = idx & 255, rem = idx >> 8;
  int op = rem % 100, n = rem / 100;
  int py = op / 10, px = op - py * 10;
  const f16* base = g1 + (((size_t)n * 400 + (size_t)(2 * py) * 20 + 2 * px) * 512) + c2 * 2;
  float a0 = (float)base[0],   a1 = (float)base[1];
  float b0 = (float)base[512], b1 = (float)base[513];
  const f16* base2 = base + 20 * 512;
  float c0 = (float)base2[0],   c1 = (float)base2[1];
  float d0 = (float)base2[512], d1 = (float)base2[513];
  f16* o = f1h + ((size_t)n * 100 + op) * 512 + c2 * 2;
  o[0] = (f16)fmaxf(fmaxf(a0, b0), fmaxf(c0, d0));
  o[1] = (f16)fmaxf(fmaxf(a1, b1), fmaxf(c1, d1));
}

__global__ void pool2_k(const f16* __restrict__ g2, f16* __restrict__ f2h) {
  int idx = blockIdx.x * 256 + threadIdx.x;
  if (idx >= 32 * 25 * 512) return;
  int c2 = idx & 511, rem = idx >> 9;
  int op = rem % 25, n = rem / 25;
  int py = op / 5, px = op - py * 5;
  const f16* base = g2 + (((size_t)n * 100 + (size_t)(2 * py) * 10 + 2 * px) * 1024) + c2 * 2;
  float a0 = (float)base[0],    a1 = (float)base[1];
  float b0 = (float)base[1024], b1 = (float)base[1025];
  const f16* base2 = base + 10 * 1024;
  float c0 = (float)base2[0],    c1 = (float)base2[1];
  float d0 = (float)base2[1024], d1 = (float)base2[1025];
  f16* o = f2h + ((size_t)n * 25 + op) * 1024 + c2 * 2;
  o[0] = (f16)fmaxf(fmaxf(a0, b0), fmaxf(c0, d0));
  o[1] = (f16)fmaxf(fmaxf(a1, b1), fmaxf(c1, d1));
}

// ======================= pack f1 into scene buffer =======================
__global__ void pack_k(const f16* __restrict__ f1h, f16* __restrict__ scnh) {
  int idx = blockIdx.x * 256 + threadIdx.x;
  if (idx >= 204800) return;                     // 32*100*512/8
  int c8 = idx & 63, row = idx >> 6;
  *(half8*)(scnh + (size_t)row * 1024 + c8 * 8) =
      *(const half8*)(f1h + (size_t)row * 512 + c8 * 8);
}

// ======================= conv transpose 2x2 s2 (1024->512), MFMA =======================
__global__ __launch_bounds__(256, 1) void convt_mfma_k(
    const f16* __restrict__ f2h, const f16* __restrict__ ctwh,
    const float* __restrict__ ctb, f16* __restrict__ scnh) {
  __shared__ f16 act[32 * 72];
  int b = blockIdx.x;                      // 64 = 32 n * 2 halves
  int nh = b & 1, n = b >> 1;
  int t = threadIdx.x, lane = t & 63, w = t >> 6;
  int quad = lane >> 4, l16 = lane & 15;
  f32x4 acc[2][16] = {};
  for (int kc = 0; kc < 16; ++kc) {
    int k0 = kc * 64;
    __syncthreads();
    {
      int row = t >> 3, c8 = t & 7;
      half8 v = {};
      if (row < 25) v = *(const half8*)(f2h + ((size_t)n * 25 + row) * 1024 + k0 + c8 * 8);
      *(half8*)(act + row * 72 + c8 * 8) = v;
    }
    __syncthreads();
#pragma unroll
    for (int ks = 0; ks < 2; ++ks) {
      half8 a0 = *(const half8*)(act + l16 * 72 + ks * 32 + quad * 8);
      half8 a1 = *(const half8*)(act + (16 + l16) * 72 + ks * 32 + quad * 8);
#pragma unroll
      for (int nt = 0; nt < 16; ++nt) {
        half8 bf = *(const half8*)(ctwh +
            (size_t)(nh * 1024 + w * 256 + nt * 16 + l16) * 1024 + k0 + ks * 32 + quad * 8);
        acc[0][nt] = MFMA16(a0, bf, acc[0][nt]);
        acc[1][nt] = MFMA16(a1, bf, acc[1][nt]);
      }
    }
  }
#pragma unroll
  for (int nt = 0; nt < 16; ++nt) {
    int np = nh * 1024 + w * 256 + nt * 16 + l16;
    int p = np >> 9, co = np & 511;
    int a = p >> 1, bc = p & 1;
    float bb = ctb[co];
#pragma unroll
    for (int mt = 0; mt < 2; ++mt)
#pragma unroll
      for (int r = 0; r < 4; ++r) {
        int px = mt * 16 + quad * 4 + r;
        if (px < 25) {
          int ph = px / 5, pw = px - ph * 5;
          int opx = (2 * ph + a) * 10 + 2 * pw + bc;
          scnh[((size_t)n * 100 + opx) * 1024 + 512 + co] = (f16)(acc[mt][nt][r] + bb);
        }
      }
  }
}

// ======================= object SA: fused 4-layer MFMA + max =======================
__global__ __launch_bounds__(256) void sa_mfma_k(
    const float* __restrict__ oc, const float* __restrict__ ocm,
    const float* __restrict__ w1, const float* __restrict__ b1,
    const f16* __restrict__ w2h, const float* __restrict__ b2,
    const f16* __restrict__ w3h, const float* __restrict__ b3,
    const f16* __restrict__ w4h, const float* __restrict__ b4,
    float* __restrict__ obj) {
  __shared__ f16 act1[32 * 72];            // [pt][K=64]
  __shared__ f16 act2[32 * 136];           // [pt][K=128]
  __shared__ f16 act3[32 * 264];           // [pt][K=256]
  __shared__ float pcx[32], pcy[32];
  int b = blockIdx.x;                      // 2048 = 32 n * 64 chunks of 32 pts
  int n = b >> 6, pb = (b & 63) * 32;
  int t = threadIdx.x, lane = t & 63, w = t >> 6;
  int quad = lane >> 4, l16 = lane & 15;
  if (t < 32) {
    pcx[t] = oc[((size_t)n * OPP + pb + t) * 2 + 0] - ocm[n * 2 + 0];
    pcy[t] = oc[((size_t)n * OPP + pb + t) * 2 + 1] - ocm[n * 2 + 1];
  }
  __syncthreads();
  {                                        // layer1: 2 -> 64
    int c = t & 63, pg = t >> 6;
    float wx = w1[c * 2], wy = w1[c * 2 + 1], bb = b1[c];
#pragma unroll
    for (int j = 0; j < 8; ++j) {
      int p = pg * 8 + j;
      act1[p * 72 + c] = (f16)fmaxf(fmaf(wx, pcx[p], fmaf(wy, pcy[p], bb)), 0.0f);
    }
  }
  __syncthreads();
  {                                        // layer2: K=64, N=128
    int n0 = w * 32;
    f32x4 acc[2][2] = {};
#pragma unroll
    for (int ks = 0; ks < 2; ++ks) {
      half8 a0 = *(const half8*)(act1 + l16 * 72 + ks * 32 + quad * 8);
      half8 a1 = *(const half8*)(act1 + (16 + l16) * 72 + ks * 32 + quad * 8);
#pragma unroll
      for (int nt = 0; nt < 2; ++nt) {
        half8 bf = *(const half8*)(w2h + (size_t)(n0 + nt * 16 + l16) * 64 + ks * 32 + quad * 8);
        acc[0][nt] = MFMA16(a0, bf, acc[0][nt]);
        acc[1][nt] = MFMA16(a1, bf, acc[1][nt]);
      }
    }
#pragma unroll
    for (int nt = 0; nt < 2; ++nt) {
      int col = n0 + nt * 16 + l16;
      float bb = b2[col];
#pragma unroll
      for (int mt = 0; mt < 2; ++mt)
#pragma unroll
        for (int r = 0; r < 4; ++r)
          act2[(mt * 16 + quad * 4 + r) * 136 + col] = (f16)fmaxf(acc[mt][nt][r] + bb, 0.0f);
    }
  }
  __syncthreads();
  {                                        // layer3: K=128, N=256
    int n0 = w * 64;
    f32x4 acc[2][4] = {};
#pragma unroll
    for (int ks = 0; ks < 4; ++ks) {
      half8 a0 = *(const half8*)(act2 + l16 * 136 + ks * 32 + quad * 8);
      half8 a1 = *(const half8*)(act2 + (16 + l16) * 136 + ks * 32 + quad * 8);
#pragma unroll
      for (int nt = 0; nt < 4; ++nt) {
        half8 bf = *(const half8*)(w3h + (size_t)(n0 + nt * 16 + l16) * 128 + ks * 32 + quad * 8);
        acc[0][nt] = MFMA16(a0, bf, acc[0][nt]);
        acc[1][nt] = MFMA16(a1, bf, acc[1][nt]);
      }
    }
#pragma unroll
    for (int nt = 0; nt < 4; ++nt) {
      int col = n0 + nt * 16 + l16;
      float bb = b3[col];
#pragma unroll
      for (int mt = 0; mt < 2; ++mt)
#pragma unroll
        for (int r = 0; r < 4; ++r)
          act3[(mt * 16 + quad * 4 + r) * 264 + col] = (f16)fmaxf(acc[mt][nt][r] + bb, 0.0f);
    }
  }
  __syncthreads();
  {                                        // layer4: K=256, N=512; + max over points
    int n0 = w * 128;
    f32x4 acc[2][8] = {};
#pragma unroll
    for (int ks = 0; ks < 8; ++ks) {
      half8 a0 = *(const half8*)(act3 + l16 * 264 + ks * 32 + quad * 8);
      half8 a1 = *(const half8*)(act3 + (16 + l16) * 264 + ks * 32 + quad * 8);
#pragma unroll
      for (int nt = 0; nt < 8; ++nt) {
        half8 bf = *(const half8*)(w4h + (size_t)(n0 + nt * 16 + l16) * 256 + ks * 32 + quad * 8);
        acc[0][nt] = MFMA16(a0, bf, acc[0][nt]);
        acc[1][nt] = MFMA16(a1, bf, acc[1][nt]);
      }
    }
#pragma unroll
    for (int nt = 0; nt < 8; ++nt) {
      int col = n0 + nt * 16 + l16;
      float bb = b4[col];
      float v = 0.0f;
#pragma unroll
      for (int mt = 0; mt < 2; ++mt)
#pragma unroll
        for (int r = 0; r < 4; ++r)
          v = fmaxf(v, acc[mt][nt][r] + bb);
      v = fmaxf(v, 0.0f);
      v = fmaxf(v, __shfl_xor(v, 16));
      v = fmaxf(v, __shfl_xor(v, 32));
      if (quad == 0)
        atomicMax((int*)obj + (size_t)n * 512 + col, __float_as_int(v));
    }
  }
}

// ======================= classifier layer 1 (1538 -> 1024), MFMA =======================
__global__ __launch_bounds__(256) void cls1_mfma_k(
    const f16* __restrict__ scnh, const float* __restrict__ obj,
    const float* __restrict__ pos, const float* __restrict__ w1raw,
    const f16* __restrict__ w1h, const float* __restrict__ b1,
    f16* __restrict__ h1h) {
  __shared__ f16 act[112 * 72];
  __shared__ float objl[512];
  __shared__ float odl[128], wAl[128], wBl[128];
  int b = blockIdx.x;                      // 256 = 32 n * 8 octants
  int o8 = b & 7, n = b >> 3;
  int co0 = o8 * 128;
  int t = threadIdx.x, lane = t & 63, w = t >> 6;
  int quad = lane >> 4, l16 = lane & 15;
  objl[t] = obj[(size_t)n * 512 + t];
  objl[t + 256] = obj[(size_t)n * 512 + t + 256];
  __syncthreads();
  if (t < 128) {
    int co = co0 + t;
    const float* wr = w1raw + (size_t)co * 1538;
    float od = 0.0f;
    for (int k = 0; k < 512; ++k) od = fmaf(objl[k], wr[1024 + k], od);
    odl[t] = od + b1[co];
    wAl[t] = wr[1536]; wBl[t] = wr[1537];
  }
  __syncthreads();
  float posx = pos[n * 2 + 0], posy = pos[n * 2 + 1];
  f32x4 acc[7][2];
#pragma unroll
  for (int mt = 0; mt < 7; ++mt)
#pragma unroll
    for (int nt = 0; nt < 2; ++nt) {
      int cl = w * 32 + nt * 16 + l16;
      float od = odl[cl], wA = wAl[cl], wB = wBl[cl];
#pragma unroll
      for (int r = 0; r < 4; ++r) {
        int px = mt * 16 + quad * 4 + r;
        float relx = posx - (-0.5f + ((px / 10) + 0.5f) * 0.1f);
        float rely = posy - (-0.5f + ((px % 10) + 0.5f) * 0.1f);
        acc[mt][nt][r] = od + relx * wA + rely * wB;
      }
    }
  for (int kc = 0; kc < 16; ++kc) {
    int k0 = kc * 64;
    __syncthreads();
    for (int i = t; i < 896; i += 256) {
      int row = i >> 3, c8 = i & 7;
      half8 v = {};
      if (row < 100) v = *(const half8*)(scnh + ((size_t)n * 100 + row) * 1024 + k0 + c8 * 8);
      *(half8*)(act + row * 72 + c8 * 8) = v;
    }
    __syncthreads();
#pragma unroll
    for (int ks = 0; ks < 2; ++ks) {
      half8 bf0 = *(const half8*)(w1h + (size_t)(co0 + w * 32 + l16) * 1024 + k0 + ks * 32 + quad * 8);
      half8 bf1 = *(const half8*)(w1h + (size_t)(co0 + w * 32 + 16 + l16) * 1024 + k0 + ks * 32 + quad * 8);
#pragma unroll
      for (int mt = 0; mt < 7; ++mt) {
        half8 a = *(const half8*)(act + (mt * 16 + l16) * 72 + ks * 32 + quad * 8);
        acc[mt][0] = MFMA16(a, bf0, acc[mt][0]);
        acc[mt][1] = MFMA16(a, bf1, acc[mt][1]);
      }
    }
  }
#pragma unroll
  for (int mt = 0; mt < 7; ++mt)
#pragma unroll
    for (int nt = 0; nt < 2; ++nt) {
      int co = co0 + w * 32 + nt * 16 + l16;
#pragma unroll
      for (int r = 0; r < 4; ++r) {
        int px = mt * 16 + quad * 4 + r;
        if (px < 100)
          h1h[((size_t)n * 100 + px) * 1024 + co] = (f16)fmaxf(acc[mt][nt][r], 0.0f);
      }
    }
}

// ======================= classifier layer 2 (1024 -> 256) =======================
__global__ __launch_bounds__(256) void cls2_k(
    const f16* __restrict__ h1h, const float* __restrict__ w2T,
    const float* __restrict__ b2, float* __restrict__ h2) {
  __shared__ float scT[256 * 28];
  int b = blockIdx.x;
  int q = b & 3, n = b >> 2;
  int t = threadIdx.x, lane = t & 63, w = t >> 6;
  int co = w * 64 + lane;
  int p0 = q * 25;
  float acc[25];
  float bb = b2[co];
#pragma unroll
  for (int j = 0; j < 25; ++j) acc[j] = bb;
  for (int kc = 0; kc < 1024; kc += 256) {
    __syncthreads();
    for (int j = 0; j < 25; ++j)
      scT[t * 28 + j] = (float)h1h[((size_t)n * 100 + p0 + j) * 1024 + kc + t];
    __syncthreads();
    for (int k = 0; k < 256; ++k) {
      float wv = w2T[(size_t)(kc + k) * 256 + co];
      float v[28];
      const float* g = &scT[k * 28];
#pragma unroll
      for (int qq = 0; qq < 7; ++qq) *(float4*)&v[qq * 4] = *(const float4*)&g[qq * 4];
#pragma unroll
      for (int j = 0; j < 25; ++j) acc[j] = fmaf(wv, v[j], acc[j]);
    }
  }
#pragma unroll
  for (int j = 0; j < 25; ++j)
    h2[((size_t)n * 100 + p0 + j) * 256 + co] = fmaxf(acc[j], 0.0f);
}

// ======================= classifier layer 3 (256 -> 1) =======================
__global__ void cls3_k(const float* __restrict__ h2, const float* __restrict__ w3,
                       const float* __restrict__ b3, float* __restrict__ out) {
  int n = blockIdx.x, t = threadIdx.x;
  if (t < 100) {
    float acc = b3[0];
    const float* hp = &h2[((size_t)n * 100 + t) * 256];
    for (int k = 0; k < 256; ++k) acc = fmaf(hp[k], w3[k], acc);
    out[n * 100 + t] = acc;
  }
}

// ======================= launch =======================
extern "C" void kernel_launch(void* const* d_in, const int* in_sizes, int n_in,
                              void* d_out, int out_size, void* d_ws, size_t ws_size,
                              hipStream_t stream) {
  const float* sc      = (const float*)d_in[0];
  const float* oc      = (const float*)d_in[1];
  const float* pos     = (const float*)d_in[2];
  const float* mlp_w1  = (const float*)d_in[3];
  const float* mlp_b1  = (const float*)d_in[4];
  const float* mlp_w2  = (const float*)d_in[5];
  const float* mlp_b2  = (const float*)d_in[6];
  const float* conv1_w = (const float*)d_in[7];
  const float* conv1_b = (const float*)d_in[8];
  const float* conv2_w = (const float*)d_in[9];
  const float* conv2_b = (const float*)d_in[10];
  const float* convt_w = (const float*)d_in[11];
  const float* convt_b = (const float*)d_in[12];
  const float* sa_w1   = (const float*)d_in[13];
  const float* sa_b1   = (const float*)d_in[14];
  const float* sa_w2   = (const float*)d_in[15];
  const float* sa_b2   = (const float*)d_in[16];
  const float* sa_w3   = (const float*)d_in[17];
  const float* sa_b3   = (const float*)d_in[18];
  const float* sa_w4   = (const float*)d_in[19];
  const float* sa_b4   = (const float*)d_in[20];
  const float* cls_w1  = (const float*)d_in[21];
  const float* cls_b1  = (const float*)d_in[22];
  const float* cls_w2  = (const float*)d_in[23];
  const float* cls_b2  = (const float*)d_in[24];
  const float* cls_w3  = (const float*)d_in[25];
  const float* cls_b3  = (const float*)d_in[26];

  float* ws = (float*)d_ws;
  // ---- workspace layout (float units) ----
  f16*   w1h   = (f16*)ws;                         // 589,824 f
  f16*   w2h   = (f16*)(ws + 589824);              // 2,359,296 f (reused: h1h)
  f16*   mw2h  = (f16*)(ws + 2949120);             // 16,384 f
  f16*   saw2h = (f16*)(ws + 2965504);             // 4,096 f
  f16*   saw3h = (f16*)(ws + 2969600);             // 16,384 f
  f16*   saw4h = (f16*)(ws + 2985984);             // 65,536 f
  f16*   cw1h  = (f16*)(ws + 3051520);             // 524,288 f
  f16*   ctwh  = (f16*)(ws + 3575808);             // 1,048,576 f
  float* cw2T  = ws + 4624384;                     // 262,144 f
  float* big   = ws + 4886528;                     // 3,276,800 f (g1buf, g2buf)
  f16*   voxh  = (f16*)(ws + 8163328);             // 819,200 f (reused: f2h)
  f16*   f1h   = (f16*)(ws + 8982528);             // 819,200 f
  f16*   scnh  = (f16*)(ws + 9801728);             // 1,638,400 f (reused: h2)
  float* obj   = ws + 11440128;                    // 16,384 f
  float* ocm   = ws + 11456512;                    // 64 f

  f16*   g1buf = (f16*)big;                        // conv1 out
  f16*   g2buf = (f16*)big;                        // conv2 out (g1buf dead after pool1)
  f16*   f2h   = voxh;                             // pool2 out (voxh dead after conv1)
  f16*   h1h   = w2h;                              // cls1 out (w2h dead after conv2)
  float* h2    = (float*)scnh;                     // cls2 out (scnh dead after cls1)
  float* outp  = (float*)d_out;

  // ---- weight preps ----
  wprep2_k<512, 256><<<512, 256, 0, stream>>>(conv1_w, w1h);
  wprep2_k<1024, 512><<<1024, 256, 0, stream>>>(conv2_w, w2h);
  cvt16_k<<<32, 256, 0, stream>>>(mlp_w2, mw2h, 8192);
  cvt16_k<<<8, 256, 0, stream>>>(sa_w2, saw2h, 2048);
  cvt16_k<<<32, 256, 0, stream>>>(sa_w3, saw3h, 8192);
  cvt16_k<<<128, 256, 0, stream>>>(sa_w4, saw4h, 32768);
  cw1prep_k<<<4096, 256, 0, stream>>>(cls_w1, cw1h);
  ctprep_k<<<8192, 256, 0, stream>>>(convt_w, ctwh);
  dim3 tb(32, 8);
  transpose_k<<<dim3(32, 8), tb, 0, stream>>>(cls_w2, cw2T, 256, 1024, 1, 0);

  hipMemsetAsync(obj, 0, (size_t)16384 * 4, stream);
  ocmean_k<<<32, 256, 0, stream>>>(oc, ocm);

  pointnet_lds_k<<<256, 256, 0, stream>>>(sc, mlp_w1, mlp_b1, mw2h, mlp_b2, voxh);

  convmfma_k<20, 20, 256, 512, 4><<<512, 256, (7 * 22 + 384) * 80, stream>>>(
      voxh, w1h, conv1_b, g1buf);
  pool1_k<<<3200, 256, 0, stream>>>(g1buf, f1h);
  pack_k<<<800, 256, 0, stream>>>(f1h, scnh);
  convmfma_k<10, 10, 512, 1024, 2><<<512, 256, (7 * 12 + 384) * 80, stream>>>(
      f1h, w2h, conv2_b, g2buf);
  pool2_k<<<1600, 256, 0, stream>>>(g2buf, f2h);
  convt_mfma_k<<<64, 256, 0, stream>>>(f2h, ctwh, convt_b, scnh);

  sa_mfma_k<<<2048, 256, 0, stream>>>(oc, ocm, sa_w1, sa_b1, saw2h, sa_b2,
                                      saw3h, sa_b3, saw4h, sa_b4, obj);

  cls1_mfma_k<<<256, 256, 0, stream>>>(scnh, obj, pos, cls_w1, cw1h, cls_b1, h1h);
  cls2_k<<<128, 256, 0, stream>>>(h1h, cw2T, cls_b2, h2);
  cls3_k<<<32, 128, 0, stream>>>(h2, cls_w3, cls_b3, outp);
}

// Round 6
// 811.814 us; speedup vs baseline: 1.2855x; 1.2855x over previous
//
#include <hip/hip_runtime.h>

#define NB 32
#define PP 8192
#define OPP 2048

typedef _Float16 f16;
typedef f16 half8 __attribute__((ext_vector_type(8)));
typedef f16 half4 __attribute__((ext_vector_type(4)));
typedef float f32x4 __attribute__((ext_vector_type(4)));

#define MFMA16(a, b, c) __builtin_amdgcn_mfma_f32_16x16x32_f16(a, b, c, 0, 0, 0)

// ======================= generic tiled transpose (fp32) =======================
__global__ void transpose_k(const float* __restrict__ in, float* __restrict__ out,
                            int R, int C, int es, int eo) {
  __shared__ float tile[32][33];
  int jb = blockIdx.x * 32, ib = blockIdx.y * 32;
  int tx = threadIdx.x, ty = threadIdx.y;
  for (int yy = ty; yy < 32; yy += 8) {
    int i = ib + yy, j = jb + tx;
    if (i < R && j < C) tile[yy][tx] = in[((size_t)i * C + j) * (size_t)es + eo];
  }
  __syncthreads();
  for (int yy = ty; yy < 32; yy += 8) {
    int j = jb + yy, i = ib + tx;
    if (j < C && i < R) out[(size_t)j * R + i] = tile[tx][yy];
  }
}

// ======================= conv weight prep (coalesced): [co][ci][9] -> [k][co][ci] fp16 ====
template <int CO, int CI>
__global__ __launch_bounds__(256) void wprep2_k(const float* __restrict__ wsrc,
                                                f16* __restrict__ wdst) {
  __shared__ float tile[CI * 9];
  int co = blockIdx.x, t = threadIdx.x;
  const float* src = wsrc + (size_t)co * CI * 9;
  for (int i = t; i < CI * 9; i += 256) tile[i] = src[i];
  __syncthreads();
  for (int i = t; i < CI * 9; i += 256) {
    int k = i / CI, ci = i - k * CI;
    wdst[((size_t)k * CO + co) * CI + ci] = (f16)tile[ci * 9 + k];
  }
}

__global__ void cvt16_k(const float* __restrict__ in, f16* __restrict__ out, int n4) {
  int idx = blockIdx.x * 256 + threadIdx.x;
  if (idx >= n4) return;
  float4 v = ((const float4*)in)[idx];
  half4 h; h.x = (f16)v.x; h.y = (f16)v.y; h.z = (f16)v.z; h.w = (f16)v.w;
  ((half4*)out)[idx] = h;
}

// cls_w1 scene part [1024][1538] -> [1024][1024] fp16
__global__ void cw1prep_k(const float* __restrict__ w, f16* __restrict__ out) {
  int idx = blockIdx.x * 256 + threadIdx.x;
  if (idx >= 1024 * 1024) return;
  int co = idx >> 10, k = idx & 1023;
  out[idx] = (f16)w[(size_t)co * 1538 + k];
}

// convt_w [o][i][a'][b'] -> ctwh[(p*512+o)*1024+i] = w[o][i][3-p] fp16
__global__ void ctprep_k(const float* __restrict__ w, f16* __restrict__ out) {
  int idx = blockIdx.x * 256 + threadIdx.x;
  if (idx >= 2048 * 1024) return;
  int np = idx >> 10, i = idx & 1023;
  int p = np >> 9, o = np & 511;
  out[idx] = (f16)w[((size_t)o * 1024 + i) * 4 + (3 - p)];
}

// ======================= object-cloud mean =======================
__global__ void ocmean_k(const float* __restrict__ oc, float* __restrict__ ocm) {
  int n = blockIdx.x, t = threadIdx.x;
  __shared__ float sx[256], sy[256];
  float ax = 0.f, ay = 0.f;
  for (int p = t; p < OPP; p += 256) {
    ax += oc[((size_t)n * OPP + p) * 2 + 0];
    ay += oc[((size_t)n * OPP + p) * 2 + 1];
  }
  sx[t] = ax; sy[t] = ay;
  __syncthreads();
  for (int s = 128; s > 0; s >>= 1) {
    if (t < s) { sx[t] += sx[t + s]; sy[t] += sy[t + s]; }
    __syncthreads();
  }
  if (t == 0) {
    ocm[n * 2 + 0] = sx[0] / (float)OPP;
    ocm[n * 2 + 1] = sy[0] / (float)OPP;
  }
}

// ======================= voxel PointNet: barrier-free LDS scatter-max =======================
// Grid: 256 = 32 images x 8 channel-groups (32 ch). LDS vox slice [400][33] fp32.
// A-fragment (h-layer) computed in registers per thread; B (W2 slice) register-resident.
// No block barriers inside the 128-iteration point loop.
__global__ __launch_bounds__(256) void pointnet_lds_k(
    const float* __restrict__ sc, const float* __restrict__ w1, const float* __restrict__ b1,
    const f16* __restrict__ w2h, const float* __restrict__ b2, f16* __restrict__ voxh) {
  __shared__ float voxl[400 * 33];         // 52,800 B
  __shared__ int binl[64];                 // wave-local bin broadcast
  int t = threadIdx.x, lane = t & 63, w = t >> 6;
  int quad = lane >> 4, l16 = lane & 15;
  int b = blockIdx.x;
  int cg = b & 7, n = b >> 3;
  // per-thread W1 rows: k = ks*32 + quad*8 + j
  float w1x[32], w1y[32], b1v[32];
#pragma unroll
  for (int ks = 0; ks < 4; ++ks)
#pragma unroll
    for (int j = 0; j < 8; ++j) {
      int k = ks * 32 + quad * 8 + j;
      w1x[ks * 8 + j] = w1[k * 2];
      w1y[ks * 8 + j] = w1[k * 2 + 1];
      b1v[ks * 8 + j] = b1[k];
    }
  // register-resident B fragments (32 output channels for this block)
  half8 bf[2][4];
  float bias[2];
#pragma unroll
  for (int nt = 0; nt < 2; ++nt) {
    int ch = cg * 32 + nt * 16 + l16;
    bias[nt] = b2[ch];
#pragma unroll
    for (int ks = 0; ks < 4; ++ks)
      bf[nt][ks] = *(const half8*)(w2h + (size_t)ch * 128 + ks * 32 + quad * 8);
  }
  for (int i = t; i < 400 * 33; i += 256) voxl[i] = 0.0f;
  __syncthreads();
  const float* scp = sc + (size_t)n * PP * 2;
  int p0 = w * 16 + l16;                   // this thread's point slot (dup x4 over quads)
  float2 xy = *(const float2*)(scp + p0 * 2);
  for (int it = 0; it < 128; ++it) {
    float x = xy.x, y = xy.y;
    if (it < 127) xy = *(const float2*)(scp + ((it + 1) * 64 + p0) * 2);  // prefetch
    float bif = fminf(fmaxf(ceilf((x + 0.5f) * 20.0f) - 1.0f, 0.0f), 19.0f);
    float bjf = fminf(fmaxf(ceilf((y + 0.5f) * 20.0f) - 1.0f, 0.0f), 19.0f);
    bool valid = (x > -0.5f) && (x <= 0.5f) && (y > -0.5f) && (y <= 0.5f);
    float px = x - (-0.5f + (bif + 0.5f) * 0.05f);
    float py = y - (-0.5f + (bjf + 0.5f) * 0.05f);
    int bn = valid ? ((int)bif * 20 + (int)bjf) : -1;
    if (quad == 0) binl[w * 16 + l16] = bn;
    f32x4 acc0 = {}, acc1 = {};
#pragma unroll
    for (int ks = 0; ks < 4; ++ks) {
      half8 af;
#pragma unroll
      for (int j = 0; j < 8; ++j)
        af[j] = (f16)fmaxf(fmaf(w1x[ks * 8 + j], px, fmaf(w1y[ks * 8 + j], py, b1v[ks * 8 + j])), 0.0f);
      acc0 = MFMA16(af, bf[0][ks], acc0);
      acc1 = MFMA16(af, bf[1][ks], acc1);
    }
#pragma unroll
    for (int r = 0; r < 4; ++r) {
      int bn2 = binl[w * 16 + quad * 4 + r];   // wave-internal read (no barrier needed)
      if (bn2 >= 0) {
        float v0 = fmaxf(acc0[r] + bias[0], 0.0f);
        float v1 = fmaxf(acc1[r] + bias[1], 0.0f);
        atomicMax((int*)voxl + bn2 * 33 + l16, __float_as_int(v0));
        atomicMax((int*)voxl + bn2 * 33 + 16 + l16, __float_as_int(v1));
      }
    }
  }
  __syncthreads();
  // write out 400 bins x 32 ch as fp16 (half2 packed)
  for (int i = t; i < 400 * 16; i += 256) {
    int bin = i >> 4, cp = i & 15;
    union { f16 h[2]; unsigned u; } pk;
    pk.h[0] = (f16)voxl[bin * 33 + cp * 2];
    pk.h[1] = (f16)voxl[bin * 33 + cp * 2 + 1];
    *(unsigned*)(voxh + ((size_t)n * 400 + bin) * 256 + cg * 32 + cp * 2) = pk.u;
  }
}

// ======================= MFMA implicit-GEMM conv 3x3 pad1 + relu =======================
template <int H, int W, int CI, int CO, int MSPLIT>
__global__ __launch_bounds__(256, 2) void convmfma_k(
    const f16* __restrict__ inh, const f16* __restrict__ wh,
    const float* __restrict__ bias, f16* __restrict__ outh) {
  constexpr int HS = H / MSPLIT;
  constexpr int Mpix = HS * W;
  constexpr int MT = (Mpix + 15) / 16;
  constexpr int PR = HS + 2, PC = W + 2;
  constexpr int NCIC = CI / 32;
  constexpr int COG = CO / 128;
  extern __shared__ char smem[];
  f16* Ap = (f16*)smem;                          // [PR*PC][40]
  f16* Bp = (f16*)(smem + PR * PC * 80);         // [3*128][40]
  int b = blockIdx.x;
  int cog = b % COG;
  int ms = (b / COG) % MSPLIT;
  int n = b / (COG * MSPLIT);
  int co0 = cog * 128;
  int r0 = ms * HS;
  int t = threadIdx.x, lane = t & 63, w = t >> 6;
  int quad = lane >> 4, l16 = lane & 15;

  int abase[MT];
#pragma unroll
  for (int mi = 0; mi < MT; ++mi) {
    int pl = mi * 16 + l16; if (pl > Mpix - 1) pl = Mpix - 1;
    int y = pl / W, x = pl - y * W;
    abase[mi] = (y * PC + x) * 40 + quad * 8;    // halves
  }
  f32x4 acc[MT][2] = {};

  const f16* inbase = inh + (size_t)n * H * W * CI;
  int nl = w * 32;

  for (int cic = 0; cic < NCIC; ++cic) {
    for (int cell = t; cell < PR * PC; cell += 256) {
      int pr = cell / PC, pc = cell - pr * PC;
      int yin = r0 - 1 + pr, xin = pc - 1;
      uint4 d0 = {0,0,0,0}, d1 = {0,0,0,0}, d2 = {0,0,0,0}, d3 = {0,0,0,0};
      if (yin >= 0 && yin < H && xin >= 0 && xin < W) {
        const uint4* src = (const uint4*)(inbase + ((size_t)yin * W + xin) * CI + cic * 32);
        d0 = src[0]; d1 = src[1]; d2 = src[2]; d3 = src[3];
      }
      uint4* dst = (uint4*)(Ap + cell * 40);
      dst[0] = d0; dst[1] = d1; dst[2] = d2; dst[3] = d3;
    }
    for (int ky = 0; ky < 3; ++ky) {
      for (int idx = t; idx < 3 * 128; idx += 256) {
        int kx = idx >> 7, cr = idx & 127;
        int k = ky * 3 + kx;
        const uint4* src = (const uint4*)(wh + ((size_t)k * CO + co0 + cr) * CI + cic * 32);
        uint4* dst = (uint4*)(Bp + idx * 40);
        dst[0] = src[0]; dst[1] = src[1]; dst[2] = src[2]; dst[3] = src[3];
      }
      __syncthreads();
#pragma unroll
      for (int kx = 0; kx < 3; ++kx) {
        int shift = (ky * PC + kx) * 40;
        half8 bf0 = *(const half8*)(Bp + (kx * 128 + nl + l16) * 40 + quad * 8);
        half8 bf1 = *(const half8*)(Bp + (kx * 128 + nl + 16 + l16) * 40 + quad * 8);
#pragma unroll
        for (int mi = 0; mi < MT; ++mi) {
          half8 af = *(const half8*)(Ap + abase[mi] + shift);
          acc[mi][0] = MFMA16(af, bf0, acc[mi][0]);
          acc[mi][1] = MFMA16(af, bf1, acc[mi][1]);
        }
      }
      __syncthreads();
    }
  }
  int co_w = co0 + nl;
  float bv0 = bias[co_w + l16];
  float bv1 = bias[co_w + 16 + l16];
  f16* ob = outh + ((size_t)n * H * W + (size_t)ms * Mpix) * CO;
#pragma unroll
  for (int mi = 0; mi < MT; ++mi) {
#pragma unroll
    for (int r = 0; r < 4; ++r) {
      int p = mi * 16 + quad * 4 + r;
      if (p < Mpix) {
        float v0 = acc[mi][0][r] + bv0; v0 = v0 > 0.f ? v0 : 0.f;
        float v1 = acc[mi][1][r] + bv1; v1 = v1 > 0.f ? v1 : 0.f;
        ob[(size_t)p * CO + co_w + l16] = (f16)v0;
        ob[(size_t)p * CO + co_w + 16 + l16] = (f16)v1;
      }
    }
  }
}

// ======================= maxpool 2x2 (+ fused pack into scene buffer) =======================
__global__ void pool1_k(const f16* __restrict__ g1, f16* __restrict__ f1h,
                        f16* __restrict__ scnh) {
  int idx = blockIdx.x * 256 + threadIdx.x;
  if (idx >= 32 * 100 * 256) return;
  int c2 = idx & 255, rem = idx >> 8;
  int op = rem % 100, n = rem / 100;
  int py = op / 10, px = op - py * 10;
  const f16* base = g1 + (((size_t)n * 400 + (size_t)(2 * py) * 20 + 2 * px) * 512) + c2 * 2;
  float a0 = (float)base[0],   a1 = (float)base[1];
  float b0 = (float)base[512], b1 = (float)base[513];
  const f16* base2 = base + 20 * 512;
  float c0 = (float)base2[0],   c1 = (float)base2[1];
  float d0 = (float)base2[512], d1 = (float)base2[513];
  union { f16 h[2]; unsigned u; } pk;
  pk.h[0] = (f16)fmaxf(fmaxf(a0, b0), fmaxf(c0, d0));
  pk.h[1] = (f16)fmaxf(fmaxf(a1, b1), fmaxf(c1, d1));
  *(unsigned*)(f1h + ((size_t)n * 100 + op) * 512 + c2 * 2) = pk.u;
  *(unsigned*)(scnh + ((size_t)n * 100 + op) * 1024 + c2 * 2) = pk.u;
}

__global__ void pool2_k(const f16* __restrict__ g2, f16* __restrict__ f2h) {
  int idx = blockIdx.x * 256 + threadIdx.x;
  if (idx >= 32 * 25 * 512) return;
  int c2 = idx & 511, rem = idx >> 9;
  int op = rem % 25, n = rem / 25;
  int py = op / 5, px = op - py * 5;
  const f16* base = g2 + (((size_t)n * 100 + (size_t)(2 * py) * 10 + 2 * px) * 1024) + c2 * 2;
  float a0 = (float)base[0],    a1 = (float)base[1];
  float b0 = (float)base[1024], b1 = (float)base[1025];
  const f16* base2 = base + 10 * 1024;
  float c0 = (float)base2[0],    c1 = (float)base2[1];
  float d0 = (float)base2[1024], d1 = (float)base2[1025];
  f16* o = f2h + ((size_t)n * 25 + op) * 1024 + c2 * 2;
  o[0] = (f16)fmaxf(fmaxf(a0, b0), fmaxf(c0, d0));
  o[1] = (f16)fmaxf(fmaxf(a1, b1), fmaxf(c1, d1));
}

// ======================= conv transpose 2x2 s2 (1024->512), MFMA =======================
__global__ __launch_bounds__(256, 1) void convt_mfma_k(
    const f16* __restrict__ f2h, const f16* __restrict__ ctwh,
    const float* __restrict__ ctb, f16* __restrict__ scnh) {
  __shared__ f16 act[32 * 72];
  int b = blockIdx.x;                      // 64 = 32 n * 2 halves
  int nh = b & 1, n = b >> 1;
  int t = threadIdx.x, lane = t & 63, w = t >> 6;
  int quad = lane >> 4, l16 = lane & 15;
  f32x4 acc[2][16] = {};
  for (int kc = 0; kc < 16; ++kc) {
    int k0 = kc * 64;
    __syncthreads();
    {
      int row = t >> 3, c8 = t & 7;
      half8 v = {};
      if (row < 25) v = *(const half8*)(f2h + ((size_t)n * 25 + row) * 1024 + k0 + c8 * 8);
      *(half8*)(act + row * 72 + c8 * 8) = v;
    }
    __syncthreads();
#pragma unroll
    for (int ks = 0; ks < 2; ++ks) {
      half8 a0 = *(const half8*)(act + l16 * 72 + ks * 32 + quad * 8);
      half8 a1 = *(const half8*)(act + (16 + l16) * 72 + ks * 32 + quad * 8);
#pragma unroll
      for (int nt = 0; nt < 16; ++nt) {
        half8 bf = *(const half8*)(ctwh +
            (size_t)(nh * 1024 + w * 256 + nt * 16 + l16) * 1024 + k0 + ks * 32 + quad * 8);
        acc[0][nt] = MFMA16(a0, bf, acc[0][nt]);
        acc[1][nt] = MFMA16(a1, bf, acc[1][nt]);
      }
    }
  }
#pragma unroll
  for (int nt = 0; nt < 16; ++nt) {
    int np = nh * 1024 + w * 256 + nt * 16 + l16;
    int p = np >> 9, co = np & 511;
    int a = p >> 1, bc = p & 1;
    float bb = ctb[co];
#pragma unroll
    for (int mt = 0; mt < 2; ++mt)
#pragma unroll
      for (int r = 0; r < 4; ++r) {
        int px = mt * 16 + quad * 4 + r;
        if (px < 25) {
          int ph = px / 5, pw = px - ph * 5;
          int opx = (2 * ph + a) * 10 + 2 * pw + bc;
          scnh[((size_t)n * 100 + opx) * 1024 + 512 + co] = (f16)(acc[mt][nt][r] + bb);
        }
      }
  }
}

// ======================= object SA: fused 4-layer MFMA + max =======================
__global__ __launch_bounds__(256) void sa_mfma_k(
    const float* __restrict__ oc, const float* __restrict__ ocm,
    const float* __restrict__ w1, const float* __restrict__ b1,
    const f16* __restrict__ w2h, const float* __restrict__ b2,
    const f16* __restrict__ w3h, const float* __restrict__ b3,
    const f16* __restrict__ w4h, const float* __restrict__ b4,
    float* __restrict__ obj) {
  __shared__ f16 act1[32 * 72];            // [pt][K=64]
  __shared__ f16 act2[32 * 136];           // [pt][K=128]
  __shared__ f16 act3[32 * 264];           // [pt][K=256]
  __shared__ float pcx[32], pcy[32];
  int b = blockIdx.x;                      // 2048 = 32 n * 64 chunks of 32 pts
  int n = b >> 6, pb = (b & 63) * 32;
  int t = threadIdx.x, lane = t & 63, w = t >> 6;
  int quad = lane >> 4, l16 = lane & 15;
  if (t < 32) {
    pcx[t] = oc[((size_t)n * OPP + pb + t) * 2 + 0] - ocm[n * 2 + 0];
    pcy[t] = oc[((size_t)n * OPP + pb + t) * 2 + 1] - ocm[n * 2 + 1];
  }
  __syncthreads();
  {                                        // layer1: 2 -> 64
    int c = t & 63, pg = t >> 6;
    float wx = w1[c * 2], wy = w1[c * 2 + 1], bb = b1[c];
#pragma unroll
    for (int j = 0; j < 8; ++j) {
      int p = pg * 8 + j;
      act1[p * 72 + c] = (f16)fmaxf(fmaf(wx, pcx[p], fmaf(wy, pcy[p], bb)), 0.0f);
    }
  }
  __syncthreads();
  {                                        // layer2: K=64, N=128
    int n0 = w * 32;
    f32x4 acc[2][2] = {};
#pragma unroll
    for (int ks = 0; ks < 2; ++ks) {
      half8 a0 = *(const half8*)(act1 + l16 * 72 + ks * 32 + quad * 8);
      half8 a1 = *(const half8*)(act1 + (16 + l16) * 72 + ks * 32 + quad * 8);
#pragma unroll
      for (int nt = 0; nt < 2; ++nt) {
        half8 bf = *(const half8*)(w2h + (size_t)(n0 + nt * 16 + l16) * 64 + ks * 32 + quad * 8);
        acc[0][nt] = MFMA16(a0, bf, acc[0][nt]);
        acc[1][nt] = MFMA16(a1, bf, acc[1][nt]);
      }
    }
#pragma unroll
    for (int nt = 0; nt < 2; ++nt) {
      int col = n0 + nt * 16 + l16;
      float bb = b2[col];
#pragma unroll
      for (int mt = 0; mt < 2; ++mt)
#pragma unroll
        for (int r = 0; r < 4; ++r)
          act2[(mt * 16 + quad * 4 + r) * 136 + col] = (f16)fmaxf(acc[mt][nt][r] + bb, 0.0f);
    }
  }
  __syncthreads();
  {                                        // layer3: K=128, N=256
    int n0 = w * 64;
    f32x4 acc[2][4] = {};
#pragma unroll
    for (int ks = 0; ks < 4; ++ks) {
      half8 a0 = *(const half8*)(act2 + l16 * 136 + ks * 32 + quad * 8);
      half8 a1 = *(const half8*)(act2 + (16 + l16) * 136 + ks * 32 + quad * 8);
#pragma unroll
      for (int nt = 0; nt < 4; ++nt) {
        half8 bf = *(const half8*)(w3h + (size_t)(n0 + nt * 16 + l16) * 128 + ks * 32 + quad * 8);
        acc[0][nt] = MFMA16(a0, bf, acc[0][nt]);
        acc[1][nt] = MFMA16(a1, bf, acc[1][nt]);
      }
    }
#pragma unroll
    for (int nt = 0; nt < 4; ++nt) {
      int col = n0 + nt * 16 + l16;
      float bb = b3[col];
#pragma unroll
      for (int mt = 0; mt < 2; ++mt)
#pragma unroll
        for (int r = 0; r < 4; ++r)
          act3[(mt * 16 + quad * 4 + r) * 264 + col] = (f16)fmaxf(acc[mt][nt][r] + bb, 0.0f);
    }
  }
  __syncthreads();
  {                                        // layer4: K=256, N=512; + max over points
    int n0 = w * 128;
    f32x4 acc[2][8] = {};
#pragma unroll
    for (int ks = 0; ks < 8; ++ks) {
      half8 a0 = *(const half8*)(act3 + l16 * 264 + ks * 32 + quad * 8);
      half8 a1 = *(const half8*)(act3 + (16 + l16) * 264 + ks * 32 + quad * 8);
#pragma unroll
      for (int nt = 0; nt < 8; ++nt) {
        half8 bf = *(const half8*)(w4h + (size_t)(n0 + nt * 16 + l16) * 256 + ks * 32 + quad * 8);
        acc[0][nt] = MFMA16(a0, bf, acc[0][nt]);
        acc[1][nt] = MFMA16(a1, bf, acc[1][nt]);
      }
    }
#pragma unroll
    for (int nt = 0; nt < 8; ++nt) {
      int col = n0 + nt * 16 + l16;
      float bb = b4[col];
      float v = 0.0f;
#pragma unroll
      for (int mt = 0; mt < 2; ++mt)
#pragma unroll
        for (int r = 0; r < 4; ++r)
          v = fmaxf(v, acc[mt][nt][r] + bb);
      v = fmaxf(v, 0.0f);
      v = fmaxf(v, __shfl_xor(v, 16));
      v = fmaxf(v, __shfl_xor(v, 32));
      if (quad == 0)
        atomicMax((int*)obj + (size_t)n * 512 + col, __float_as_int(v));
    }
  }
}

// ======================= classifier layer 1 (1538 -> 1024), MFMA =======================
__global__ __launch_bounds__(256) void cls1_mfma_k(
    const f16* __restrict__ scnh, const float* __restrict__ obj,
    const float* __restrict__ pos, const float* __restrict__ w1raw,
    const f16* __restrict__ w1h, const float* __restrict__ b1,
    f16* __restrict__ h1h) {
  __shared__ f16 act[112 * 72];
  __shared__ float objl[512];
  __shared__ float odl[128], wAl[128], wBl[128];
  int b = blockIdx.x;                      // 256 = 32 n * 8 octants
  int o8 = b & 7, n = b >> 3;
  int co0 = o8 * 128;
  int t = threadIdx.x, lane = t & 63, w = t >> 6;
  int quad = lane >> 4, l16 = lane & 15;
  objl[t] = obj[(size_t)n * 512 + t];
  objl[t + 256] = obj[(size_t)n * 512 + t + 256];
  __syncthreads();
  if (t < 128) {
    int co = co0 + t;
    const float* wr = w1raw + (size_t)co * 1538;
    float od = 0.0f;
    for (int k = 0; k < 512; ++k) od = fmaf(objl[k], wr[1024 + k], od);
    odl[t] = od + b1[co];
    wAl[t] = wr[1536]; wBl[t] = wr[1537];
  }
  __syncthreads();
  float posx = pos[n * 2 + 0], posy = pos[n * 2 + 1];
  f32x4 acc[7][2];
#pragma unroll
  for (int mt = 0; mt < 7; ++mt)
#pragma unroll
    for (int nt = 0; nt < 2; ++nt) {
      int cl = w * 32 + nt * 16 + l16;
      float od = odl[cl], wA = wAl[cl], wB = wBl[cl];
#pragma unroll
      for (int r = 0; r < 4; ++r) {
        int px = mt * 16 + quad * 4 + r;
        float relx = posx - (-0.5f + ((px / 10) + 0.5f) * 0.1f);
        float rely = posy - (-0.5f + ((px % 10) + 0.5f) * 0.1f);
        acc[mt][nt][r] = od + relx * wA + rely * wB;
      }
    }
  for (int kc = 0; kc < 16; ++kc) {
    int k0 = kc * 64;
    __syncthreads();
    for (int i = t; i < 896; i += 256) {
      int row = i >> 3, c8 = i & 7;
      half8 v = {};
      if (row < 100) v = *(const half8*)(scnh + ((size_t)n * 100 + row) * 1024 + k0 + c8 * 8);
      *(half8*)(act + row * 72 + c8 * 8) = v;
    }
    __syncthreads();
#pragma unroll
    for (int ks = 0; ks < 2; ++ks) {
      half8 bf0 = *(const half8*)(w1h + (size_t)(co0 + w * 32 + l16) * 1024 + k0 + ks * 32 + quad * 8);
      half8 bf1 = *(const half8*)(w1h + (size_t)(co0 + w * 32 + 16 + l16) * 1024 + k0 + ks * 32 + quad * 8);
#pragma unroll
      for (int mt = 0; mt < 7; ++mt) {
        half8 a = *(const half8*)(act + (mt * 16 + l16) * 72 + ks * 32 + quad * 8);
        acc[mt][0] = MFMA16(a, bf0, acc[mt][0]);
        acc[mt][1] = MFMA16(a, bf1, acc[mt][1]);
      }
    }
  }
#pragma unroll
  for (int mt = 0; mt < 7; ++mt)
#pragma unroll
    for (int nt = 0; nt < 2; ++nt) {
      int co = co0 + w * 32 + nt * 16 + l16;
#pragma unroll
      for (int r = 0; r < 4; ++r) {
        int px = mt * 16 + quad * 4 + r;
        if (px < 100)
          h1h[((size_t)n * 100 + px) * 1024 + co] = (f16)fmaxf(acc[mt][nt][r], 0.0f);
      }
    }
}

// ======================= classifier layer 2 (1024 -> 256) =======================
__global__ __launch_bounds__(256) void cls2_k(
    const f16* __restrict__ h1h, const float* __restrict__ w2T,
    const float* __restrict__ b2, float* __restrict__ h2) {
  __shared__ float scT[256 * 28];
  int b = blockIdx.x;
  int q = b & 3, n = b >> 2;
  int t = threadIdx.x, lane = t & 63, w = t >> 6;
  int co = w * 64 + lane;
  int p0 = q * 25;
  float acc[25];
  float bb = b2[co];
#pragma unroll
  for (int j = 0; j < 25; ++j) acc[j] = bb;
  for (int kc = 0; kc < 1024; kc += 256) {
    __syncthreads();
    for (int j = 0; j < 25; ++j)
      scT[t * 28 + j] = (float)h1h[((size_t)n * 100 + p0 + j) * 1024 + kc + t];
    __syncthreads();
    for (int k = 0; k < 256; ++k) {
      float wv = w2T[(size_t)(kc + k) * 256 + co];
      float v[28];
      const float* g = &scT[k * 28];
#pragma unroll
      for (int qq = 0; qq < 7; ++qq) *(float4*)&v[qq * 4] = *(const float4*)&g[qq * 4];
#pragma unroll
      for (int j = 0; j < 25; ++j) acc[j] = fmaf(wv, v[j], acc[j]);
    }
  }
#pragma unroll
  for (int j = 0; j < 25; ++j)
    h2[((size_t)n * 100 + p0 + j) * 256 + co] = fmaxf(acc[j], 0.0f);
}

// ======================= classifier layer 3 (256 -> 1) =======================
__global__ void cls3_k(const float* __restrict__ h2, const float* __restrict__ w3,
                       const float* __restrict__ b3, float* __restrict__ out) {
  int n = blockIdx.x, t = threadIdx.x;
  if (t < 100) {
    float acc = b3[0];
    const float* hp = &h2[((size_t)n * 100 + t) * 256];
    for (int k = 0; k < 256; ++k) acc = fmaf(hp[k], w3[k], acc);
    out[n * 100 + t] = acc;
  }
}

// ======================= launch =======================
extern "C" void kernel_launch(void* const* d_in, const int* in_sizes, int n_in,
                              void* d_out, int out_size, void* d_ws, size_t ws_size,
                              hipStream_t stream) {
  const float* sc      = (const float*)d_in[0];
  const float* oc      = (const float*)d_in[1];
  const float* pos     = (const float*)d_in[2];
  const float* mlp_w1  = (const float*)d_in[3];
  const float* mlp_b1  = (const float*)d_in[4];
  const float* mlp_w2  = (const float*)d_in[5];
  const float* mlp_b2  = (const float*)d_in[6];
  const float* conv1_w = (const float*)d_in[7];
  const float* conv1_b = (const float*)d_in[8];
  const float* conv2_w = (const float*)d_in[9];
  const float* conv2_b = (const float*)d_in[10];
  const float* convt_w = (const float*)d_in[11];
  const float* convt_b = (const float*)d_in[12];
  const float* sa_w1   = (const float*)d_in[13];
  const float* sa_b1   = (const float*)d_in[14];
  const float* sa_w2   = (const float*)d_in[15];
  const float* sa_b2   = (const float*)d_in[16];
  const float* sa_w3   = (const float*)d_in[17];
  const float* sa_b3   = (const float*)d_in[18];
  const float* sa_w4   = (const float*)d_in[19];
  const float* sa_b4   = (const float*)d_in[20];
  const float* cls_w1  = (const float*)d_in[21];
  const float* cls_b1  = (const float*)d_in[22];
  const float* cls_w2  = (const float*)d_in[23];
  const float* cls_b2  = (const float*)d_in[24];
  const float* cls_w3  = (const float*)d_in[25];
  const float* cls_b3  = (const float*)d_in[26];

  float* ws = (float*)d_ws;
  // ---- workspace layout (float units) ----
  f16*   w1h   = (f16*)ws;                         // 589,824 f
  f16*   w2h   = (f16*)(ws + 589824);              // 2,359,296 f (reused: h1h)
  f16*   mw2h  = (f16*)(ws + 2949120);             // 16,384 f
  f16*   saw2h = (f16*)(ws + 2965504);             // 4,096 f
  f16*   saw3h = (f16*)(ws + 2969600);             // 16,384 f
  f16*   saw4h = (f16*)(ws + 2985984);             // 65,536 f
  f16*   cw1h  = (f16*)(ws + 3051520);             // 524,288 f
  f16*   ctwh  = (f16*)(ws + 3575808);             // 1,048,576 f
  float* cw2T  = ws + 4624384;                     // 262,144 f
  float* big   = ws + 4886528;                     // 3,276,800 f (g1buf, g2buf)
  f16*   voxh  = (f16*)(ws + 8163328);             // 819,200 f (reused: f2h)
  f16*   f1h   = (f16*)(ws + 8982528);             // 819,200 f
  f16*   scnh  = (f16*)(ws + 9801728);             // 1,638,400 f (reused: h2)
  float* obj   = ws + 11440128;                    // 16,384 f
  float* ocm   = ws + 11456512;                    // 64 f

  f16*   g1buf = (f16*)big;                        // conv1 out
  f16*   g2buf = (f16*)big;                        // conv2 out (g1buf dead after pool1)
  f16*   f2h   = voxh;                             // pool2 out (voxh dead after conv1)
  f16*   h1h   = w2h;                              // cls1 out (w2h dead after conv2)
  float* h2    = (float*)scnh;                     // cls2 out (scnh dead after cls1)
  float* outp  = (float*)d_out;

  // ---- weight preps ----
  wprep2_k<512, 256><<<512, 256, 0, stream>>>(conv1_w, w1h);
  wprep2_k<1024, 512><<<1024, 256, 0, stream>>>(conv2_w, w2h);
  cvt16_k<<<32, 256, 0, stream>>>(mlp_w2, mw2h, 8192);
  cvt16_k<<<8, 256, 0, stream>>>(sa_w2, saw2h, 2048);
  cvt16_k<<<32, 256, 0, stream>>>(sa_w3, saw3h, 8192);
  cvt16_k<<<128, 256, 0, stream>>>(sa_w4, saw4h, 32768);
  cw1prep_k<<<4096, 256, 0, stream>>>(cls_w1, cw1h);
  ctprep_k<<<8192, 256, 0, stream>>>(convt_w, ctwh);
  dim3 tb(32, 8);
  transpose_k<<<dim3(32, 8), tb, 0, stream>>>(cls_w2, cw2T, 256, 1024, 1, 0);

  hipMemsetAsync(obj, 0, (size_t)16384 * 4, stream);
  ocmean_k<<<32, 256, 0, stream>>>(oc, ocm);

  pointnet_lds_k<<<256, 256, 0, stream>>>(sc, mlp_w1, mlp_b1, mw2h, mlp_b2, voxh);

  convmfma_k<20, 20, 256, 512, 4><<<512, 256, (7 * 22 + 384) * 80, stream>>>(
      voxh, w1h, conv1_b, g1buf);
  pool1_k<<<3200, 256, 0, stream>>>(g1buf, f1h, scnh);
  convmfma_k<10, 10, 512, 1024, 2><<<512, 256, (7 * 12 + 384) * 80, stream>>>(
      f1h, w2h, conv2_b, g2buf);
  pool2_k<<<1600, 256, 0, stream>>>(g2buf, f2h);
  convt_mfma_k<<<64, 256, 0, stream>>>(f2h, ctwh, convt_b, scnh);

  sa_mfma_k<<<2048, 256, 0, stream>>>(oc, ocm, sa_w1, sa_b1, saw2h, sa_b2,
                                      saw3h, sa_b3, saw4h, sa_b4, obj);

  cls1_mfma_k<<<256, 256, 0, stream>>>(scnh, obj, pos, cls_w1, cw1h, cls_b1, h1h);
  cls2_k<<<128, 256, 0, stream>>>(h1h, cw2T, cls_b2, h2);
  cls3_k<<<32, 128, 0, stream>>>(h2, cls_w3, cls_b3, outp);
}

// Round 7
// 697.986 us; speedup vs baseline: 1.4952x; 1.1631x over previous
//
#include <hip/hip_runtime.h>

#define NB 32
#define PP 8192
#define OPP 2048

typedef _Float16 f16;
typedef f16 half8 __attribute__((ext_vector_type(8)));
typedef f16 half4 __attribute__((ext_vector_type(4)));
typedef float f32x4 __attribute__((ext_vector_type(4)));

#define MFMA16(a, b, c) __builtin_amdgcn_mfma_f32_16x16x32_f16(a, b, c, 0, 0, 0)

// ======================= generic tiled transpose (fp32) =======================
__global__ void transpose_k(const float* __restrict__ in, float* __restrict__ out,
                            int R, int C, int es, int eo) {
  __shared__ float tile[32][33];
  int jb = blockIdx.x * 32, ib = blockIdx.y * 32;
  int tx = threadIdx.x, ty = threadIdx.y;
  for (int yy = ty; yy < 32; yy += 8) {
    int i = ib + yy, j = jb + tx;
    if (i < R && j < C) tile[yy][tx] = in[((size_t)i * C + j) * (size_t)es + eo];
  }
  __syncthreads();
  for (int yy = ty; yy < 32; yy += 8) {
    int j = jb + yy, i = ib + tx;
    if (j < C && i < R) out[(size_t)j * R + i] = tile[tx][yy];
  }
}

// ======================= conv weight prep (coalesced): [co][ci][9] -> [k][co][ci] fp16 ====
template <int CO, int CI>
__global__ __launch_bounds__(256) void wprep2_k(const float* __restrict__ wsrc,
                                                f16* __restrict__ wdst) {
  __shared__ float tile[CI * 9];
  int co = blockIdx.x, t = threadIdx.x;
  const float* src = wsrc + (size_t)co * CI * 9;
  for (int i = t; i < CI * 9; i += 256) tile[i] = src[i];
  __syncthreads();
  for (int i = t; i < CI * 9; i += 256) {
    int k = i / CI, ci = i - k * CI;
    wdst[((size_t)k * CO + co) * CI + ci] = (f16)tile[ci * 9 + k];
  }
}

__global__ void cvt16_k(const float* __restrict__ in, f16* __restrict__ out, int n4) {
  int idx = blockIdx.x * 256 + threadIdx.x;
  if (idx >= n4) return;
  float4 v = ((const float4*)in)[idx];
  half4 h; h.x = (f16)v.x; h.y = (f16)v.y; h.z = (f16)v.z; h.w = (f16)v.w;
  ((half4*)out)[idx] = h;
}

// cls_w1 scene part [1024][1538] -> [1024][1024] fp16
__global__ void cw1prep_k(const float* __restrict__ w, f16* __restrict__ out) {
  int idx = blockIdx.x * 256 + threadIdx.x;
  if (idx >= 1024 * 1024) return;
  int co = idx >> 10, k = idx & 1023;
  out[idx] = (f16)w[(size_t)co * 1538 + k];
}

// convt_w [o][i][a'][b'] -> MFMA B-fragment layout:
// ctwf[((nb*32+kb)*64 + lane)*8 + j] = W_t[np = nb*16 + (lane&15)][k = kb*32 + (lane>>4)*8 + j]
// where W_t[np][k] = convt_w[o = np&511][i = k][3 - (np>>9)]
__global__ void ctprep_k(const float* __restrict__ w, f16* __restrict__ out) {
  int idx = blockIdx.x * 256 + threadIdx.x;
  if (idx >= 2048 * 1024) return;
  int j = idx & 7, l = (idx >> 3) & 63, kb = (idx >> 9) & 31, nb = idx >> 14;
  int n16 = l & 15, quad = l >> 4;
  int np = nb * 16 + n16;
  int k = kb * 32 + quad * 8 + j;
  int p = np >> 9, o = np & 511;
  out[idx] = (f16)w[((size_t)o * 1024 + k) * 4 + (3 - p)];
}

// ======================= object-cloud mean =======================
__global__ void ocmean_k(const float* __restrict__ oc, float* __restrict__ ocm) {
  int n = blockIdx.x, t = threadIdx.x;
  __shared__ float sx[256], sy[256];
  float ax = 0.f, ay = 0.f;
  for (int p = t; p < OPP; p += 256) {
    ax += oc[((size_t)n * OPP + p) * 2 + 0];
    ay += oc[((size_t)n * OPP + p) * 2 + 1];
  }
  sx[t] = ax; sy[t] = ay;
  __syncthreads();
  for (int s = 128; s > 0; s >>= 1) {
    if (t < s) { sx[t] += sx[t + s]; sy[t] += sy[t + s]; }
    __syncthreads();
  }
  if (t == 0) {
    ocm[n * 2 + 0] = sx[0] / (float)OPP;
    ocm[n * 2 + 1] = sy[0] / (float)OPP;
  }
}

// ======================= voxel PointNet: barrier-free LDS scatter-max =======================
__global__ __launch_bounds__(256) void pointnet_lds_k(
    const float* __restrict__ sc, const float* __restrict__ w1, const float* __restrict__ b1,
    const f16* __restrict__ w2h, const float* __restrict__ b2, f16* __restrict__ voxh) {
  __shared__ float voxl[400 * 33];         // 52,800 B
  __shared__ int binl[64];                 // wave-local bin broadcast
  int t = threadIdx.x, lane = t & 63, w = t >> 6;
  int quad = lane >> 4, l16 = lane & 15;
  int b = blockIdx.x;
  int cg = b & 7, n = b >> 3;
  float w1x[32], w1y[32], b1v[32];
#pragma unroll
  for (int ks = 0; ks < 4; ++ks)
#pragma unroll
    for (int j = 0; j < 8; ++j) {
      int k = ks * 32 + quad * 8 + j;
      w1x[ks * 8 + j] = w1[k * 2];
      w1y[ks * 8 + j] = w1[k * 2 + 1];
      b1v[ks * 8 + j] = b1[k];
    }
  half8 bf[2][4];
  float bias[2];
#pragma unroll
  for (int nt = 0; nt < 2; ++nt) {
    int ch = cg * 32 + nt * 16 + l16;
    bias[nt] = b2[ch];
#pragma unroll
    for (int ks = 0; ks < 4; ++ks)
      bf[nt][ks] = *(const half8*)(w2h + (size_t)ch * 128 + ks * 32 + quad * 8);
  }
  for (int i = t; i < 400 * 33; i += 256) voxl[i] = 0.0f;
  __syncthreads();
  const float* scp = sc + (size_t)n * PP * 2;
  int p0 = w * 16 + l16;
  float2 xy = *(const float2*)(scp + p0 * 2);
  for (int it = 0; it < 128; ++it) {
    float x = xy.x, y = xy.y;
    if (it < 127) xy = *(const float2*)(scp + ((it + 1) * 64 + p0) * 2);
    float bif = fminf(fmaxf(ceilf((x + 0.5f) * 20.0f) - 1.0f, 0.0f), 19.0f);
    float bjf = fminf(fmaxf(ceilf((y + 0.5f) * 20.0f) - 1.0f, 0.0f), 19.0f);
    bool valid = (x > -0.5f) && (x <= 0.5f) && (y > -0.5f) && (y <= 0.5f);
    float px = x - (-0.5f + (bif + 0.5f) * 0.05f);
    float py = y - (-0.5f + (bjf + 0.5f) * 0.05f);
    int bn = valid ? ((int)bif * 20 + (int)bjf) : -1;
    if (quad == 0) binl[w * 16 + l16] = bn;
    f32x4 acc0 = {}, acc1 = {};
#pragma unroll
    for (int ks = 0; ks < 4; ++ks) {
      half8 af;
#pragma unroll
      for (int j = 0; j < 8; ++j)
        af[j] = (f16)fmaxf(fmaf(w1x[ks * 8 + j], px, fmaf(w1y[ks * 8 + j], py, b1v[ks * 8 + j])), 0.0f);
      acc0 = MFMA16(af, bf[0][ks], acc0);
      acc1 = MFMA16(af, bf[1][ks], acc1);
    }
#pragma unroll
    for (int r = 0; r < 4; ++r) {
      int bn2 = binl[w * 16 + quad * 4 + r];
      if (bn2 >= 0) {
        float v0 = fmaxf(acc0[r] + bias[0], 0.0f);
        float v1 = fmaxf(acc1[r] + bias[1], 0.0f);
        atomicMax((int*)voxl + bn2 * 33 + l16, __float_as_int(v0));
        atomicMax((int*)voxl + bn2 * 33 + 16 + l16, __float_as_int(v1));
      }
    }
  }
  __syncthreads();
  for (int i = t; i < 400 * 16; i += 256) {
    int bin = i >> 4, cp = i & 15;
    union { f16 h[2]; unsigned u; } pk;
    pk.h[0] = (f16)voxl[bin * 33 + cp * 2];
    pk.h[1] = (f16)voxl[bin * 33 + cp * 2 + 1];
    *(unsigned*)(voxh + ((size_t)n * 400 + bin) * 256 + cg * 32 + cp * 2) = pk.u;
  }
}

// ======================= MFMA implicit-GEMM conv 3x3 pad1 + relu =======================
template <int H, int W, int CI, int CO, int MSPLIT>
__global__ __launch_bounds__(256, 2) void convmfma_k(
    const f16* __restrict__ inh, const f16* __restrict__ wh,
    const float* __restrict__ bias, f16* __restrict__ outh) {
  constexpr int HS = H / MSPLIT;
  constexpr int Mpix = HS * W;
  constexpr int MT = (Mpix + 15) / 16;
  constexpr int PR = HS + 2, PC = W + 2;
  constexpr int NCIC = CI / 32;
  constexpr int COG = CO / 128;
  extern __shared__ char smem[];
  f16* Ap = (f16*)smem;                          // [PR*PC][40]
  f16* Bp = (f16*)(smem + PR * PC * 80);         // [3*128][40]
  int b = blockIdx.x;
  int cog = b % COG;
  int ms = (b / COG) % MSPLIT;
  int n = b / (COG * MSPLIT);
  int co0 = cog * 128;
  int r0 = ms * HS;
  int t = threadIdx.x, lane = t & 63, w = t >> 6;
  int quad = lane >> 4, l16 = lane & 15;

  int abase[MT];
#pragma unroll
  for (int mi = 0; mi < MT; ++mi) {
    int pl = mi * 16 + l16; if (pl > Mpix - 1) pl = Mpix - 1;
    int y = pl / W, x = pl - y * W;
    abase[mi] = (y * PC + x) * 40 + quad * 8;    // halves
  }
  f32x4 acc[MT][2] = {};

  const f16* inbase = inh + (size_t)n * H * W * CI;
  int nl = w * 32;

  for (int cic = 0; cic < NCIC; ++cic) {
    for (int cell = t; cell < PR * PC; cell += 256) {
      int pr = cell / PC, pc = cell - pr * PC;
      int yin = r0 - 1 + pr, xin = pc - 1;
      uint4 d0 = {0,0,0,0}, d1 = {0,0,0,0}, d2 = {0,0,0,0}, d3 = {0,0,0,0};
      if (yin >= 0 && yin < H && xin >= 0 && xin < W) {
        const uint4* src = (const uint4*)(inbase + ((size_t)yin * W + xin) * CI + cic * 32);
        d0 = src[0]; d1 = src[1]; d2 = src[2]; d3 = src[3];
      }
      uint4* dst = (uint4*)(Ap + cell * 40);
      dst[0] = d0; dst[1] = d1; dst[2] = d2; dst[3] = d3;
    }
    for (int ky = 0; ky < 3; ++ky) {
      for (int idx = t; idx < 3 * 128; idx += 256) {
        int kx = idx >> 7, cr = idx & 127;
        int k = ky * 3 + kx;
        const uint4* src = (const uint4*)(wh + ((size_t)k * CO + co0 + cr) * CI + cic * 32);
        uint4* dst = (uint4*)(Bp + idx * 40);
        dst[0] = src[0]; dst[1] = src[1]; dst[2] = src[2]; dst[3] = src[3];
      }
      __syncthreads();
#pragma unroll
      for (int kx = 0; kx < 3; ++kx) {
        int shift = (ky * PC + kx) * 40;
        half8 bf0 = *(const half8*)(Bp + (kx * 128 + nl + l16) * 40 + quad * 8);
        half8 bf1 = *(const half8*)(Bp + (kx * 128 + nl + 16 + l16) * 40 + quad * 8);
#pragma unroll
        for (int mi = 0; mi < MT; ++mi) {
          half8 af = *(const half8*)(Ap + abase[mi] + shift);
          acc[mi][0] = MFMA16(af, bf0, acc[mi][0]);
          acc[mi][1] = MFMA16(af, bf1, acc[mi][1]);
        }
      }
      __syncthreads();
    }
  }
  int co_w = co0 + nl;
  float bv0 = bias[co_w + l16];
  float bv1 = bias[co_w + 16 + l16];
  f16* ob = outh + ((size_t)n * H * W + (size_t)ms * Mpix) * CO;
#pragma unroll
  for (int mi = 0; mi < MT; ++mi) {
#pragma unroll
    for (int r = 0; r < 4; ++r) {
      int p = mi * 16 + quad * 4 + r;
      if (p < Mpix) {
        float v0 = acc[mi][0][r] + bv0; v0 = v0 > 0.f ? v0 : 0.f;
        float v1 = acc[mi][1][r] + bv1; v1 = v1 > 0.f ? v1 : 0.f;
        ob[(size_t)p * CO + co_w + l16] = (f16)v0;
        ob[(size_t)p * CO + co_w + 16 + l16] = (f16)v1;
      }
    }
  }
}

// ======================= maxpool 2x2 (+ fused pack into scene buffer) =======================
__global__ void pool1_k(const f16* __restrict__ g1, f16* __restrict__ f1h,
                        f16* __restrict__ scnh) {
  int idx = blockIdx.x * 256 + threadIdx.x;
  if (idx >= 32 * 100 * 256) return;
  int c2 = idx & 255, rem = idx >> 8;
  int op = rem % 100, n = rem / 100;
  int py = op / 10, px = op - py * 10;
  const f16* base = g1 + (((size_t)n * 400 + (size_t)(2 * py) * 20 + 2 * px) * 512) + c2 * 2;
  float a0 = (float)base[0],   a1 = (float)base[1];
  float b0 = (float)base[512], b1 = (float)base[513];
  const f16* base2 = base + 20 * 512;
  float c0 = (float)base2[0],   c1 = (float)base2[1];
  float d0 = (float)base2[512], d1 = (float)base2[513];
  union { f16 h[2]; unsigned u; } pk;
  pk.h[0] = (f16)fmaxf(fmaxf(a0, b0), fmaxf(c0, d0));
  pk.h[1] = (f16)fmaxf(fmaxf(a1, b1), fmaxf(c1, d1));
  *(unsigned*)(f1h + ((size_t)n * 100 + op) * 512 + c2 * 2) = pk.u;
  *(unsigned*)(scnh + ((size_t)n * 100 + op) * 1024 + c2 * 2) = pk.u;
}

__global__ void pool2_k(const f16* __restrict__ g2, f16* __restrict__ f2h) {
  int idx = blockIdx.x * 256 + threadIdx.x;
  if (idx >= 32 * 25 * 512) return;
  int c2 = idx & 511, rem = idx >> 9;
  int op = rem % 25, n = rem / 25;
  int py = op / 5, px = op - py * 5;
  const f16* base = g2 + (((size_t)n * 100 + (size_t)(2 * py) * 10 + 2 * px) * 1024) + c2 * 2;
  float a0 = (float)base[0],    a1 = (float)base[1];
  float b0 = (float)base[1024], b1 = (float)base[1025];
  const f16* base2 = base + 10 * 1024;
  float c0 = (float)base2[0],    c1 = (float)base2[1];
  float d0 = (float)base2[1024], d1 = (float)base2[1025];
  f16* o = f2h + ((size_t)n * 25 + op) * 1024 + c2 * 2;
  o[0] = (f16)fmaxf(fmaxf(a0, b0), fmaxf(c0, d0));
  o[1] = (f16)fmaxf(fmaxf(a1, b1), fmaxf(c1, d1));
}

// ======================= conv transpose 2x2 s2 (1024->512), MFMA v2 =======================
// Grid 512 = 32 n x 16 output-groups (128 of 2048 np each). Weights in B-frag layout (ctwf).
// Act (25x1024) staged once in LDS (stride 1048 halves -> 2-way banks, free). Barrier-free K-loop.
__global__ __launch_bounds__(256, 2) void convt_mfma_k(
    const f16* __restrict__ f2h, const f16* __restrict__ ctwf,
    const float* __restrict__ ctb, f16* __restrict__ scnh) {
  __shared__ f16 act[25 * 1048];           // 52,400 B
  int b = blockIdx.x;
  int ng = b & 15, n = b >> 4;
  int t = threadIdx.x, lane = t & 63, w = t >> 6;
  int quad = lane >> 4, l16 = lane & 15;
  for (int i = t; i < 25 * 128; i += 256) {
    int row = i >> 7, c8 = i & 127;
    *(half8*)(act + row * 1048 + c8 * 8) =
        *(const half8*)(f2h + ((size_t)n * 25 + row) * 1024 + c8 * 8);
  }
  __syncthreads();
  int r1 = 16 + (l16 > 8 ? 8 : l16);       // clamp: garbage rows never stored
  f32x4 acc[2][2] = {};
  const f16* wp0 = ctwf + ((size_t)((ng * 8 + w * 2 + 0) * 32) * 64 + lane) * 8;
  const f16* wp1 = ctwf + ((size_t)((ng * 8 + w * 2 + 1) * 32) * 64 + lane) * 8;
#pragma unroll 4
  for (int ks = 0; ks < 32; ++ks) {
    half8 a0 = *(const half8*)(act + l16 * 1048 + ks * 32 + quad * 8);
    half8 a1 = *(const half8*)(act + r1 * 1048 + ks * 32 + quad * 8);
    half8 b0 = *(const half8*)(wp0 + (size_t)ks * 512);
    half8 b1 = *(const half8*)(wp1 + (size_t)ks * 512);
    acc[0][0] = MFMA16(a0, b0, acc[0][0]);
    acc[1][0] = MFMA16(a1, b0, acc[1][0]);
    acc[0][1] = MFMA16(a0, b1, acc[0][1]);
    acc[1][1] = MFMA16(a1, b1, acc[1][1]);
  }
#pragma unroll
  for (int nt = 0; nt < 2; ++nt) {
    int np = ng * 128 + w * 32 + nt * 16 + l16;
    int p = np >> 9, co = np & 511;
    int a = p >> 1, bc = p & 1;
    float bb = ctb[co];
#pragma unroll
    for (int mt = 0; mt < 2; ++mt)
#pragma unroll
      for (int r = 0; r < 4; ++r) {
        int px = mt * 16 + quad * 4 + r;
        if (px < 25) {
          int ph = px / 5, pw = px - ph * 5;
          int opx = (2 * ph + a) * 10 + 2 * pw + bc;
          scnh[((size_t)n * 100 + opx) * 1024 + 512 + co] = (f16)(acc[mt][nt][r] + bb);
        }
      }
  }
}

// ======================= object SA: fused 4-layer MFMA + max =======================
__global__ __launch_bounds__(256) void sa_mfma_k(
    const float* __restrict__ oc, const float* __restrict__ ocm,
    const float* __restrict__ w1, const float* __restrict__ b1,
    const f16* __restrict__ w2h, const float* __restrict__ b2,
    const f16* __restrict__ w3h, const float* __restrict__ b3,
    const f16* __restrict__ w4h, const float* __restrict__ b4,
    float* __restrict__ obj) {
  __shared__ f16 act1[32 * 72];            // [pt][K=64]
  __shared__ f16 act2[32 * 136];           // [pt][K=128]
  __shared__ f16 act3[32 * 264];           // [pt][K=256]
  __shared__ float pcx[32], pcy[32];
  int b = blockIdx.x;                      // 2048 = 32 n * 64 chunks of 32 pts
  int n = b >> 6, pb = (b & 63) * 32;
  int t = threadIdx.x, lane = t & 63, w = t >> 6;
  int quad = lane >> 4, l16 = lane & 15;
  if (t < 32) {
    pcx[t] = oc[((size_t)n * OPP + pb + t) * 2 + 0] - ocm[n * 2 + 0];
    pcy[t] = oc[((size_t)n * OPP + pb + t) * 2 + 1] - ocm[n * 2 + 1];
  }
  __syncthreads();
  {                                        // layer1: 2 -> 64
    int c = t & 63, pg = t >> 6;
    float wx = w1[c * 2], wy = w1[c * 2 + 1], bb = b1[c];
#pragma unroll
    for (int j = 0; j < 8; ++j) {
      int p = pg * 8 + j;
      act1[p * 72 + c] = (f16)fmaxf(fmaf(wx, pcx[p], fmaf(wy, pcy[p], bb)), 0.0f);
    }
  }
  __syncthreads();
  {                                        // layer2: K=64, N=128
    int n0 = w * 32;
    f32x4 acc[2][2] = {};
#pragma unroll
    for (int ks = 0; ks < 2; ++ks) {
      half8 a0 = *(const half8*)(act1 + l16 * 72 + ks * 32 + quad * 8);
      half8 a1 = *(const half8*)(act1 + (16 + l16) * 72 + ks * 32 + quad * 8);
#pragma unroll
      for (int nt = 0; nt < 2; ++nt) {
        half8 bf = *(const half8*)(w2h + (size_t)(n0 + nt * 16 + l16) * 64 + ks * 32 + quad * 8);
        acc[0][nt] = MFMA16(a0, bf, acc[0][nt]);
        acc[1][nt] = MFMA16(a1, bf, acc[1][nt]);
      }
    }
#pragma unroll
    for (int nt = 0; nt < 2; ++nt) {
      int col = n0 + nt * 16 + l16;
      float bb = b2[col];
#pragma unroll
      for (int mt = 0; mt < 2; ++mt)
#pragma unroll
        for (int r = 0; r < 4; ++r)
          act2[(mt * 16 + quad * 4 + r) * 136 + col] = (f16)fmaxf(acc[mt][nt][r] + bb, 0.0f);
    }
  }
  __syncthreads();
  {                                        // layer3: K=128, N=256
    int n0 = w * 64;
    f32x4 acc[2][4] = {};
#pragma unroll
    for (int ks = 0; ks < 4; ++ks) {
      half8 a0 = *(const half8*)(act2 + l16 * 136 + ks * 32 + quad * 8);
      half8 a1 = *(const half8*)(act2 + (16 + l16) * 136 + ks * 32 + quad * 8);
#pragma unroll
      for (int nt = 0; nt < 4; ++nt) {
        half8 bf = *(const half8*)(w3h + (size_t)(n0 + nt * 16 + l16) * 128 + ks * 32 + quad * 8);
        acc[0][nt] = MFMA16(a0, bf, acc[0][nt]);
        acc[1][nt] = MFMA16(a1, bf, acc[1][nt]);
      }
    }
#pragma unroll
    for (int nt = 0; nt < 4; ++nt) {
      int col = n0 + nt * 16 + l16;
      float bb = b3[col];
#pragma unroll
      for (int mt = 0; mt < 2; ++mt)
#pragma unroll
        for (int r = 0; r < 4; ++r)
          act3[(mt * 16 + quad * 4 + r) * 264 + col] = (f16)fmaxf(acc[mt][nt][r] + bb, 0.0f);
    }
  }
  __syncthreads();
  {                                        // layer4: K=256, N=512; + max over points
    int n0 = w * 128;
    f32x4 acc[2][8] = {};
#pragma unroll
    for (int ks = 0; ks < 8; ++ks) {
      half8 a0 = *(const half8*)(act3 + l16 * 264 + ks * 32 + quad * 8);
      half8 a1 = *(const half8*)(act3 + (16 + l16) * 264 + ks * 32 + quad * 8);
#pragma unroll
      for (int nt = 0; nt < 8; ++nt) {
        half8 bf = *(const half8*)(w4h + (size_t)(n0 + nt * 16 + l16) * 256 + ks * 32 + quad * 8);
        acc[0][nt] = MFMA16(a0, bf, acc[0][nt]);
        acc[1][nt] = MFMA16(a1, bf, acc[1][nt]);
      }
    }
#pragma unroll
    for (int nt = 0; nt < 8; ++nt) {
      int col = n0 + nt * 16 + l16;
      float bb = b4[col];
      float v = 0.0f;
#pragma unroll
      for (int mt = 0; mt < 2; ++mt)
#pragma unroll
        for (int r = 0; r < 4; ++r)
          v = fmaxf(v, acc[mt][nt][r] + bb);
      v = fmaxf(v, 0.0f);
      v = fmaxf(v, __shfl_xor(v, 16));
      v = fmaxf(v, __shfl_xor(v, 32));
      if (quad == 0)
        atomicMax((int*)obj + (size_t)n * 512 + col, __float_as_int(v));
    }
  }
}

// ======================= classifier layer 1 (1538 -> 1024), MFMA =======================
__global__ __launch_bounds__(256) void cls1_mfma_k(
    const f16* __restrict__ scnh, const float* __restrict__ obj,
    const float* __restrict__ pos, const float* __restrict__ w1raw,
    const f16* __restrict__ w1h, const float* __restrict__ b1,
    f16* __restrict__ h1h) {
  __shared__ f16 act[112 * 72];
  __shared__ float objl[512];
  __shared__ float odl[128], wAl[128], wBl[128];
  int b = blockIdx.x;                      // 256 = 32 n * 8 octants
  int o8 = b & 7, n = b >> 3;
  int co0 = o8 * 128;
  int t = threadIdx.x, lane = t & 63, w = t >> 6;
  int quad = lane >> 4, l16 = lane & 15;
  objl[t] = obj[(size_t)n * 512 + t];
  objl[t + 256] = obj[(size_t)n * 512 + t + 256];
  __syncthreads();
  if (t < 128) {
    int co = co0 + t;
    const float* wr = w1raw + (size_t)co * 1538;
    float od = 0.0f;
    for (int k = 0; k < 512; ++k) od = fmaf(objl[k], wr[1024 + k], od);
    odl[t] = od + b1[co];
    wAl[t] = wr[1536]; wBl[t] = wr[1537];
  }
  __syncthreads();
  float posx = pos[n * 2 + 0], posy = pos[n * 2 + 1];
  f32x4 acc[7][2];
#pragma unroll
  for (int mt = 0; mt < 7; ++mt)
#pragma unroll
    for (int nt = 0; nt < 2; ++nt) {
      int cl = w * 32 + nt * 16 + l16;
      float od = odl[cl], wA = wAl[cl], wB = wBl[cl];
#pragma unroll
      for (int r = 0; r < 4; ++r) {
        int px = mt * 16 + quad * 4 + r;
        float relx = posx - (-0.5f + ((px / 10) + 0.5f) * 0.1f);
        float rely = posy - (-0.5f + ((px % 10) + 0.5f) * 0.1f);
        acc[mt][nt][r] = od + relx * wA + rely * wB;
      }
    }
  for (int kc = 0; kc < 16; ++kc) {
    int k0 = kc * 64;
    __syncthreads();
    for (int i = t; i < 896; i += 256) {
      int row = i >> 3, c8 = i & 7;
      half8 v = {};
      if (row < 100) v = *(const half8*)(scnh + ((size_t)n * 100 + row) * 1024 + k0 + c8 * 8);
      *(half8*)(act + row * 72 + c8 * 8) = v;
    }
    __syncthreads();
#pragma unroll
    for (int ks = 0; ks < 2; ++ks) {
      half8 bf0 = *(const half8*)(w1h + (size_t)(co0 + w * 32 + l16) * 1024 + k0 + ks * 32 + quad * 8);
      half8 bf1 = *(const half8*)(w1h + (size_t)(co0 + w * 32 + 16 + l16) * 1024 + k0 + ks * 32 + quad * 8);
#pragma unroll
      for (int mt = 0; mt < 7; ++mt) {
        half8 a = *(const half8*)(act + (mt * 16 + l16) * 72 + ks * 32 + quad * 8);
        acc[mt][0] = MFMA16(a, bf0, acc[mt][0]);
        acc[mt][1] = MFMA16(a, bf1, acc[mt][1]);
      }
    }
  }
#pragma unroll
  for (int mt = 0; mt < 7; ++mt)
#pragma unroll
    for (int nt = 0; nt < 2; ++nt) {
      int co = co0 + w * 32 + nt * 16 + l16;
#pragma unroll
      for (int r = 0; r < 4; ++r) {
        int px = mt * 16 + quad * 4 + r;
        if (px < 100)
          h1h[((size_t)n * 100 + px) * 1024 + co] = (f16)fmaxf(acc[mt][nt][r], 0.0f);
      }
    }
}

// ======================= classifier layer 2 (1024 -> 256) =======================
__global__ __launch_bounds__(256) void cls2_k(
    const f16* __restrict__ h1h, const float* __restrict__ w2T,
    const float* __restrict__ b2, float* __restrict__ h2) {
  __shared__ float scT[256 * 28];
  int b = blockIdx.x;
  int q = b & 3, n = b >> 2;
  int t = threadIdx.x, lane = t & 63, w = t >> 6;
  int co = w * 64 + lane;
  int p0 = q * 25;
  float acc[25];
  float bb = b2[co];
#pragma unroll
  for (int j = 0; j < 25; ++j) acc[j] = bb;
  for (int kc = 0; kc < 1024; kc += 256) {
    __syncthreads();
    for (int j = 0; j < 25; ++j)
      scT[t * 28 + j] = (float)h1h[((size_t)n * 100 + p0 + j) * 1024 + kc + t];
    __syncthreads();
    for (int k = 0; k < 256; ++k) {
      float wv = w2T[(size_t)(kc + k) * 256 + co];
      float v[28];
      const float* g = &scT[k * 28];
#pragma unroll
      for (int qq = 0; qq < 7; ++qq) *(float4*)&v[qq * 4] = *(const float4*)&g[qq * 4];
#pragma unroll
      for (int j = 0; j < 25; ++j) acc[j] = fmaf(wv, v[j], acc[j]);
    }
  }
#pragma unroll
  for (int j = 0; j < 25; ++j)
    h2[((size_t)n * 100 + p0 + j) * 256 + co] = fmaxf(acc[j], 0.0f);
}

// ======================= classifier layer 3 (256 -> 1) =======================
__global__ void cls3_k(const float* __restrict__ h2, const float* __restrict__ w3,
                       const float* __restrict__ b3, float* __restrict__ out) {
  int n = blockIdx.x, t = threadIdx.x;
  if (t < 100) {
    float acc = b3[0];
    const float* hp = &h2[((size_t)n * 100 + t) * 256];
    for (int k = 0; k < 256; ++k) acc = fmaf(hp[k], w3[k], acc);
    out[n * 100 + t] = acc;
  }
}

// ======================= launch =======================
extern "C" void kernel_launch(void* const* d_in, const int* in_sizes, int n_in,
                              void* d_out, int out_size, void* d_ws, size_t ws_size,
                              hipStream_t stream) {
  const float* sc      = (const float*)d_in[0];
  const float* oc      = (const float*)d_in[1];
  const float* pos     = (const float*)d_in[2];
  const float* mlp_w1  = (const float*)d_in[3];
  const float* mlp_b1  = (const float*)d_in[4];
  const float* mlp_w2  = (const float*)d_in[5];
  const float* mlp_b2  = (const float*)d_in[6];
  const float* conv1_w = (const float*)d_in[7];
  const float* conv1_b = (const float*)d_in[8];
  const float* conv2_w = (const float*)d_in[9];
  const float* conv2_b = (const float*)d_in[10];
  const float* convt_w = (const float*)d_in[11];
  const float* convt_b = (const float*)d_in[12];
  const float* sa_w1   = (const float*)d_in[13];
  const float* sa_b1   = (const float*)d_in[14];
  const float* sa_w2   = (const float*)d_in[15];
  const float* sa_b2   = (const float*)d_in[16];
  const float* sa_w3   = (const float*)d_in[17];
  const float* sa_b3   = (const float*)d_in[18];
  const float* sa_w4   = (const float*)d_in[19];
  const float* sa_b4   = (const float*)d_in[20];
  const float* cls_w1  = (const float*)d_in[21];
  const float* cls_b1  = (const float*)d_in[22];
  const float* cls_w2  = (const float*)d_in[23];
  const float* cls_b2  = (const float*)d_in[24];
  const float* cls_w3  = (const float*)d_in[25];
  const float* cls_b3  = (const float*)d_in[26];

  float* ws = (float*)d_ws;
  // ---- workspace layout (float units) ----
  f16*   w1h   = (f16*)ws;                         // 589,824 f
  f16*   w2h   = (f16*)(ws + 589824);              // 2,359,296 f (reused: h1h)
  f16*   mw2h  = (f16*)(ws + 2949120);             // 16,384 f
  f16*   saw2h = (f16*)(ws + 2965504);             // 4,096 f
  f16*   saw3h = (f16*)(ws + 2969600);             // 16,384 f
  f16*   saw4h = (f16*)(ws + 2985984);             // 65,536 f
  f16*   cw1h  = (f16*)(ws + 3051520);             // 524,288 f
  f16*   ctwh  = (f16*)(ws + 3575808);             // 1,048,576 f (B-frag layout)
  float* cw2T  = ws + 4624384;                     // 262,144 f
  float* big   = ws + 4886528;                     // 3,276,800 f (g1buf, g2buf)
  f16*   voxh  = (f16*)(ws + 8163328);             // 819,200 f (reused: f2h)
  f16*   f1h   = (f16*)(ws + 8982528);             // 819,200 f
  f16*   scnh  = (f16*)(ws + 9801728);             // 1,638,400 f (reused: h2)
  float* obj   = ws + 11440128;                    // 16,384 f
  float* ocm   = ws + 11456512;                    // 64 f

  f16*   g1buf = (f16*)big;                        // conv1 out
  f16*   g2buf = (f16*)big;                        // conv2 out (g1buf dead after pool1)
  f16*   f2h   = voxh;                             // pool2 out (voxh dead after conv1)
  f16*   h1h   = w2h;                              // cls1 out (w2h dead after conv2)
  float* h2    = (float*)scnh;                     // cls2 out (scnh dead after cls1)
  float* outp  = (float*)d_out;

  // ---- weight preps ----
  wprep2_k<512, 256><<<512, 256, 0, stream>>>(conv1_w, w1h);
  wprep2_k<1024, 512><<<1024, 256, 0, stream>>>(conv2_w, w2h);
  cvt16_k<<<32, 256, 0, stream>>>(mlp_w2, mw2h, 8192);
  cvt16_k<<<8, 256, 0, stream>>>(sa_w2, saw2h, 2048);
  cvt16_k<<<32, 256, 0, stream>>>(sa_w3, saw3h, 8192);
  cvt16_k<<<128, 256, 0, stream>>>(sa_w4, saw4h, 32768);
  cw1prep_k<<<4096, 256, 0, stream>>>(cls_w1, cw1h);
  ctprep_k<<<8192, 256, 0, stream>>>(convt_w, ctwh);
  dim3 tb(32, 8);
  transpose_k<<<dim3(32, 8), tb, 0, stream>>>(cls_w2, cw2T, 256, 1024, 1, 0);

  hipMemsetAsync(obj, 0, (size_t)16384 * 4, stream);
  ocmean_k<<<32, 256, 0, stream>>>(oc, ocm);

  pointnet_lds_k<<<256, 256, 0, stream>>>(sc, mlp_w1, mlp_b1, mw2h, mlp_b2, voxh);

  convmfma_k<20, 20, 256, 512, 4><<<512, 256, (7 * 22 + 384) * 80, stream>>>(
      voxh, w1h, conv1_b, g1buf);
  pool1_k<<<3200, 256, 0, stream>>>(g1buf, f1h, scnh);
  convmfma_k<10, 10, 512, 1024, 2><<<512, 256, (7 * 12 + 384) * 80, stream>>>(
      f1h, w2h, conv2_b, g2buf);
  pool2_k<<<1600, 256, 0, stream>>>(g2buf, f2h);
  convt_mfma_k<<<512, 256, 0, stream>>>(f2h, ctwh, convt_b, scnh);

  sa_mfma_k<<<2048, 256, 0, stream>>>(oc, ocm, sa_w1, sa_b1, saw2h, sa_b2,
                                      saw3h, sa_b3, saw4h, sa_b4, obj);

  cls1_mfma_k<<<256, 256, 0, stream>>>(scnh, obj, pos, cls_w1, cw1h, cls_b1, h1h);
  cls2_k<<<128, 256, 0, stream>>>(h1h, cw2T, cls_b2, h2);
  cls3_k<<<32, 128, 0, stream>>>(h2, cls_w3, cls_b3, outp);
}

// Round 8
// 611.949 us; speedup vs baseline: 1.7054x; 1.1406x over previous
//
#include <hip/hip_runtime.h>

#define NB 32
#define PP 8192
#define OPP 2048

typedef _Float16 f16;
typedef f16 half8 __attribute__((ext_vector_type(8)));
typedef f16 half4 __attribute__((ext_vector_type(4)));
typedef float f32x4 __attribute__((ext_vector_type(4)));

#define MFMA16(a, b, c) __builtin_amdgcn_mfma_f32_16x16x32_f16(a, b, c, 0, 0, 0)

// ======================= conv weight prep (coalesced): [co][ci][9] -> [k][co][ci] fp16 ====
template <int CO, int CI>
__global__ __launch_bounds__(256) void wprep2_k(const float* __restrict__ wsrc,
                                                f16* __restrict__ wdst) {
  __shared__ float tile[CI * 9];
  int co = blockIdx.x, t = threadIdx.x;
  const float* src = wsrc + (size_t)co * CI * 9;
  for (int i = t; i < CI * 9; i += 256) tile[i] = src[i];
  __syncthreads();
  for (int i = t; i < CI * 9; i += 256) {
    int k = i / CI, ci = i - k * CI;
    wdst[((size_t)k * CO + co) * CI + ci] = (f16)tile[ci * 9 + k];
  }
}

__global__ void cvt16_k(const float* __restrict__ in, f16* __restrict__ out, int n4) {
  int idx = blockIdx.x * 256 + threadIdx.x;
  if (idx >= n4) return;
  float4 v = ((const float4*)in)[idx];
  half4 h; h.x = (f16)v.x; h.y = (f16)v.y; h.z = (f16)v.z; h.w = (f16)v.w;
  ((half4*)out)[idx] = h;
}

// cls_w1 scene part [1024][1538] -> [1024][1024] fp16
__global__ void cw1prep_k(const float* __restrict__ w, f16* __restrict__ out) {
  int idx = blockIdx.x * 256 + threadIdx.x;
  if (idx >= 1024 * 1024) return;
  int co = idx >> 10, k = idx & 1023;
  out[idx] = (f16)w[(size_t)co * 1538 + k];
}

// convt_w [o][i][a'][b'] -> MFMA B-fragment layout
__global__ void ctprep_k(const float* __restrict__ w, f16* __restrict__ out) {
  int idx = blockIdx.x * 256 + threadIdx.x;
  if (idx >= 2048 * 1024) return;
  int j = idx & 7, l = (idx >> 3) & 63, kb = (idx >> 9) & 31, nb = idx >> 14;
  int n16 = l & 15, quad = l >> 4;
  int np = nb * 16 + n16;
  int k = kb * 32 + quad * 8 + j;
  int p = np >> 9, o = np & 511;
  out[idx] = (f16)w[((size_t)o * 1024 + k) * 4 + (3 - p)];
}

// ======================= object-cloud mean =======================
__global__ void ocmean_k(const float* __restrict__ oc, float* __restrict__ ocm) {
  int n = blockIdx.x, t = threadIdx.x;
  __shared__ float sx[256], sy[256];
  float ax = 0.f, ay = 0.f;
  for (int p = t; p < OPP; p += 256) {
    ax += oc[((size_t)n * OPP + p) * 2 + 0];
    ay += oc[((size_t)n * OPP + p) * 2 + 1];
  }
  sx[t] = ax; sy[t] = ay;
  __syncthreads();
  for (int s = 128; s > 0; s >>= 1) {
    if (t < s) { sx[t] += sx[t + s]; sy[t] += sy[t + s]; }
    __syncthreads();
  }
  if (t == 0) {
    ocm[n * 2 + 0] = sx[0] / (float)OPP;
    ocm[n * 2 + 1] = sy[0] / (float)OPP;
  }
}

// ======================= voxel PointNet: barrier-free LDS scatter-max =======================
__global__ __launch_bounds__(256) void pointnet_lds_k(
    const float* __restrict__ sc, const float* __restrict__ w1, const float* __restrict__ b1,
    const f16* __restrict__ w2h, const float* __restrict__ b2, f16* __restrict__ voxh) {
  __shared__ float voxl[400 * 33];         // 52,800 B
  __shared__ int binl[64];                 // wave-local bin broadcast
  int t = threadIdx.x, lane = t & 63, w = t >> 6;
  int quad = lane >> 4, l16 = lane & 15;
  int b = blockIdx.x;
  int cg = b & 7, n = b >> 3;
  float w1x[32], w1y[32], b1v[32];
#pragma unroll
  for (int ks = 0; ks < 4; ++ks)
#pragma unroll
    for (int j = 0; j < 8; ++j) {
      int k = ks * 32 + quad * 8 + j;
      w1x[ks * 8 + j] = w1[k * 2];
      w1y[ks * 8 + j] = w1[k * 2 + 1];
      b1v[ks * 8 + j] = b1[k];
    }
  half8 bf[2][4];
  float bias[2];
#pragma unroll
  for (int nt = 0; nt < 2; ++nt) {
    int ch = cg * 32 + nt * 16 + l16;
    bias[nt] = b2[ch];
#pragma unroll
    for (int ks = 0; ks < 4; ++ks)
      bf[nt][ks] = *(const half8*)(w2h + (size_t)ch * 128 + ks * 32 + quad * 8);
  }
  for (int i = t; i < 400 * 33; i += 256) voxl[i] = 0.0f;
  __syncthreads();
  const float* scp = sc + (size_t)n * PP * 2;
  int p0 = w * 16 + l16;
  float2 xy = *(const float2*)(scp + p0 * 2);
  for (int it = 0; it < 128; ++it) {
    float x = xy.x, y = xy.y;
    if (it < 127) xy = *(const float2*)(scp + ((it + 1) * 64 + p0) * 2);
    float bif = fminf(fmaxf(ceilf((x + 0.5f) * 20.0f) - 1.0f, 0.0f), 19.0f);
    float bjf = fminf(fmaxf(ceilf((y + 0.5f) * 20.0f) - 1.0f, 0.0f), 19.0f);
    bool valid = (x > -0.5f) && (x <= 0.5f) && (y > -0.5f) && (y <= 0.5f);
    float px = x - (-0.5f + (bif + 0.5f) * 0.05f);
    float py = y - (-0.5f + (bjf + 0.5f) * 0.05f);
    int bn = valid ? ((int)bif * 20 + (int)bjf) : -1;
    if (quad == 0) binl[w * 16 + l16] = bn;
    f32x4 acc0 = {}, acc1 = {};
#pragma unroll
    for (int ks = 0; ks < 4; ++ks) {
      half8 af;
#pragma unroll
      for (int j = 0; j < 8; ++j)
        af[j] = (f16)fmaxf(fmaf(w1x[ks * 8 + j], px, fmaf(w1y[ks * 8 + j], py, b1v[ks * 8 + j])), 0.0f);
      acc0 = MFMA16(af, bf[0][ks], acc0);
      acc1 = MFMA16(af, bf[1][ks], acc1);
    }
#pragma unroll
    for (int r = 0; r < 4; ++r) {
      int bn2 = binl[w * 16 + quad * 4 + r];
      if (bn2 >= 0) {
        float v0 = fmaxf(acc0[r] + bias[0], 0.0f);
        float v1 = fmaxf(acc1[r] + bias[1], 0.0f);
        atomicMax((int*)voxl + bn2 * 33 + l16, __float_as_int(v0));
        atomicMax((int*)voxl + bn2 * 33 + 16 + l16, __float_as_int(v1));
      }
    }
  }
  __syncthreads();
  for (int i = t; i < 400 * 16; i += 256) {
    int bin = i >> 4, cp = i & 15;
    union { f16 h[2]; unsigned u; } pk;
    pk.h[0] = (f16)voxl[bin * 33 + cp * 2];
    pk.h[1] = (f16)voxl[bin * 33 + cp * 2 + 1];
    *(unsigned*)(voxh + ((size_t)n * 400 + bin) * 256 + cg * 32 + cp * 2) = pk.u;
  }
}

// ======================= MFMA implicit-GEMM conv 3x3 pad1 + relu =======================
template <int H, int W, int CI, int CO, int MSPLIT>
__global__ __launch_bounds__(256, 2) void convmfma_k(
    const f16* __restrict__ inh, const f16* __restrict__ wh,
    const float* __restrict__ bias, f16* __restrict__ outh) {
  constexpr int HS = H / MSPLIT;
  constexpr int Mpix = HS * W;
  constexpr int MT = (Mpix + 15) / 16;
  constexpr int PR = HS + 2, PC = W + 2;
  constexpr int NCIC = CI / 32;
  constexpr int COG = CO / 128;
  extern __shared__ char smem[];
  f16* Ap = (f16*)smem;                          // [PR*PC][40]
  f16* Bp = (f16*)(smem + PR * PC * 80);         // [3*128][40]
  int b = blockIdx.x;
  int cog = b % COG;
  int ms = (b / COG) % MSPLIT;
  int n = b / (COG * MSPLIT);
  int co0 = cog * 128;
  int r0 = ms * HS;
  int t = threadIdx.x, lane = t & 63, w = t >> 6;
  int quad = lane >> 4, l16 = lane & 15;

  int abase[MT];
#pragma unroll
  for (int mi = 0; mi < MT; ++mi) {
    int pl = mi * 16 + l16; if (pl > Mpix - 1) pl = Mpix - 1;
    int y = pl / W, x = pl - y * W;
    abase[mi] = (y * PC + x) * 40 + quad * 8;    // halves
  }
  f32x4 acc[MT][2] = {};

  const f16* inbase = inh + (size_t)n * H * W * CI;
  int nl = w * 32;

  for (int cic = 0; cic < NCIC; ++cic) {
    for (int cell = t; cell < PR * PC; cell += 256) {
      int pr = cell / PC, pc = cell - pr * PC;
      int yin = r0 - 1 + pr, xin = pc - 1;
      uint4 d0 = {0,0,0,0}, d1 = {0,0,0,0}, d2 = {0,0,0,0}, d3 = {0,0,0,0};
      if (yin >= 0 && yin < H && xin >= 0 && xin < W) {
        const uint4* src = (const uint4*)(inbase + ((size_t)yin * W + xin) * CI + cic * 32);
        d0 = src[0]; d1 = src[1]; d2 = src[2]; d3 = src[3];
      }
      uint4* dst = (uint4*)(Ap + cell * 40);
      dst[0] = d0; dst[1] = d1; dst[2] = d2; dst[3] = d3;
    }
    for (int ky = 0; ky < 3; ++ky) {
      for (int idx = t; idx < 3 * 128; idx += 256) {
        int kx = idx >> 7, cr = idx & 127;
        int k = ky * 3 + kx;
        const uint4* src = (const uint4*)(wh + ((size_t)k * CO + co0 + cr) * CI + cic * 32);
        uint4* dst = (uint4*)(Bp + idx * 40);
        dst[0] = src[0]; dst[1] = src[1]; dst[2] = src[2]; dst[3] = src[3];
      }
      __syncthreads();
#pragma unroll
      for (int kx = 0; kx < 3; ++kx) {
        int shift = (ky * PC + kx) * 40;
        half8 bf0 = *(const half8*)(Bp + (kx * 128 + nl + l16) * 40 + quad * 8);
        half8 bf1 = *(const half8*)(Bp + (kx * 128 + nl + 16 + l16) * 40 + quad * 8);
#pragma unroll
        for (int mi = 0; mi < MT; ++mi) {
          half8 af = *(const half8*)(Ap + abase[mi] + shift);
          acc[mi][0] = MFMA16(af, bf0, acc[mi][0]);
          acc[mi][1] = MFMA16(af, bf1, acc[mi][1]);
        }
      }
      __syncthreads();
    }
  }
  int co_w = co0 + nl;
  float bv0 = bias[co_w + l16];
  float bv1 = bias[co_w + 16 + l16];
  f16* ob = outh + ((size_t)n * H * W + (size_t)ms * Mpix) * CO;
#pragma unroll
  for (int mi = 0; mi < MT; ++mi) {
#pragma unroll
    for (int r = 0; r < 4; ++r) {
      int p = mi * 16 + quad * 4 + r;
      if (p < Mpix) {
        float v0 = acc[mi][0][r] + bv0; v0 = v0 > 0.f ? v0 : 0.f;
        float v1 = acc[mi][1][r] + bv1; v1 = v1 > 0.f ? v1 : 0.f;
        ob[(size_t)p * CO + co_w + l16] = (f16)v0;
        ob[(size_t)p * CO + co_w + 16 + l16] = (f16)v1;
      }
    }
  }
}

// ======================= maxpool 2x2 (+ fused pack into scene buffer) =======================
__global__ void pool1_k(const f16* __restrict__ g1, f16* __restrict__ f1h,
                        f16* __restrict__ scnh) {
  int idx = blockIdx.x * 256 + threadIdx.x;
  if (idx >= 32 * 100 * 256) return;
  int c2 = idx & 255, rem = idx >> 8;
  int op = rem % 100, n = rem / 100;
  int py = op / 10, px = op - py * 10;
  const f16* base = g1 + (((size_t)n * 400 + (size_t)(2 * py) * 20 + 2 * px) * 512) + c2 * 2;
  float a0 = (float)base[0],   a1 = (float)base[1];
  float b0 = (float)base[512], b1 = (float)base[513];
  const f16* base2 = base + 20 * 512;
  float c0 = (float)base2[0],   c1 = (float)base2[1];
  float d0 = (float)base2[512], d1 = (float)base2[513];
  union { f16 h[2]; unsigned u; } pk;
  pk.h[0] = (f16)fmaxf(fmaxf(a0, b0), fmaxf(c0, d0));
  pk.h[1] = (f16)fmaxf(fmaxf(a1, b1), fmaxf(c1, d1));
  *(unsigned*)(f1h + ((size_t)n * 100 + op) * 512 + c2 * 2) = pk.u;
  *(unsigned*)(scnh + ((size_t)n * 100 + op) * 1024 + c2 * 2) = pk.u;
}

__global__ void pool2_k(const f16* __restrict__ g2, f16* __restrict__ f2h) {
  int idx = blockIdx.x * 256 + threadIdx.x;
  if (idx >= 32 * 25 * 512) return;
  int c2 = idx & 511, rem = idx >> 9;
  int op = rem % 25, n = rem / 25;
  int py = op / 5, px = op - py * 5;
  const f16* base = g2 + (((size_t)n * 100 + (size_t)(2 * py) * 10 + 2 * px) * 1024) + c2 * 2;
  float a0 = (float)base[0],    a1 = (float)base[1];
  float b0 = (float)base[1024], b1 = (float)base[1025];
  const f16* base2 = base + 10 * 1024;
  float c0 = (float)base2[0],    c1 = (float)base2[1];
  float d0 = (float)base2[1024], d1 = (float)base2[1025];
  f16* o = f2h + ((size_t)n * 25 + op) * 1024 + c2 * 2;
  o[0] = (f16)fmaxf(fmaxf(a0, b0), fmaxf(c0, d0));
  o[1] = (f16)fmaxf(fmaxf(a1, b1), fmaxf(c1, d1));
}

// ======================= conv transpose 2x2 s2 (1024->512), MFMA v2 =======================
__global__ __launch_bounds__(256, 2) void convt_mfma_k(
    const f16* __restrict__ f2h, const f16* __restrict__ ctwf,
    const float* __restrict__ ctb, f16* __restrict__ scnh) {
  __shared__ f16 act[25 * 1048];           // 52,400 B
  int b = blockIdx.x;
  int ng = b & 15, n = b >> 4;
  int t = threadIdx.x, lane = t & 63, w = t >> 6;
  int quad = lane >> 4, l16 = lane & 15;
  for (int i = t; i < 25 * 128; i += 256) {
    int row = i >> 7, c8 = i & 127;
    *(half8*)(act + row * 1048 + c8 * 8) =
        *(const half8*)(f2h + ((size_t)n * 25 + row) * 1024 + c8 * 8);
  }
  __syncthreads();
  int r1 = 16 + (l16 > 8 ? 8 : l16);       // clamp: garbage rows never stored
  f32x4 acc[2][2] = {};
  const f16* wp0 = ctwf + ((size_t)((ng * 8 + w * 2 + 0) * 32) * 64 + lane) * 8;
  const f16* wp1 = ctwf + ((size_t)((ng * 8 + w * 2 + 1) * 32) * 64 + lane) * 8;
#pragma unroll 4
  for (int ks = 0; ks < 32; ++ks) {
    half8 a0 = *(const half8*)(act + l16 * 1048 + ks * 32 + quad * 8);
    half8 a1 = *(const half8*)(act + r1 * 1048 + ks * 32 + quad * 8);
    half8 b0 = *(const half8*)(wp0 + (size_t)ks * 512);
    half8 b1 = *(const half8*)(wp1 + (size_t)ks * 512);
    acc[0][0] = MFMA16(a0, b0, acc[0][0]);
    acc[1][0] = MFMA16(a1, b0, acc[1][0]);
    acc[0][1] = MFMA16(a0, b1, acc[0][1]);
    acc[1][1] = MFMA16(a1, b1, acc[1][1]);
  }
#pragma unroll
  for (int nt = 0; nt < 2; ++nt) {
    int np = ng * 128 + w * 32 + nt * 16 + l16;
    int p = np >> 9, co = np & 511;
    int a = p >> 1, bc = p & 1;
    float bb = ctb[co];
#pragma unroll
    for (int mt = 0; mt < 2; ++mt)
#pragma unroll
      for (int r = 0; r < 4; ++r) {
        int px = mt * 16 + quad * 4 + r;
        if (px < 25) {
          int ph = px / 5, pw = px - ph * 5;
          int opx = (2 * ph + a) * 10 + 2 * pw + bc;
          scnh[((size_t)n * 100 + opx) * 1024 + 512 + co] = (f16)(acc[mt][nt][r] + bb);
        }
      }
  }
}

// ======================= object SA: fused 4-layer MFMA + max =======================
__global__ __launch_bounds__(256) void sa_mfma_k(
    const float* __restrict__ oc, const float* __restrict__ ocm,
    const float* __restrict__ w1, const float* __restrict__ b1,
    const f16* __restrict__ w2h, const float* __restrict__ b2,
    const f16* __restrict__ w3h, const float* __restrict__ b3,
    const f16* __restrict__ w4h, const float* __restrict__ b4,
    float* __restrict__ obj) {
  __shared__ f16 act1[32 * 72];            // [pt][K=64]
  __shared__ f16 act2[32 * 136];           // [pt][K=128]
  __shared__ f16 act3[32 * 264];           // [pt][K=256]
  __shared__ float pcx[32], pcy[32];
  int b = blockIdx.x;                      // 2048 = 32 n * 64 chunks of 32 pts
  int n = b >> 6, pb = (b & 63) * 32;
  int t = threadIdx.x, lane = t & 63, w = t >> 6;
  int quad = lane >> 4, l16 = lane & 15;
  if (t < 32) {
    pcx[t] = oc[((size_t)n * OPP + pb + t) * 2 + 0] - ocm[n * 2 + 0];
    pcy[t] = oc[((size_t)n * OPP + pb + t) * 2 + 1] - ocm[n * 2 + 1];
  }
  __syncthreads();
  {                                        // layer1: 2 -> 64
    int c = t & 63, pg = t >> 6;
    float wx = w1[c * 2], wy = w1[c * 2 + 1], bb = b1[c];
#pragma unroll
    for (int j = 0; j < 8; ++j) {
      int p = pg * 8 + j;
      act1[p * 72 + c] = (f16)fmaxf(fmaf(wx, pcx[p], fmaf(wy, pcy[p], bb)), 0.0f);
    }
  }
  __syncthreads();
  {                                        // layer2: K=64, N=128
    int n0 = w * 32;
    f32x4 acc[2][2] = {};
#pragma unroll
    for (int ks = 0; ks < 2; ++ks) {
      half8 a0 = *(const half8*)(act1 + l16 * 72 + ks * 32 + quad * 8);
      half8 a1 = *(const half8*)(act1 + (16 + l16) * 72 + ks * 32 + quad * 8);
#pragma unroll
      for (int nt = 0; nt < 2; ++nt) {
        half8 bf = *(const half8*)(w2h + (size_t)(n0 + nt * 16 + l16) * 64 + ks * 32 + quad * 8);
        acc[0][nt] = MFMA16(a0, bf, acc[0][nt]);
        acc[1][nt] = MFMA16(a1, bf, acc[1][nt]);
      }
    }
#pragma unroll
    for (int nt = 0; nt < 2; ++nt) {
      int col = n0 + nt * 16 + l16;
      float bb = b2[col];
#pragma unroll
      for (int mt = 0; mt < 2; ++mt)
#pragma unroll
        for (int r = 0; r < 4; ++r)
          act2[(mt * 16 + quad * 4 + r) * 136 + col] = (f16)fmaxf(acc[mt][nt][r] + bb, 0.0f);
    }
  }
  __syncthreads();
  {                                        // layer3: K=128, N=256
    int n0 = w * 64;
    f32x4 acc[2][4] = {};
#pragma unroll
    for (int ks = 0; ks < 4; ++ks) {
      half8 a0 = *(const half8*)(act2 + l16 * 136 + ks * 32 + quad * 8);
      half8 a1 = *(const half8*)(act2 + (16 + l16) * 136 + ks * 32 + quad * 8);
#pragma unroll
      for (int nt = 0; nt < 4; ++nt) {
        half8 bf = *(const half8*)(w3h + (size_t)(n0 + nt * 16 + l16) * 128 + ks * 32 + quad * 8);
        acc[0][nt] = MFMA16(a0, bf, acc[0][nt]);
        acc[1][nt] = MFMA16(a1, bf, acc[1][nt]);
      }
    }
#pragma unroll
    for (int nt = 0; nt < 4; ++nt) {
      int col = n0 + nt * 16 + l16;
      float bb = b3[col];
#pragma unroll
      for (int mt = 0; mt < 2; ++mt)
#pragma unroll
        for (int r = 0; r < 4; ++r)
          act3[(mt * 16 + quad * 4 + r) * 264 + col] = (f16)fmaxf(acc[mt][nt][r] + bb, 0.0f);
    }
  }
  __syncthreads();
  {                                        // layer4: K=256, N=512; + max over points
    int n0 = w * 128;
    f32x4 acc[2][8] = {};
#pragma unroll
    for (int ks = 0; ks < 8; ++ks) {
      half8 a0 = *(const half8*)(act3 + l16 * 264 + ks * 32 + quad * 8);
      half8 a1 = *(const half8*)(act3 + (16 + l16) * 264 + ks * 32 + quad * 8);
#pragma unroll
      for (int nt = 0; nt < 8; ++nt) {
        half8 bf = *(const half8*)(w4h + (size_t)(n0 + nt * 16 + l16) * 256 + ks * 32 + quad * 8);
        acc[0][nt] = MFMA16(a0, bf, acc[0][nt]);
        acc[1][nt] = MFMA16(a1, bf, acc[1][nt]);
      }
    }
#pragma unroll
    for (int nt = 0; nt < 8; ++nt) {
      int col = n0 + nt * 16 + l16;
      float bb = b4[col];
      float v = 0.0f;
#pragma unroll
      for (int mt = 0; mt < 2; ++mt)
#pragma unroll
        for (int r = 0; r < 4; ++r)
          v = fmaxf(v, acc[mt][nt][r] + bb);
      v = fmaxf(v, 0.0f);
      v = fmaxf(v, __shfl_xor(v, 16));
      v = fmaxf(v, __shfl_xor(v, 32));
      if (quad == 0)
        atomicMax((int*)obj + (size_t)n * 512 + col, __float_as_int(v));
    }
  }
}

// ======================= classifier layer 1 (1538 -> 1024), MFMA =======================
__global__ __launch_bounds__(256) void cls1_mfma_k(
    const f16* __restrict__ scnh, const float* __restrict__ obj,
    const float* __restrict__ pos, const float* __restrict__ w1raw,
    const f16* __restrict__ w1h, const float* __restrict__ b1,
    f16* __restrict__ h1h) {
  __shared__ f16 act[112 * 72];
  __shared__ float objl[512];
  __shared__ float odl[128], wAl[128], wBl[128];
  int b = blockIdx.x;                      // 256 = 32 n * 8 octants
  int o8 = b & 7, n = b >> 3;
  int co0 = o8 * 128;
  int t = threadIdx.x, lane = t & 63, w = t >> 6;
  int quad = lane >> 4, l16 = lane & 15;
  objl[t] = obj[(size_t)n * 512 + t];
  objl[t + 256] = obj[(size_t)n * 512 + t + 256];
  __syncthreads();
  if (t < 128) {
    int co = co0 + t;
    const float* wr = w1raw + (size_t)co * 1538;
    float od = 0.0f;
    for (int k = 0; k < 512; ++k) od = fmaf(objl[k], wr[1024 + k], od);
    odl[t] = od + b1[co];
    wAl[t] = wr[1536]; wBl[t] = wr[1537];
  }
  __syncthreads();
  float posx = pos[n * 2 + 0], posy = pos[n * 2 + 1];
  f32x4 acc[7][2];
#pragma unroll
  for (int mt = 0; mt < 7; ++mt)
#pragma unroll
    for (int nt = 0; nt < 2; ++nt) {
      int cl = w * 32 + nt * 16 + l16;
      float od = odl[cl], wA = wAl[cl], wB = wBl[cl];
#pragma unroll
      for (int r = 0; r < 4; ++r) {
        int px = mt * 16 + quad * 4 + r;
        float relx = posx - (-0.5f + ((px / 10) + 0.5f) * 0.1f);
        float rely = posy - (-0.5f + ((px % 10) + 0.5f) * 0.1f);
        acc[mt][nt][r] = od + relx * wA + rely * wB;
      }
    }
  for (int kc = 0; kc < 16; ++kc) {
    int k0 = kc * 64;
    __syncthreads();
    for (int i = t; i < 896; i += 256) {
      int row = i >> 3, c8 = i & 7;
      half8 v = {};
      if (row < 100) v = *(const half8*)(scnh + ((size_t)n * 100 + row) * 1024 + k0 + c8 * 8);
      *(half8*)(act + row * 72 + c8 * 8) = v;
    }
    __syncthreads();
#pragma unroll
    for (int ks = 0; ks < 2; ++ks) {
      half8 bf0 = *(const half8*)(w1h + (size_t)(co0 + w * 32 + l16) * 1024 + k0 + ks * 32 + quad * 8);
      half8 bf1 = *(const half8*)(w1h + (size_t)(co0 + w * 32 + 16 + l16) * 1024 + k0 + ks * 32 + quad * 8);
#pragma unroll
      for (int mt = 0; mt < 7; ++mt) {
        half8 a = *(const half8*)(act + (mt * 16 + l16) * 72 + ks * 32 + quad * 8);
        acc[mt][0] = MFMA16(a, bf0, acc[mt][0]);
        acc[mt][1] = MFMA16(a, bf1, acc[mt][1]);
      }
    }
  }
#pragma unroll
  for (int mt = 0; mt < 7; ++mt)
#pragma unroll
    for (int nt = 0; nt < 2; ++nt) {
      int co = co0 + w * 32 + nt * 16 + l16;
#pragma unroll
      for (int r = 0; r < 4; ++r) {
        int px = mt * 16 + quad * 4 + r;
        if (px < 100)
          h1h[((size_t)n * 100 + px) * 1024 + co] = (f16)fmaxf(acc[mt][nt][r], 0.0f);
      }
    }
}

// ======================= classifier layer 2 (1024 -> 256), MFMA =======================
// Grid 128 = 32 n x 2 m-halves (50 px) x 2 co-groups (128). h2 out fp16.
__global__ __launch_bounds__(256) void cls2_mfma_k(
    const f16* __restrict__ h1h, const f16* __restrict__ w2h16,
    const float* __restrict__ b2, f16* __restrict__ h2h) {
  __shared__ f16 act[64 * 72];
  int b = blockIdx.x;
  int ng = b & 1, mh = (b >> 1) & 1, n = b >> 2;
  int co0 = ng * 128, p0 = mh * 50;
  int t = threadIdx.x, lane = t & 63, w = t >> 6;
  int quad = lane >> 4, l16 = lane & 15;
  f32x4 acc[4][2] = {};
  for (int kc = 0; kc < 16; ++kc) {
    int k0 = kc * 64;
    __syncthreads();
    for (int i = t; i < 512; i += 256) {
      int row = i >> 3, c8 = i & 7;                // rows 0..63
      int gr = p0 + (row < 50 ? row : 49);         // clamp; garbage rows never stored
      *(half8*)(act + row * 72 + c8 * 8) =
          *(const half8*)(h1h + ((size_t)n * 100 + gr) * 1024 + k0 + c8 * 8);
    }
    __syncthreads();
#pragma unroll
    for (int ks = 0; ks < 2; ++ks) {
      half8 bf0 = *(const half8*)(w2h16 + (size_t)(co0 + w * 32 + l16) * 1024 + k0 + ks * 32 + quad * 8);
      half8 bf1 = *(const half8*)(w2h16 + (size_t)(co0 + w * 32 + 16 + l16) * 1024 + k0 + ks * 32 + quad * 8);
#pragma unroll
      for (int mt = 0; mt < 4; ++mt) {
        half8 a = *(const half8*)(act + (mt * 16 + l16) * 72 + ks * 32 + quad * 8);
        acc[mt][0] = MFMA16(a, bf0, acc[mt][0]);
        acc[mt][1] = MFMA16(a, bf1, acc[mt][1]);
      }
    }
  }
#pragma unroll
  for (int mt = 0; mt < 4; ++mt)
#pragma unroll
    for (int nt = 0; nt < 2; ++nt) {
      int co = co0 + w * 32 + nt * 16 + l16;
      float bb = b2[co];
#pragma unroll
      for (int r = 0; r < 4; ++r) {
        int pl = mt * 16 + quad * 4 + r;
        if (pl < 50)
          h2h[((size_t)n * 100 + p0 + pl) * 256 + co] = (f16)fmaxf(acc[mt][nt][r] + bb, 0.0f);
      }
    }
}

// ======================= classifier layer 3 (256 -> 1) =======================
__global__ void cls3_k(const f16* __restrict__ h2h, const float* __restrict__ w3,
                       const float* __restrict__ b3, float* __restrict__ out) {
  int n = blockIdx.x, t = threadIdx.x;
  if (t < 100) {
    float acc = b3[0];
    const f16* hp = &h2h[((size_t)n * 100 + t) * 256];
    for (int k = 0; k < 256; ++k) acc = fmaf((float)hp[k], w3[k], acc);
    out[n * 100 + t] = acc;
  }
}

// ======================= launch =======================
extern "C" void kernel_launch(void* const* d_in, const int* in_sizes, int n_in,
                              void* d_out, int out_size, void* d_ws, size_t ws_size,
                              hipStream_t stream) {
  const float* sc      = (const float*)d_in[0];
  const float* oc      = (const float*)d_in[1];
  const float* pos     = (const float*)d_in[2];
  const float* mlp_w1  = (const float*)d_in[3];
  const float* mlp_b1  = (const float*)d_in[4];
  const float* mlp_w2  = (const float*)d_in[5];
  const float* mlp_b2  = (const float*)d_in[6];
  const float* conv1_w = (const float*)d_in[7];
  const float* conv1_b = (const float*)d_in[8];
  const float* conv2_w = (const float*)d_in[9];
  const float* conv2_b = (const float*)d_in[10];
  const float* convt_w = (const float*)d_in[11];
  const float* convt_b = (const float*)d_in[12];
  const float* sa_w1   = (const float*)d_in[13];
  const float* sa_b1   = (const float*)d_in[14];
  const float* sa_w2   = (const float*)d_in[15];
  const float* sa_b2   = (const float*)d_in[16];
  const float* sa_w3   = (const float*)d_in[17];
  const float* sa_b3   = (const float*)d_in[18];
  const float* sa_w4   = (const float*)d_in[19];
  const float* sa_b4   = (const float*)d_in[20];
  const float* cls_w1  = (const float*)d_in[21];
  const float* cls_b1  = (const float*)d_in[22];
  const float* cls_w2  = (const float*)d_in[23];
  const float* cls_b2  = (const float*)d_in[24];
  const float* cls_w3  = (const float*)d_in[25];
  const float* cls_b3  = (const float*)d_in[26];

  float* ws = (float*)d_ws;
  // ---- workspace layout (float units) ----
  f16*   w1h   = (f16*)ws;                         // 589,824 f
  f16*   w2h   = (f16*)(ws + 589824);              // 2,359,296 f (reused: h1h)
  f16*   mw2h  = (f16*)(ws + 2949120);             // 16,384 f
  f16*   saw2h = (f16*)(ws + 2965504);             // 4,096 f
  f16*   saw3h = (f16*)(ws + 2969600);             // 16,384 f
  f16*   saw4h = (f16*)(ws + 2985984);             // 65,536 f
  f16*   cw1h  = (f16*)(ws + 3051520);             // 524,288 f
  f16*   ctwh  = (f16*)(ws + 3575808);             // 1,048,576 f (B-frag layout)
  f16*   cw2h  = (f16*)(ws + 4624384);             // 131,072 f ([256][1024] fp16)
  float* big   = ws + 4886528;                     // 3,276,800 f (g1buf, g2buf)
  f16*   voxh  = (f16*)(ws + 8163328);             // 819,200 f (reused: f2h)
  f16*   f1h   = (f16*)(ws + 8982528);             // 819,200 f
  f16*   scnh  = (f16*)(ws + 9801728);             // 1,638,400 f (reused: h2h)
  float* obj   = ws + 11440128;                    // 16,384 f
  float* ocm   = ws + 11456512;                    // 64 f

  f16*   g1buf = (f16*)big;                        // conv1 out
  f16*   g2buf = (f16*)big;                        // conv2 out (g1buf dead after pool1)
  f16*   f2h   = voxh;                             // pool2 out (voxh dead after conv1)
  f16*   h1h   = w2h;                              // cls1 out (w2h dead after conv2)
  f16*   h2h   = scnh;                             // cls2 out (scnh dead after cls1)
  float* outp  = (float*)d_out;

  // ---- weight preps ----
  wprep2_k<512, 256><<<512, 256, 0, stream>>>(conv1_w, w1h);
  wprep2_k<1024, 512><<<1024, 256, 0, stream>>>(conv2_w, w2h);
  cvt16_k<<<32, 256, 0, stream>>>(mlp_w2, mw2h, 8192);
  cvt16_k<<<8, 256, 0, stream>>>(sa_w2, saw2h, 2048);
  cvt16_k<<<32, 256, 0, stream>>>(sa_w3, saw3h, 8192);
  cvt16_k<<<128, 256, 0, stream>>>(sa_w4, saw4h, 32768);
  cw1prep_k<<<4096, 256, 0, stream>>>(cls_w1, cw1h);
  ctprep_k<<<8192, 256, 0, stream>>>(convt_w, ctwh);
  cvt16_k<<<256, 256, 0, stream>>>(cls_w2, cw2h, 65536);

  hipMemsetAsync(obj, 0, (size_t)16384 * 4, stream);
  ocmean_k<<<32, 256, 0, stream>>>(oc, ocm);

  pointnet_lds_k<<<256, 256, 0, stream>>>(sc, mlp_w1, mlp_b1, mw2h, mlp_b2, voxh);

  convmfma_k<20, 20, 256, 512, 4><<<512, 256, (7 * 22 + 384) * 80, stream>>>(
      voxh, w1h, conv1_b, g1buf);
  pool1_k<<<3200, 256, 0, stream>>>(g1buf, f1h, scnh);
  convmfma_k<10, 10, 512, 1024, 2><<<512, 256, (7 * 12 + 384) * 80, stream>>>(
      f1h, w2h, conv2_b, g2buf);
  pool2_k<<<1600, 256, 0, stream>>>(g2buf, f2h);
  convt_mfma_k<<<512, 256, 0, stream>>>(f2h, ctwh, convt_b, scnh);

  sa_mfma_k<<<2048, 256, 0, stream>>>(oc, ocm, sa_w1, sa_b1, saw2h, sa_b2,
                                      saw3h, sa_b3, saw4h, sa_b4, obj);

  cls1_mfma_k<<<256, 256, 0, stream>>>(scnh, obj, pos, cls_w1, cw1h, cls_b1, h1h);
  cls2_mfma_k<<<128, 256, 0, stream>>>(h1h, cw2h, cls_b2, h2h);
  cls3_k<<<32, 128, 0, stream>>>(h2h, cls_w3, cls_b3, outp);
}

// Round 9
// 570.305 us; speedup vs baseline: 1.8299x; 1.0730x over previous
//
#include <hip/hip_runtime.h>

#define NB 32
#define PP 8192
#define OPP 2048

typedef _Float16 f16;
typedef f16 half8 __attribute__((ext_vector_type(8)));
typedef f16 half4 __attribute__((ext_vector_type(4)));
typedef float f32x4 __attribute__((ext_vector_type(4)));

#define MFMA16(a, b, c) __builtin_amdgcn_mfma_f32_16x16x32_f16(a, b, c, 0, 0, 0)

// ======= conv weight prep: [co][ci][3][3] fp32 -> MFMA B-fragment order fp16 =======
// wf[(((cic*9 + kk)*(CO/16) + nb)*64 + quad*16 + l16)*8 + j] = w[nb*16+l16][cic*32+quad*8+j][kk]
template <int CO, int CI>
__global__ __launch_bounds__(256) void wfragprep_k(const float* __restrict__ wsrc,
                                                   f16* __restrict__ wf) {
  __shared__ float tile[CI * 9];
  int co = blockIdx.x, t = threadIdx.x;
  const float* src = wsrc + (size_t)co * CI * 9;
  for (int i = t; i < CI * 9; i += 256) tile[i] = src[i];
  __syncthreads();
  constexpr int NBB = CO / 16;
  int nb = co >> 4, l16 = co & 15;
  for (int e = t; e < (CI / 32) * 9 * 4; e += 256) {
    int quad = e & 3;
    int kk = (e >> 2) % 9;
    int cic = e / 36;
    half8 v;
#pragma unroll
    for (int j = 0; j < 8; ++j) {
      int ci = cic * 32 + quad * 8 + j;
      v[j] = (f16)tile[ci * 9 + kk];
    }
    *(half8*)(wf + ((((size_t)cic * 9 + kk) * NBB + nb) * 64 + quad * 16 + l16) * 8) = v;
  }
}

__global__ void cvt16_k(const float* __restrict__ in, f16* __restrict__ out, int n4) {
  int idx = blockIdx.x * 256 + threadIdx.x;
  if (idx >= n4) return;
  float4 v = ((const float4*)in)[idx];
  half4 h; h.x = (f16)v.x; h.y = (f16)v.y; h.z = (f16)v.z; h.w = (f16)v.w;
  ((half4*)out)[idx] = h;
}

// cls_w1 scene part [1024][1538] -> [1024][1024] fp16
__global__ void cw1prep_k(const float* __restrict__ w, f16* __restrict__ out) {
  int idx = blockIdx.x * 256 + threadIdx.x;
  if (idx >= 1024 * 1024) return;
  int co = idx >> 10, k = idx & 1023;
  out[idx] = (f16)w[(size_t)co * 1538 + k];
}

// convt_w [o][i][a'][b'] -> MFMA B-fragment layout
__global__ void ctprep_k(const float* __restrict__ w, f16* __restrict__ out) {
  int idx = blockIdx.x * 256 + threadIdx.x;
  if (idx >= 2048 * 1024) return;
  int j = idx & 7, l = (idx >> 3) & 63, kb = (idx >> 9) & 31, nb = idx >> 14;
  int n16 = l & 15, quad = l >> 4;
  int np = nb * 16 + n16;
  int k = kb * 32 + quad * 8 + j;
  int p = np >> 9, o = np & 511;
  out[idx] = (f16)w[((size_t)o * 1024 + k) * 4 + (3 - p)];
}

// ======================= object-cloud mean =======================
__global__ void ocmean_k(const float* __restrict__ oc, float* __restrict__ ocm) {
  int n = blockIdx.x, t = threadIdx.x;
  __shared__ float sx[256], sy[256];
  float ax = 0.f, ay = 0.f;
  for (int p = t; p < OPP; p += 256) {
    ax += oc[((size_t)n * OPP + p) * 2 + 0];
    ay += oc[((size_t)n * OPP + p) * 2 + 1];
  }
  sx[t] = ax; sy[t] = ay;
  __syncthreads();
  for (int s = 128; s > 0; s >>= 1) {
    if (t < s) { sx[t] += sx[t + s]; sy[t] += sy[t + s]; }
    __syncthreads();
  }
  if (t == 0) {
    ocm[n * 2 + 0] = sx[0] / (float)OPP;
    ocm[n * 2 + 1] = sy[0] / (float)OPP;
  }
}

// ======================= voxel PointNet: barrier-free LDS scatter-max =======================
__global__ __launch_bounds__(256) void pointnet_lds_k(
    const float* __restrict__ sc, const float* __restrict__ w1, const float* __restrict__ b1,
    const f16* __restrict__ w2h, const float* __restrict__ b2, f16* __restrict__ voxh) {
  __shared__ float voxl[400 * 33];         // 52,800 B
  __shared__ int binl[64];                 // wave-local bin broadcast
  int t = threadIdx.x, lane = t & 63, w = t >> 6;
  int quad = lane >> 4, l16 = lane & 15;
  int b = blockIdx.x;
  int cg = b & 7, n = b >> 3;
  float w1x[32], w1y[32], b1v[32];
#pragma unroll
  for (int ks = 0; ks < 4; ++ks)
#pragma unroll
    for (int j = 0; j < 8; ++j) {
      int k = ks * 32 + quad * 8 + j;
      w1x[ks * 8 + j] = w1[k * 2];
      w1y[ks * 8 + j] = w1[k * 2 + 1];
      b1v[ks * 8 + j] = b1[k];
    }
  half8 bf[2][4];
  float bias[2];
#pragma unroll
  for (int nt = 0; nt < 2; ++nt) {
    int ch = cg * 32 + nt * 16 + l16;
    bias[nt] = b2[ch];
#pragma unroll
    for (int ks = 0; ks < 4; ++ks)
      bf[nt][ks] = *(const half8*)(w2h + (size_t)ch * 128 + ks * 32 + quad * 8);
  }
  for (int i = t; i < 400 * 33; i += 256) voxl[i] = 0.0f;
  __syncthreads();
  const float* scp = sc + (size_t)n * PP * 2;
  int p0 = w * 16 + l16;
  float2 xy = *(const float2*)(scp + p0 * 2);
  for (int it = 0; it < 128; ++it) {
    float x = xy.x, y = xy.y;
    if (it < 127) xy = *(const float2*)(scp + ((it + 1) * 64 + p0) * 2);
    float bif = fminf(fmaxf(ceilf((x + 0.5f) * 20.0f) - 1.0f, 0.0f), 19.0f);
    float bjf = fminf(fmaxf(ceilf((y + 0.5f) * 20.0f) - 1.0f, 0.0f), 19.0f);
    bool valid = (x > -0.5f) && (x <= 0.5f) && (y > -0.5f) && (y <= 0.5f);
    float px = x - (-0.5f + (bif + 0.5f) * 0.05f);
    float py = y - (-0.5f + (bjf + 0.5f) * 0.05f);
    int bn = valid ? ((int)bif * 20 + (int)bjf) : -1;
    if (quad == 0) binl[w * 16 + l16] = bn;
    f32x4 acc0 = {}, acc1 = {};
#pragma unroll
    for (int ks = 0; ks < 4; ++ks) {
      half8 af;
#pragma unroll
      for (int j = 0; j < 8; ++j)
        af[j] = (f16)fmaxf(fmaf(w1x[ks * 8 + j], px, fmaf(w1y[ks * 8 + j], py, b1v[ks * 8 + j])), 0.0f);
      acc0 = MFMA16(af, bf[0][ks], acc0);
      acc1 = MFMA16(af, bf[1][ks], acc1);
    }
#pragma unroll
    for (int r = 0; r < 4; ++r) {
      int bn2 = binl[w * 16 + quad * 4 + r];
      if (bn2 >= 0) {
        float v0 = fmaxf(acc0[r] + bias[0], 0.0f);
        float v1 = fmaxf(acc1[r] + bias[1], 0.0f);
        atomicMax((int*)voxl + bn2 * 33 + l16, __float_as_int(v0));
        atomicMax((int*)voxl + bn2 * 33 + 16 + l16, __float_as_int(v1));
      }
    }
  }
  __syncthreads();
  for (int i = t; i < 400 * 16; i += 256) {
    int bin = i >> 4, cp = i & 15;
    union { f16 h[2]; unsigned u; } pk;
    pk.h[0] = (f16)voxl[bin * 33 + cp * 2];
    pk.h[1] = (f16)voxl[bin * 33 + cp * 2 + 1];
    *(unsigned*)(voxh + ((size_t)n * 400 + bin) * 256 + cg * 32 + cp * 2) = pk.u;
  }
}

// ======================= MFMA implicit-GEMM conv 3x3 pad1 + relu =======================
// B weights read directly from global in fragment order (no LDS stage, no B barriers).
template <int H, int W, int CI, int CO, int MSPLIT>
__global__ __launch_bounds__(256, 2) void convmfma_k(
    const f16* __restrict__ inh, const f16* __restrict__ wf,
    const float* __restrict__ bias, f16* __restrict__ outh) {
  constexpr int HS = H / MSPLIT;
  constexpr int Mpix = HS * W;
  constexpr int MT = (Mpix + 15) / 16;
  constexpr int PR = HS + 2, PC = W + 2;
  constexpr int NCIC = CI / 32;
  constexpr int COG = CO / 128;
  constexpr int NBB = CO / 16;
  extern __shared__ char smem[];
  f16* Ap = (f16*)smem;                          // [PR*PC][40]
  int b = blockIdx.x;
  int cog = b % COG;
  int ms = (b / COG) % MSPLIT;
  int n = b / (COG * MSPLIT);
  int co0 = cog * 128;
  int r0 = ms * HS;
  int t = threadIdx.x, lane = t & 63, w = t >> 6;
  int quad = lane >> 4, l16 = lane & 15;
  int nb0 = cog * 8 + w * 2;                     // B-fragment row-block (16 co each)

  int abase[MT];
#pragma unroll
  for (int mi = 0; mi < MT; ++mi) {
    int pl = mi * 16 + l16; if (pl > Mpix - 1) pl = Mpix - 1;
    int y = pl / W, x = pl - y * W;
    abase[mi] = (y * PC + x) * 40 + quad * 8;    // halves
  }
  f32x4 acc[MT][2] = {};

  const f16* inbase = inh + (size_t)n * H * W * CI;

  for (int cic = 0; cic < NCIC; ++cic) {
    __syncthreads();                             // protect Ap from prior reads
    for (int cell = t; cell < PR * PC; cell += 256) {
      int pr = cell / PC, pc = cell - pr * PC;
      int yin = r0 - 1 + pr, xin = pc - 1;
      uint4 d0 = {0,0,0,0}, d1 = {0,0,0,0}, d2 = {0,0,0,0}, d3 = {0,0,0,0};
      if (yin >= 0 && yin < H && xin >= 0 && xin < W) {
        const uint4* src = (const uint4*)(inbase + ((size_t)yin * W + xin) * CI + cic * 32);
        d0 = src[0]; d1 = src[1]; d2 = src[2]; d3 = src[3];
      }
      uint4* dst = (uint4*)(Ap + cell * 40);
      dst[0] = d0; dst[1] = d1; dst[2] = d2; dst[3] = d3;
    }
    __syncthreads();
    const f16* wfc = wf + (size_t)(cic * 9) * NBB * 512;
#pragma unroll
    for (int ky = 0; ky < 3; ++ky)
#pragma unroll
      for (int kx = 0; kx < 3; ++kx) {
        int kk = ky * 3 + kx;
        half8 bf0 = *(const half8*)(wfc + ((size_t)(kk * NBB + nb0) * 64 + lane) * 8);
        half8 bf1 = *(const half8*)(wfc + ((size_t)(kk * NBB + nb0 + 1) * 64 + lane) * 8);
        int shift = (ky * PC + kx) * 40;
#pragma unroll
        for (int mi = 0; mi < MT; ++mi) {
          half8 af = *(const half8*)(Ap + abase[mi] + shift);
          acc[mi][0] = MFMA16(af, bf0, acc[mi][0]);
          acc[mi][1] = MFMA16(af, bf1, acc[mi][1]);
        }
      }
  }
  int co_w = co0 + w * 32;
  float bv0 = bias[co_w + l16];
  float bv1 = bias[co_w + 16 + l16];
  f16* ob = outh + ((size_t)n * H * W + (size_t)ms * Mpix) * CO;
#pragma unroll
  for (int mi = 0; mi < MT; ++mi) {
#pragma unroll
    for (int r = 0; r < 4; ++r) {
      int p = mi * 16 + quad * 4 + r;
      if (p < Mpix) {
        float v0 = acc[mi][0][r] + bv0; v0 = v0 > 0.f ? v0 : 0.f;
        float v1 = acc[mi][1][r] + bv1; v1 = v1 > 0.f ? v1 : 0.f;
        ob[(size_t)p * CO + co_w + l16] = (f16)v0;
        ob[(size_t)p * CO + co_w + 16 + l16] = (f16)v1;
      }
    }
  }
}

// ======================= maxpool 2x2 (+ fused pack into scene buffer) =======================
__global__ void pool1_k(const f16* __restrict__ g1, f16* __restrict__ f1h,
                        f16* __restrict__ scnh) {
  int idx = blockIdx.x * 256 + threadIdx.x;
  if (idx >= 32 * 100 * 256) return;
  int c2 = idx & 255, rem = idx >> 8;
  int op = rem % 100, n = rem / 100;
  int py = op / 10, px = op - py * 10;
  const f16* base = g1 + (((size_t)n * 400 + (size_t)(2 * py) * 20 + 2 * px) * 512) + c2 * 2;
  float a0 = (float)base[0],   a1 = (float)base[1];
  float b0 = (float)base[512], b1 = (float)base[513];
  const f16* base2 = base + 20 * 512;
  float c0 = (float)base2[0],   c1 = (float)base2[1];
  float d0 = (float)base2[512], d1 = (float)base2[513];
  union { f16 h[2]; unsigned u; } pk;
  pk.h[0] = (f16)fmaxf(fmaxf(a0, b0), fmaxf(c0, d0));
  pk.h[1] = (f16)fmaxf(fmaxf(a1, b1), fmaxf(c1, d1));
  *(unsigned*)(f1h + ((size_t)n * 100 + op) * 512 + c2 * 2) = pk.u;
  *(unsigned*)(scnh + ((size_t)n * 100 + op) * 1024 + c2 * 2) = pk.u;
}

__global__ void pool2_k(const f16* __restrict__ g2, f16* __restrict__ f2h) {
  int idx = blockIdx.x * 256 + threadIdx.x;
  if (idx >= 32 * 25 * 512) return;
  int c2 = idx & 511, rem = idx >> 9;
  int op = rem % 25, n = rem / 25;
  int py = op / 5, px = op - py * 5;
  const f16* base = g2 + (((size_t)n * 100 + (size_t)(2 * py) * 10 + 2 * px) * 1024) + c2 * 2;
  float a0 = (float)base[0],    a1 = (float)base[1];
  float b0 = (float)base[1024], b1 = (float)base[1025];
  const f16* base2 = base + 10 * 1024;
  float c0 = (float)base2[0],    c1 = (float)base2[1];
  float d0 = (float)base2[1024], d1 = (float)base2[1025];
  f16* o = f2h + ((size_t)n * 25 + op) * 1024 + c2 * 2;
  o[0] = (f16)fmaxf(fmaxf(a0, b0), fmaxf(c0, d0));
  o[1] = (f16)fmaxf(fmaxf(a1, b1), fmaxf(c1, d1));
}

// ======================= conv transpose 2x2 s2 (1024->512), MFMA v2 =======================
__global__ __launch_bounds__(256, 2) void convt_mfma_k(
    const f16* __restrict__ f2h, const f16* __restrict__ ctwf,
    const float* __restrict__ ctb, f16* __restrict__ scnh) {
  __shared__ f16 act[25 * 1048];           // 52,400 B
  int b = blockIdx.x;
  int ng = b & 15, n = b >> 4;
  int t = threadIdx.x, lane = t & 63, w = t >> 6;
  int quad = lane >> 4, l16 = lane & 15;
  for (int i = t; i < 25 * 128; i += 256) {
    int row = i >> 7, c8 = i & 127;
    *(half8*)(act + row * 1048 + c8 * 8) =
        *(const half8*)(f2h + ((size_t)n * 25 + row) * 1024 + c8 * 8);
  }
  __syncthreads();
  int r1 = 16 + (l16 > 8 ? 8 : l16);       // clamp: garbage rows never stored
  f32x4 acc[2][2] = {};
  const f16* wp0 = ctwf + ((size_t)((ng * 8 + w * 2 + 0) * 32) * 64 + lane) * 8;
  const f16* wp1 = ctwf + ((size_t)((ng * 8 + w * 2 + 1) * 32) * 64 + lane) * 8;
#pragma unroll 4
  for (int ks = 0; ks < 32; ++ks) {
    half8 a0 = *(const half8*)(act + l16 * 1048 + ks * 32 + quad * 8);
    half8 a1 = *(const half8*)(act + r1 * 1048 + ks * 32 + quad * 8);
    half8 b0 = *(const half8*)(wp0 + (size_t)ks * 512);
    half8 b1 = *(const half8*)(wp1 + (size_t)ks * 512);
    acc[0][0] = MFMA16(a0, b0, acc[0][0]);
    acc[1][0] = MFMA16(a1, b0, acc[1][0]);
    acc[0][1] = MFMA16(a0, b1, acc[0][1]);
    acc[1][1] = MFMA16(a1, b1, acc[1][1]);
  }
#pragma unroll
  for (int nt = 0; nt < 2; ++nt) {
    int np = ng * 128 + w * 32 + nt * 16 + l16;
    int p = np >> 9, co = np & 511;
    int a = p >> 1, bc = p & 1;
    float bb = ctb[co];
#pragma unroll
    for (int mt = 0; mt < 2; ++mt)
#pragma unroll
      for (int r = 0; r < 4; ++r) {
        int px = mt * 16 + quad * 4 + r;
        if (px < 25) {
          int ph = px / 5, pw = px - ph * 5;
          int opx = (2 * ph + a) * 10 + 2 * pw + bc;
          scnh[((size_t)n * 100 + opx) * 1024 + 512 + co] = (f16)(acc[mt][nt][r] + bb);
        }
      }
  }
}

// ======================= object SA: fused 4-layer MFMA + max =======================
__global__ __launch_bounds__(256) void sa_mfma_k(
    const float* __restrict__ oc, const float* __restrict__ ocm,
    const float* __restrict__ w1, const float* __restrict__ b1,
    const f16* __restrict__ w2h, const float* __restrict__ b2,
    const f16* __restrict__ w3h, const float* __restrict__ b3,
    const f16* __restrict__ w4h, const float* __restrict__ b4,
    float* __restrict__ obj) {
  __shared__ f16 act1[32 * 72];            // [pt][K=64]
  __shared__ f16 act2[32 * 136];           // [pt][K=128]
  __shared__ f16 act3[32 * 264];           // [pt][K=256]
  __shared__ float pcx[32], pcy[32];
  int b = blockIdx.x;                      // 2048 = 32 n * 64 chunks of 32 pts
  int n = b >> 6, pb = (b & 63) * 32;
  int t = threadIdx.x, lane = t & 63, w = t >> 6;
  int quad = lane >> 4, l16 = lane & 15;
  if (t < 32) {
    pcx[t] = oc[((size_t)n * OPP + pb + t) * 2 + 0] - ocm[n * 2 + 0];
    pcy[t] = oc[((size_t)n * OPP + pb + t) * 2 + 1] - ocm[n * 2 + 1];
  }
  __syncthreads();
  {                                        // layer1: 2 -> 64
    int c = t & 63, pg = t >> 6;
    float wx = w1[c * 2], wy = w1[c * 2 + 1], bb = b1[c];
#pragma unroll
    for (int j = 0; j < 8; ++j) {
      int p = pg * 8 + j;
      act1[p * 72 + c] = (f16)fmaxf(fmaf(wx, pcx[p], fmaf(wy, pcy[p], bb)), 0.0f);
    }
  }
  __syncthreads();
  {                                        // layer2: K=64, N=128
    int n0 = w * 32;
    f32x4 acc[2][2] = {};
#pragma unroll
    for (int ks = 0; ks < 2; ++ks) {
      half8 a0 = *(const half8*)(act1 + l16 * 72 + ks * 32 + quad * 8);
      half8 a1 = *(const half8*)(act1 + (16 + l16) * 72 + ks * 32 + quad * 8);
#pragma unroll
      for (int nt = 0; nt < 2; ++nt) {
        half8 bf = *(const half8*)(w2h + (size_t)(n0 + nt * 16 + l16) * 64 + ks * 32 + quad * 8);
        acc[0][nt] = MFMA16(a0, bf, acc[0][nt]);
        acc[1][nt] = MFMA16(a1, bf, acc[1][nt]);
      }
    }
#pragma unroll
    for (int nt = 0; nt < 2; ++nt) {
      int col = n0 + nt * 16 + l16;
      float bb = b2[col];
#pragma unroll
      for (int mt = 0; mt < 2; ++mt)
#pragma unroll
        for (int r = 0; r < 4; ++r)
          act2[(mt * 16 + quad * 4 + r) * 136 + col] = (f16)fmaxf(acc[mt][nt][r] + bb, 0.0f);
    }
  }
  __syncthreads();
  {                                        // layer3: K=128, N=256
    int n0 = w * 64;
    f32x4 acc[2][4] = {};
#pragma unroll
    for (int ks = 0; ks < 4; ++ks) {
      half8 a0 = *(const half8*)(act2 + l16 * 136 + ks * 32 + quad * 8);
      half8 a1 = *(const half8*)(act2 + (16 + l16) * 136 + ks * 32 + quad * 8);
#pragma unroll
      for (int nt = 0; nt < 4; ++nt) {
        half8 bf = *(const half8*)(w3h + (size_t)(n0 + nt * 16 + l16) * 128 + ks * 32 + quad * 8);
        acc[0][nt] = MFMA16(a0, bf, acc[0][nt]);
        acc[1][nt] = MFMA16(a1, bf, acc[1][nt]);
      }
    }
#pragma unroll
    for (int nt = 0; nt < 4; ++nt) {
      int col = n0 + nt * 16 + l16;
      float bb = b3[col];
#pragma unroll
      for (int mt = 0; mt < 2; ++mt)
#pragma unroll
        for (int r = 0; r < 4; ++r)
          act3[(mt * 16 + quad * 4 + r) * 264 + col] = (f16)fmaxf(acc[mt][nt][r] + bb, 0.0f);
    }
  }
  __syncthreads();
  {                                        // layer4: K=256, N=512; + max over points
    int n0 = w * 128;
    f32x4 acc[2][8] = {};
#pragma unroll
    for (int ks = 0; ks < 8; ++ks) {
      half8 a0 = *(const half8*)(act3 + l16 * 264 + ks * 32 + quad * 8);
      half8 a1 = *(const half8*)(act3 + (16 + l16) * 264 + ks * 32 + quad * 8);
#pragma unroll
      for (int nt = 0; nt < 8; ++nt) {
        half8 bf = *(const half8*)(w4h + (size_t)(n0 + nt * 16 + l16) * 256 + ks * 32 + quad * 8);
        acc[0][nt] = MFMA16(a0, bf, acc[0][nt]);
        acc[1][nt] = MFMA16(a1, bf, acc[1][nt]);
      }
    }
#pragma unroll
    for (int nt = 0; nt < 8; ++nt) {
      int col = n0 + nt * 16 + l16;
      float bb = b4[col];
      float v = 0.0f;
#pragma unroll
      for (int mt = 0; mt < 2; ++mt)
#pragma unroll
        for (int r = 0; r < 4; ++r)
          v = fmaxf(v, acc[mt][nt][r] + bb);
      v = fmaxf(v, 0.0f);
      v = fmaxf(v, __shfl_xor(v, 16));
      v = fmaxf(v, __shfl_xor(v, 32));
      if (quad == 0)
        atomicMax((int*)obj + (size_t)n * 512 + col, __float_as_int(v));
    }
  }
}

// ======================= classifier layer 1 (1538 -> 1024), MFMA =======================
__global__ __launch_bounds__(256) void cls1_mfma_k(
    const f16* __restrict__ scnh, const float* __restrict__ obj,
    const float* __restrict__ pos, const float* __restrict__ w1raw,
    const f16* __restrict__ w1h, const float* __restrict__ b1,
    f16* __restrict__ h1h) {
  __shared__ f16 act[112 * 72];
  __shared__ float objl[512];
  __shared__ float odl[128], wAl[128], wBl[128];
  int b = blockIdx.x;                      // 256 = 32 n * 8 octants
  int o8 = b & 7, n = b >> 3;
  int co0 = o8 * 128;
  int t = threadIdx.x, lane = t & 63, w = t >> 6;
  int quad = lane >> 4, l16 = lane & 15;
  objl[t] = obj[(size_t)n * 512 + t];
  objl[t + 256] = obj[(size_t)n * 512 + t + 256];
  __syncthreads();
  if (t < 128) {
    int co = co0 + t;
    const float* wr = w1raw + (size_t)co * 1538;
    float od = 0.0f;
    for (int k = 0; k < 512; ++k) od = fmaf(objl[k], wr[1024 + k], od);
    odl[t] = od + b1[co];
    wAl[t] = wr[1536]; wBl[t] = wr[1537];
  }
  __syncthreads();
  float posx = pos[n * 2 + 0], posy = pos[n * 2 + 1];
  f32x4 acc[7][2];
#pragma unroll
  for (int mt = 0; mt < 7; ++mt)
#pragma unroll
    for (int nt = 0; nt < 2; ++nt) {
      int cl = w * 32 + nt * 16 + l16;
      float od = odl[cl], wA = wAl[cl], wB = wBl[cl];
#pragma unroll
      for (int r = 0; r < 4; ++r) {
        int px = mt * 16 + quad * 4 + r;
        float relx = posx - (-0.5f + ((px / 10) + 0.5f) * 0.1f);
        float rely = posy - (-0.5f + ((px % 10) + 0.5f) * 0.1f);
        acc[mt][nt][r] = od + relx * wA + rely * wB;
      }
    }
  for (int kc = 0; kc < 16; ++kc) {
    int k0 = kc * 64;
    __syncthreads();
    for (int i = t; i < 896; i += 256) {
      int row = i >> 3, c8 = i & 7;
      half8 v = {};
      if (row < 100) v = *(const half8*)(scnh + ((size_t)n * 100 + row) * 1024 + k0 + c8 * 8);
      *(half8*)(act + row * 72 + c8 * 8) = v;
    }
    __syncthreads();
#pragma unroll
    for (int ks = 0; ks < 2; ++ks) {
      half8 bf0 = *(const half8*)(w1h + (size_t)(co0 + w * 32 + l16) * 1024 + k0 + ks * 32 + quad * 8);
      half8 bf1 = *(const half8*)(w1h + (size_t)(co0 + w * 32 + 16 + l16) * 1024 + k0 + ks * 32 + quad * 8);
#pragma unroll
      for (int mt = 0; mt < 7; ++mt) {
        half8 a = *(const half8*)(act + (mt * 16 + l16) * 72 + ks * 32 + quad * 8);
        acc[mt][0] = MFMA16(a, bf0, acc[mt][0]);
        acc[mt][1] = MFMA16(a, bf1, acc[mt][1]);
      }
    }
  }
#pragma unroll
  for (int mt = 0; mt < 7; ++mt)
#pragma unroll
    for (int nt = 0; nt < 2; ++nt) {
      int co = co0 + w * 32 + nt * 16 + l16;
#pragma unroll
      for (int r = 0; r < 4; ++r) {
        int px = mt * 16 + quad * 4 + r;
        if (px < 100)
          h1h[((size_t)n * 100 + px) * 1024 + co] = (f16)fmaxf(acc[mt][nt][r], 0.0f);
      }
    }
}

// ======================= classifier layer 2 (1024 -> 256), MFMA =======================
__global__ __launch_bounds__(256) void cls2_mfma_k(
    const f16* __restrict__ h1h, const f16* __restrict__ w2h16,
    const float* __restrict__ b2, f16* __restrict__ h2h) {
  __shared__ f16 act[64 * 72];
  int b = blockIdx.x;
  int ng = b & 1, mh = (b >> 1) & 1, n = b >> 2;
  int co0 = ng * 128, p0 = mh * 50;
  int t = threadIdx.x, lane = t & 63, w = t >> 6;
  int quad = lane >> 4, l16 = lane & 15;
  f32x4 acc[4][2] = {};
  for (int kc = 0; kc < 16; ++kc) {
    int k0 = kc * 64;
    __syncthreads();
    for (int i = t; i < 512; i += 256) {
      int row = i >> 3, c8 = i & 7;                // rows 0..63
      int gr = p0 + (row < 50 ? row : 49);         // clamp; garbage rows never stored
      *(half8*)(act + row * 72 + c8 * 8) =
          *(const half8*)(h1h + ((size_t)n * 100 + gr) * 1024 + k0 + c8 * 8);
    }
    __syncthreads();
#pragma unroll
    for (int ks = 0; ks < 2; ++ks) {
      half8 bf0 = *(const half8*)(w2h16 + (size_t)(co0 + w * 32 + l16) * 1024 + k0 + ks * 32 + quad * 8);
      half8 bf1 = *(const half8*)(w2h16 + (size_t)(co0 + w * 32 + 16 + l16) * 1024 + k0 + ks * 32 + quad * 8);
#pragma unroll
      for (int mt = 0; mt < 4; ++mt) {
        half8 a = *(const half8*)(act + (mt * 16 + l16) * 72 + ks * 32 + quad * 8);
        acc[mt][0] = MFMA16(a, bf0, acc[mt][0]);
        acc[mt][1] = MFMA16(a, bf1, acc[mt][1]);
      }
    }
  }
#pragma unroll
  for (int mt = 0; mt < 4; ++mt)
#pragma unroll
    for (int nt = 0; nt < 2; ++nt) {
      int co = co0 + w * 32 + nt * 16 + l16;
      float bb = b2[co];
#pragma unroll
      for (int r = 0; r < 4; ++r) {
        int pl = mt * 16 + quad * 4 + r;
        if (pl < 50)
          h2h[((size_t)n * 100 + p0 + pl) * 256 + co] = (f16)fmaxf(acc[mt][nt][r] + bb, 0.0f);
      }
    }
}

// ======================= classifier layer 3 (256 -> 1) =======================
__global__ void cls3_k(const f16* __restrict__ h2h, const float* __restrict__ w3,
                       const float* __restrict__ b3, float* __restrict__ out) {
  int n = blockIdx.x, t = threadIdx.x;
  if (t < 100) {
    float acc = b3[0];
    const f16* hp = &h2h[((size_t)n * 100 + t) * 256];
    for (int k = 0; k < 256; ++k) acc = fmaf((float)hp[k], w3[k], acc);
    out[n * 100 + t] = acc;
  }
}

// ======================= launch =======================
extern "C" void kernel_launch(void* const* d_in, const int* in_sizes, int n_in,
                              void* d_out, int out_size, void* d_ws, size_t ws_size,
                              hipStream_t stream) {
  const float* sc      = (const float*)d_in[0];
  const float* oc      = (const float*)d_in[1];
  const float* pos     = (const float*)d_in[2];
  const float* mlp_w1  = (const float*)d_in[3];
  const float* mlp_b1  = (const float*)d_in[4];
  const float* mlp_w2  = (const float*)d_in[5];
  const float* mlp_b2  = (const float*)d_in[6];
  const float* conv1_w = (const float*)d_in[7];
  const float* conv1_b = (const float*)d_in[8];
  const float* conv2_w = (const float*)d_in[9];
  const float* conv2_b = (const float*)d_in[10];
  const float* convt_w = (const float*)d_in[11];
  const float* convt_b = (const float*)d_in[12];
  const float* sa_w1   = (const float*)d_in[13];
  const float* sa_b1   = (const float*)d_in[14];
  const float* sa_w2   = (const float*)d_in[15];
  const float* sa_b2   = (const float*)d_in[16];
  const float* sa_w3   = (const float*)d_in[17];
  const float* sa_b3   = (const float*)d_in[18];
  const float* sa_w4   = (const float*)d_in[19];
  const float* sa_b4   = (const float*)d_in[20];
  const float* cls_w1  = (const float*)d_in[21];
  const float* cls_b1  = (const float*)d_in[22];
  const float* cls_w2  = (const float*)d_in[23];
  const float* cls_b2  = (const float*)d_in[24];
  const float* cls_w3  = (const float*)d_in[25];
  const float* cls_b3  = (const float*)d_in[26];

  float* ws = (float*)d_ws;
  // ---- workspace layout (float units) ----
  f16*   w1h   = (f16*)ws;                         // 589,824 f (conv1 B-frag)
  f16*   w2h   = (f16*)(ws + 589824);              // 2,359,296 f (conv2 B-frag; reused: h1h)
  f16*   mw2h  = (f16*)(ws + 2949120);             // 16,384 f
  f16*   saw2h = (f16*)(ws + 2965504);             // 4,096 f
  f16*   saw3h = (f16*)(ws + 2969600);             // 16,384 f
  f16*   saw4h = (f16*)(ws + 2985984);             // 65,536 f
  f16*   cw1h  = (f16*)(ws + 3051520);             // 524,288 f
  f16*   ctwh  = (f16*)(ws + 3575808);             // 1,048,576 f (B-frag layout)
  f16*   cw2h  = (f16*)(ws + 4624384);             // 131,072 f ([256][1024] fp16)
  float* big   = ws + 4886528;                     // 3,276,800 f (g1buf, g2buf)
  f16*   voxh  = (f16*)(ws + 8163328);             // 819,200 f (reused: f2h)
  f16*   f1h   = (f16*)(ws + 8982528);             // 819,200 f
  f16*   scnh  = (f16*)(ws + 9801728);             // 1,638,400 f (reused: h2h)
  float* obj   = ws + 11440128;                    // 16,384 f
  float* ocm   = ws + 11456512;                    // 64 f

  f16*   g1buf = (f16*)big;                        // conv1 out
  f16*   g2buf = (f16*)big;                        // conv2 out (g1buf dead after pool1)
  f16*   f2h   = voxh;                             // pool2 out (voxh dead after conv1)
  f16*   h1h   = w2h;                              // cls1 out (w2h dead after conv2)
  f16*   h2h   = scnh;                             // cls2 out (scnh dead after cls1)
  float* outp  = (float*)d_out;

  // ---- weight preps ----
  wfragprep_k<512, 256><<<512, 256, 0, stream>>>(conv1_w, w1h);
  wfragprep_k<1024, 512><<<1024, 256, 0, stream>>>(conv2_w, w2h);
  cvt16_k<<<32, 256, 0, stream>>>(mlp_w2, mw2h, 8192);
  cvt16_k<<<8, 256, 0, stream>>>(sa_w2, saw2h, 2048);
  cvt16_k<<<32, 256, 0, stream>>>(sa_w3, saw3h, 8192);
  cvt16_k<<<128, 256, 0, stream>>>(sa_w4, saw4h, 32768);
  cw1prep_k<<<4096, 256, 0, stream>>>(cls_w1, cw1h);
  ctprep_k<<<8192, 256, 0, stream>>>(convt_w, ctwh);
  cvt16_k<<<256, 256, 0, stream>>>(cls_w2, cw2h, 65536);

  hipMemsetAsync(obj, 0, (size_t)16384 * 4, stream);
  ocmean_k<<<32, 256, 0, stream>>>(oc, ocm);

  pointnet_lds_k<<<256, 256, 0, stream>>>(sc, mlp_w1, mlp_b1, mw2h, mlp_b2, voxh);

  convmfma_k<20, 20, 256, 512, 4><<<512, 256, 7 * 22 * 80, stream>>>(
      voxh, w1h, conv1_b, g1buf);
  pool1_k<<<3200, 256, 0, stream>>>(g1buf, f1h, scnh);
  convmfma_k<10, 10, 512, 1024, 2><<<512, 256, 7 * 12 * 80, stream>>>(
      f1h, w2h, conv2_b, g2buf);
  pool2_k<<<1600, 256, 0, stream>>>(g2buf, f2h);
  convt_mfma_k<<<512, 256, 0, stream>>>(f2h, ctwh, convt_b, scnh);

  sa_mfma_k<<<2048, 256, 0, stream>>>(oc, ocm, sa_w1, sa_b1, saw2h, sa_b2,
                                      saw3h, sa_b3, saw4h, sa_b4, obj);

  cls1_mfma_k<<<256, 256, 0, stream>>>(scnh, obj, pos, cls_w1, cw1h, cls_b1, h1h);
  cls2_mfma_k<<<128, 256, 0, stream>>>(h1h, cw2h, cls_b2, h2h);
  cls3_k<<<32, 128, 0, stream>>>(h2h, cls_w3, cls_b3, outp);
}

// Round 10
// 516.244 us; speedup vs baseline: 2.0216x; 1.1047x over previous
//
#include <hip/hip_runtime.h>

#define NB 32
#define PP 8192
#define OPP 2048

typedef _Float16 f16;
typedef f16 half8 __attribute__((ext_vector_type(8)));
typedef f16 half4 __attribute__((ext_vector_type(4)));
typedef float f32x4 __attribute__((ext_vector_type(4)));

#define MFMA16(a, b, c) __builtin_amdgcn_mfma_f32_16x16x32_f16(a, b, c, 0, 0, 0)

// ======= conv weight prep: [co][ci][3][3] fp32 -> MFMA B-fragment order fp16 =======
template <int CO, int CI>
__global__ __launch_bounds__(256) void wfragprep_k(const float* __restrict__ wsrc,
                                                   f16* __restrict__ wf) {
  __shared__ float tile[CI * 9];
  int co = blockIdx.x, t = threadIdx.x;
  const float* src = wsrc + (size_t)co * CI * 9;
  for (int i = t; i < CI * 9; i += 256) tile[i] = src[i];
  __syncthreads();
  constexpr int NBB = CO / 16;
  int nb = co >> 4, l16 = co & 15;
  for (int e = t; e < (CI / 32) * 9 * 4; e += 256) {
    int quad = e & 3;
    int kk = (e >> 2) % 9;
    int cic = e / 36;
    half8 v;
#pragma unroll
    for (int j = 0; j < 8; ++j) {
      int ci = cic * 32 + quad * 8 + j;
      v[j] = (f16)tile[ci * 9 + kk];
    }
    *(half8*)(wf + ((((size_t)cic * 9 + kk) * NBB + nb) * 64 + quad * 16 + l16) * 8) = v;
  }
}

__global__ void cvt16_k(const float* __restrict__ in, f16* __restrict__ out, int n4) {
  int idx = blockIdx.x * 256 + threadIdx.x;
  if (idx >= n4) return;
  float4 v = ((const float4*)in)[idx];
  half4 h; h.x = (f16)v.x; h.y = (f16)v.y; h.z = (f16)v.z; h.w = (f16)v.w;
  ((half4*)out)[idx] = h;
}

// cls_w1 scene part [1024][1538] -> [1024][1024] fp16
__global__ void cw1prep_k(const float* __restrict__ w, f16* __restrict__ out) {
  int idx = blockIdx.x * 256 + threadIdx.x;
  if (idx >= 1024 * 1024) return;
  int co = idx >> 10, k = idx & 1023;
  out[idx] = (f16)w[(size_t)co * 1538 + k];
}

// convt_w [o][i][a'][b'] -> MFMA B-fragment layout
__global__ void ctprep_k(const float* __restrict__ w, f16* __restrict__ out) {
  int idx = blockIdx.x * 256 + threadIdx.x;
  if (idx >= 2048 * 1024) return;
  int j = idx & 7, l = (idx >> 3) & 63, kb = (idx >> 9) & 31, nb = idx >> 14;
  int n16 = l & 15, quad = l >> 4;
  int np = nb * 16 + n16;
  int k = kb * 32 + quad * 8 + j;
  int p = np >> 9, o = np & 511;
  out[idx] = (f16)w[((size_t)o * 1024 + k) * 4 + (3 - p)];
}

// ======================= object-cloud mean =======================
__global__ void ocmean_k(const float* __restrict__ oc, float* __restrict__ ocm) {
  int n = blockIdx.x, t = threadIdx.x;
  __shared__ float sx[256], sy[256];
  float ax = 0.f, ay = 0.f;
  for (int p = t; p < OPP; p += 256) {
    ax += oc[((size_t)n * OPP + p) * 2 + 0];
    ay += oc[((size_t)n * OPP + p) * 2 + 1];
  }
  sx[t] = ax; sy[t] = ay;
  __syncthreads();
  for (int s = 128; s > 0; s >>= 1) {
    if (t < s) { sx[t] += sx[t + s]; sy[t] += sy[t + s]; }
    __syncthreads();
  }
  if (t == 0) {
    ocm[n * 2 + 0] = sx[0] / (float)OPP;
    ocm[n * 2 + 1] = sy[0] / (float)OPP;
  }
}

// ======================= voxel PointNet: barrier-free LDS scatter-max =======================
__global__ __launch_bounds__(256) void pointnet_lds_k(
    const float* __restrict__ sc, const float* __restrict__ w1, const float* __restrict__ b1,
    const f16* __restrict__ w2h, const float* __restrict__ b2, f16* __restrict__ voxh) {
  __shared__ float voxl[400 * 33];         // 52,800 B
  __shared__ int binl[64];                 // wave-local bin broadcast
  int t = threadIdx.x, lane = t & 63, w = t >> 6;
  int quad = lane >> 4, l16 = lane & 15;
  int b = blockIdx.x;
  int cg = b & 7, n = b >> 3;
  float w1x[32], w1y[32], b1v[32];
#pragma unroll
  for (int ks = 0; ks < 4; ++ks)
#pragma unroll
    for (int j = 0; j < 8; ++j) {
      int k = ks * 32 + quad * 8 + j;
      w1x[ks * 8 + j] = w1[k * 2];
      w1y[ks * 8 + j] = w1[k * 2 + 1];
      b1v[ks * 8 + j] = b1[k];
    }
  half8 bf[2][4];
  float bias[2];
#pragma unroll
  for (int nt = 0; nt < 2; ++nt) {
    int ch = cg * 32 + nt * 16 + l16;
    bias[nt] = b2[ch];
#pragma unroll
    for (int ks = 0; ks < 4; ++ks)
      bf[nt][ks] = *(const half8*)(w2h + (size_t)ch * 128 + ks * 32 + quad * 8);
  }
  for (int i = t; i < 400 * 33; i += 256) voxl[i] = 0.0f;
  __syncthreads();
  const float* scp = sc + (size_t)n * PP * 2;
  int p0 = w * 16 + l16;
  float2 xy = *(const float2*)(scp + p0 * 2);
  for (int it = 0; it < 128; ++it) {
    float x = xy.x, y = xy.y;
    if (it < 127) xy = *(const float2*)(scp + ((it + 1) * 64 + p0) * 2);
    float bif = fminf(fmaxf(ceilf((x + 0.5f) * 20.0f) - 1.0f, 0.0f), 19.0f);
    float bjf = fminf(fmaxf(ceilf((y + 0.5f) * 20.0f) - 1.0f, 0.0f), 19.0f);
    bool valid = (x > -0.5f) && (x <= 0.5f) && (y > -0.5f) && (y <= 0.5f);
    float px = x - (-0.5f + (bif + 0.5f) * 0.05f);
    float py = y - (-0.5f + (bjf + 0.5f) * 0.05f);
    int bn = valid ? ((int)bif * 20 + (int)bjf) : -1;
    if (quad == 0) binl[w * 16 + l16] = bn;
    f32x4 acc0 = {}, acc1 = {};
#pragma unroll
    for (int ks = 0; ks < 4; ++ks) {
      half8 af;
#pragma unroll
      for (int j = 0; j < 8; ++j)
        af[j] = (f16)fmaxf(fmaf(w1x[ks * 8 + j], px, fmaf(w1y[ks * 8 + j], py, b1v[ks * 8 + j])), 0.0f);
      acc0 = MFMA16(af, bf[0][ks], acc0);
      acc1 = MFMA16(af, bf[1][ks], acc1);
    }
#pragma unroll
    for (int r = 0; r < 4; ++r) {
      int bn2 = binl[w * 16 + quad * 4 + r];
      if (bn2 >= 0) {
        float v0 = fmaxf(acc0[r] + bias[0], 0.0f);
        float v1 = fmaxf(acc1[r] + bias[1], 0.0f);
        atomicMax((int*)voxl + bn2 * 33 + l16, __float_as_int(v0));
        atomicMax((int*)voxl + bn2 * 33 + 16 + l16, __float_as_int(v1));
      }
    }
  }
  __syncthreads();
  for (int i = t; i < 400 * 16; i += 256) {
    int bin = i >> 4, cp = i & 15;
    union { f16 h[2]; unsigned u; } pk;
    pk.h[0] = (f16)voxl[bin * 33 + cp * 2];
    pk.h[1] = (f16)voxl[bin * 33 + cp * 2 + 1];
    *(unsigned*)(voxh + ((size_t)n * 400 + bin) * 256 + cg * 32 + cp * 2) = pk.u;
  }
}

// ======================= MFMA implicit-GEMM conv 3x3 pad1 + relu =======================
template <int H, int W, int CI, int CO, int MSPLIT>
__global__ __launch_bounds__(256, 2) void convmfma_k(
    const f16* __restrict__ inh, const f16* __restrict__ wf,
    const float* __restrict__ bias, f16* __restrict__ outh) {
  constexpr int HS = H / MSPLIT;
  constexpr int Mpix = HS * W;
  constexpr int MT = (Mpix + 15) / 16;
  constexpr int PR = HS + 2, PC = W + 2;
  constexpr int NCIC = CI / 32;
  constexpr int COG = CO / 128;
  constexpr int NBB = CO / 16;
  extern __shared__ char smem[];
  f16* Ap = (f16*)smem;                          // [PR*PC][40]
  int b = blockIdx.x;
  int cog = b % COG;
  int ms = (b / COG) % MSPLIT;
  int n = b / (COG * MSPLIT);
  int co0 = cog * 128;
  int r0 = ms * HS;
  int t = threadIdx.x, lane = t & 63, w = t >> 6;
  int quad = lane >> 4, l16 = lane & 15;
  int nb0 = cog * 8 + w * 2;                     // B-fragment row-block (16 co each)

  int abase[MT];
#pragma unroll
  for (int mi = 0; mi < MT; ++mi) {
    int pl = mi * 16 + l16; if (pl > Mpix - 1) pl = Mpix - 1;
    int y = pl / W, x = pl - y * W;
    abase[mi] = (y * PC + x) * 40 + quad * 8;    // halves
  }
  f32x4 acc[MT][2] = {};

  const f16* inbase = inh + (size_t)n * H * W * CI;

  for (int cic = 0; cic < NCIC; ++cic) {
    __syncthreads();                             // protect Ap from prior reads
    for (int cell = t; cell < PR * PC; cell += 256) {
      int pr = cell / PC, pc = cell - pr * PC;
      int yin = r0 - 1 + pr, xin = pc - 1;
      uint4 d0 = {0,0,0,0}, d1 = {0,0,0,0}, d2 = {0,0,0,0}, d3 = {0,0,0,0};
      if (yin >= 0 && yin < H && xin >= 0 && xin < W) {
        const uint4* src = (const uint4*)(inbase + ((size_t)yin * W + xin) * CI + cic * 32);
        d0 = src[0]; d1 = src[1]; d2 = src[2]; d3 = src[3];
      }
      uint4* dst = (uint4*)(Ap + cell * 40);
      dst[0] = d0; dst[1] = d1; dst[2] = d2; dst[3] = d3;
    }
    __syncthreads();
    const f16* wfc = wf + (size_t)(cic * 9) * NBB * 512;
#pragma unroll
    for (int ky = 0; ky < 3; ++ky)
#pragma unroll
      for (int kx = 0; kx < 3; ++kx) {
        int kk = ky * 3 + kx;
        half8 bf0 = *(const half8*)(wfc + ((size_t)(kk * NBB + nb0) * 64 + lane) * 8);
        half8 bf1 = *(const half8*)(wfc + ((size_t)(kk * NBB + nb0 + 1) * 64 + lane) * 8);
        int shift = (ky * PC + kx) * 40;
#pragma unroll
        for (int mi = 0; mi < MT; ++mi) {
          half8 af = *(const half8*)(Ap + abase[mi] + shift);
          acc[mi][0] = MFMA16(af, bf0, acc[mi][0]);
          acc[mi][1] = MFMA16(af, bf1, acc[mi][1]);
        }
      }
  }
  int co_w = co0 + w * 32;
  float bv0 = bias[co_w + l16];
  float bv1 = bias[co_w + 16 + l16];
  f16* ob = outh + ((size_t)n * H * W + (size_t)ms * Mpix) * CO;
#pragma unroll
  for (int mi = 0; mi < MT; ++mi) {
#pragma unroll
    for (int r = 0; r < 4; ++r) {
      int p = mi * 16 + quad * 4 + r;
      if (p < Mpix) {
        float v0 = acc[mi][0][r] + bv0; v0 = v0 > 0.f ? v0 : 0.f;
        float v1 = acc[mi][1][r] + bv1; v1 = v1 > 0.f ? v1 : 0.f;
        ob[(size_t)p * CO + co_w + l16] = (f16)v0;
        ob[(size_t)p * CO + co_w + 16 + l16] = (f16)v1;
      }
    }
  }
}

// ======================= maxpool 2x2 (+ fused pack into scene buffer) =======================
__global__ void pool1_k(const f16* __restrict__ g1, f16* __restrict__ f1h,
                        f16* __restrict__ scnh) {
  int idx = blockIdx.x * 256 + threadIdx.x;
  if (idx >= 32 * 100 * 256) return;
  int c2 = idx & 255, rem = idx >> 8;
  int op = rem % 100, n = rem / 100;
  int py = op / 10, px = op - py * 10;
  const f16* base = g1 + (((size_t)n * 400 + (size_t)(2 * py) * 20 + 2 * px) * 512) + c2 * 2;
  float a0 = (float)base[0],   a1 = (float)base[1];
  float b0 = (float)base[512], b1 = (float)base[513];
  const f16* base2 = base + 20 * 512;
  float c0 = (float)base2[0],   c1 = (float)base2[1];
  float d0 = (float)base2[512], d1 = (float)base2[513];
  union { f16 h[2]; unsigned u; } pk;
  pk.h[0] = (f16)fmaxf(fmaxf(a0, b0), fmaxf(c0, d0));
  pk.h[1] = (f16)fmaxf(fmaxf(a1, b1), fmaxf(c1, d1));
  *(unsigned*)(f1h + ((size_t)n * 100 + op) * 512 + c2 * 2) = pk.u;
  *(unsigned*)(scnh + ((size_t)n * 100 + op) * 1024 + c2 * 2) = pk.u;
}

__global__ void pool2_k(const f16* __restrict__ g2, f16* __restrict__ f2h) {
  int idx = blockIdx.x * 256 + threadIdx.x;
  if (idx >= 32 * 25 * 512) return;
  int c2 = idx & 511, rem = idx >> 9;
  int op = rem % 25, n = rem / 25;
  int py = op / 5, px = op - py * 5;
  const f16* base = g2 + (((size_t)n * 100 + (size_t)(2 * py) * 10 + 2 * px) * 1024) + c2 * 2;
  float a0 = (float)base[0],    a1 = (float)base[1];
  float b0 = (float)base[1024], b1 = (float)base[1025];
  const f16* base2 = base + 10 * 1024;
  float c0 = (float)base2[0],    c1 = (float)base2[1];
  float d0 = (float)base2[1024], d1 = (float)base2[1025];
  f16* o = f2h + ((size_t)n * 25 + op) * 1024 + c2 * 2;
  o[0] = (f16)fmaxf(fmaxf(a0, b0), fmaxf(c0, d0));
  o[1] = (f16)fmaxf(fmaxf(a1, b1), fmaxf(c1, d1));
}

// ======================= conv transpose 2x2 s2 (1024->512), MFMA v2 =======================
__global__ __launch_bounds__(256, 2) void convt_mfma_k(
    const f16* __restrict__ f2h, const f16* __restrict__ ctwf,
    const float* __restrict__ ctb, f16* __restrict__ scnh) {
  __shared__ f16 act[25 * 1048];           // 52,400 B
  int b = blockIdx.x;
  int ng = b & 15, n = b >> 4;
  int t = threadIdx.x, lane = t & 63, w = t >> 6;
  int quad = lane >> 4, l16 = lane & 15;
  for (int i = t; i < 25 * 128; i += 256) {
    int row = i >> 7, c8 = i & 127;
    *(half8*)(act + row * 1048 + c8 * 8) =
        *(const half8*)(f2h + ((size_t)n * 25 + row) * 1024 + c8 * 8);
  }
  __syncthreads();
  int r1 = 16 + (l16 > 8 ? 8 : l16);       // clamp: garbage rows never stored
  f32x4 acc[2][2] = {};
  const f16* wp0 = ctwf + ((size_t)((ng * 8 + w * 2 + 0) * 32) * 64 + lane) * 8;
  const f16* wp1 = ctwf + ((size_t)((ng * 8 + w * 2 + 1) * 32) * 64 + lane) * 8;
#pragma unroll 4
  for (int ks = 0; ks < 32; ++ks) {
    half8 a0 = *(const half8*)(act + l16 * 1048 + ks * 32 + quad * 8);
    half8 a1 = *(const half8*)(act + r1 * 1048 + ks * 32 + quad * 8);
    half8 b0 = *(const half8*)(wp0 + (size_t)ks * 512);
    half8 b1 = *(const half8*)(wp1 + (size_t)ks * 512);
    acc[0][0] = MFMA16(a0, b0, acc[0][0]);
    acc[1][0] = MFMA16(a1, b0, acc[1][0]);
    acc[0][1] = MFMA16(a0, b1, acc[0][1]);
    acc[1][1] = MFMA16(a1, b1, acc[1][1]);
  }
#pragma unroll
  for (int nt = 0; nt < 2; ++nt) {
    int np = ng * 128 + w * 32 + nt * 16 + l16;
    int p = np >> 9, co = np & 511;
    int a = p >> 1, bc = p & 1;
    float bb = ctb[co];
#pragma unroll
    for (int mt = 0; mt < 2; ++mt)
#pragma unroll
      for (int r = 0; r < 4; ++r) {
        int px = mt * 16 + quad * 4 + r;
        if (px < 25) {
          int ph = px / 5, pw = px - ph * 5;
          int opx = (2 * ph + a) * 10 + 2 * pw + bc;
          scnh[((size_t)n * 100 + opx) * 1024 + 512 + co] = (f16)(acc[mt][nt][r] + bb);
        }
      }
  }
}

// ======================= object SA: fused 4-layer MFMA + max (M=64 tiles) =======================
__global__ __launch_bounds__(256, 2) void sa_mfma_k(
    const float* __restrict__ oc, const float* __restrict__ ocm,
    const float* __restrict__ w1, const float* __restrict__ b1,
    const f16* __restrict__ w2h, const float* __restrict__ b2,
    const f16* __restrict__ w3h, const float* __restrict__ b3,
    const f16* __restrict__ w4h, const float* __restrict__ b4,
    float* __restrict__ obj) {
  __shared__ f16 act1[64 * 72];            // 9,216 B [pt][K=64]
  __shared__ f16 act2[64 * 136];           // 17,408 B [pt][K=128]
  __shared__ f16 act3[64 * 264];           // 33,792 B [pt][K=256]
  __shared__ float pcx[64], pcy[64];
  int b = blockIdx.x;                      // 1024 = 32 n * 32 chunks of 64 pts
  int n = b >> 5, pb = (b & 31) * 64;
  int t = threadIdx.x, lane = t & 63, w = t >> 6;
  int quad = lane >> 4, l16 = lane & 15;
  if (t < 64) {
    pcx[t] = oc[((size_t)n * OPP + pb + t) * 2 + 0] - ocm[n * 2 + 0];
    pcy[t] = oc[((size_t)n * OPP + pb + t) * 2 + 1] - ocm[n * 2 + 1];
  }
  __syncthreads();
  {                                        // layer1: 2 -> 64 for 64 points
    int c = t & 63, pg = t >> 6;
    float wx = w1[c * 2], wy = w1[c * 2 + 1], bb = b1[c];
#pragma unroll
    for (int j = 0; j < 16; ++j) {
      int p = pg * 16 + j;
      act1[p * 72 + c] = (f16)fmaxf(fmaf(wx, pcx[p], fmaf(wy, pcy[p], bb)), 0.0f);
    }
  }
  __syncthreads();
  {                                        // layer2: M=64, K=64, N=128; wave n-range 32
    int n0 = w * 32;
    f32x4 acc[4][2] = {};
#pragma unroll
    for (int ks = 0; ks < 2; ++ks) {
      half8 a[4];
#pragma unroll
      for (int mt = 0; mt < 4; ++mt)
        a[mt] = *(const half8*)(act1 + (mt * 16 + l16) * 72 + ks * 32 + quad * 8);
#pragma unroll
      for (int nt = 0; nt < 2; ++nt) {
        half8 bf = *(const half8*)(w2h + (size_t)(n0 + nt * 16 + l16) * 64 + ks * 32 + quad * 8);
#pragma unroll
        for (int mt = 0; mt < 4; ++mt)
          acc[mt][nt] = MFMA16(a[mt], bf, acc[mt][nt]);
      }
    }
#pragma unroll
    for (int nt = 0; nt < 2; ++nt) {
      int col = n0 + nt * 16 + l16;
      float bb = b2[col];
#pragma unroll
      for (int mt = 0; mt < 4; ++mt)
#pragma unroll
        for (int r = 0; r < 4; ++r)
          act2[(mt * 16 + quad * 4 + r) * 136 + col] = (f16)fmaxf(acc[mt][nt][r] + bb, 0.0f);
    }
  }
  __syncthreads();
  {                                        // layer3: M=64, K=128, N=256; wave n-range 64
    int n0 = w * 64;
    f32x4 acc[4][4] = {};
#pragma unroll
    for (int ks = 0; ks < 4; ++ks) {
      half8 a[4];
#pragma unroll
      for (int mt = 0; mt < 4; ++mt)
        a[mt] = *(const half8*)(act2 + (mt * 16 + l16) * 136 + ks * 32 + quad * 8);
#pragma unroll
      for (int nt = 0; nt < 4; ++nt) {
        half8 bf = *(const half8*)(w3h + (size_t)(n0 + nt * 16 + l16) * 128 + ks * 32 + quad * 8);
#pragma unroll
        for (int mt = 0; mt < 4; ++mt)
          acc[mt][nt] = MFMA16(a[mt], bf, acc[mt][nt]);
      }
    }
#pragma unroll
    for (int nt = 0; nt < 4; ++nt) {
      int col = n0 + nt * 16 + l16;
      float bb = b3[col];
#pragma unroll
      for (int mt = 0; mt < 4; ++mt)
#pragma unroll
        for (int r = 0; r < 4; ++r)
          act3[(mt * 16 + quad * 4 + r) * 264 + col] = (f16)fmaxf(acc[mt][nt][r] + bb, 0.0f);
    }
  }
  __syncthreads();
  {                                        // layer4: M=64, K=256, N=512; wave n-range 128; + max
    int n0 = w * 128;
    f32x4 acc[4][8] = {};
#pragma unroll
    for (int ks = 0; ks < 8; ++ks) {
      half8 a[4];
#pragma unroll
      for (int mt = 0; mt < 4; ++mt)
        a[mt] = *(const half8*)(act3 + (mt * 16 + l16) * 264 + ks * 32 + quad * 8);
#pragma unroll
      for (int nt = 0; nt < 8; ++nt) {
        half8 bf = *(const half8*)(w4h + (size_t)(n0 + nt * 16 + l16) * 256 + ks * 32 + quad * 8);
#pragma unroll
        for (int mt = 0; mt < 4; ++mt)
          acc[mt][nt] = MFMA16(a[mt], bf, acc[mt][nt]);
      }
    }
#pragma unroll
    for (int nt = 0; nt < 8; ++nt) {
      int col = n0 + nt * 16 + l16;
      float bb = b4[col];
      float v = 0.0f;
#pragma unroll
      for (int mt = 0; mt < 4; ++mt)
#pragma unroll
        for (int r = 0; r < 4; ++r)
          v = fmaxf(v, acc[mt][nt][r] + bb);
      v = fmaxf(v, 0.0f);
      v = fmaxf(v, __shfl_xor(v, 16));
      v = fmaxf(v, __shfl_xor(v, 32));
      if (quad == 0)
        atomicMax((int*)obj + (size_t)n * 512 + col, __float_as_int(v));
    }
  }
}

// ======================= classifier layer 1 (1538 -> 1024), MFMA =======================
__global__ __launch_bounds__(256) void cls1_mfma_k(
    const f16* __restrict__ scnh, const float* __restrict__ obj,
    const float* __restrict__ pos, const float* __restrict__ w1raw,
    const f16* __restrict__ w1h, const float* __restrict__ b1,
    f16* __restrict__ h1h) {
  __shared__ f16 act[112 * 72];
  __shared__ float objl[512];
  __shared__ float odl[128], wAl[128], wBl[128];
  int b = blockIdx.x;                      // 256 = 32 n * 8 octants
  int o8 = b & 7, n = b >> 3;
  int co0 = o8 * 128;
  int t = threadIdx.x, lane = t & 63, w = t >> 6;
  int quad = lane >> 4, l16 = lane & 15;
  objl[t] = obj[(size_t)n * 512 + t];
  objl[t + 256] = obj[(size_t)n * 512 + t + 256];
  __syncthreads();
  if (t < 128) {
    int co = co0 + t;
    const float* wr = w1raw + (size_t)co * 1538;
    float od = 0.0f;
    for (int k = 0; k < 512; ++k) od = fmaf(objl[k], wr[1024 + k], od);
    odl[t] = od + b1[co];
    wAl[t] = wr[1536]; wBl[t] = wr[1537];
  }
  __syncthreads();
  float posx = pos[n * 2 + 0], posy = pos[n * 2 + 1];
  f32x4 acc[7][2];
#pragma unroll
  for (int mt = 0; mt < 7; ++mt)
#pragma unroll
    for (int nt = 0; nt < 2; ++nt) {
      int cl = w * 32 + nt * 16 + l16;
      float od = odl[cl], wA = wAl[cl], wB = wBl[cl];
#pragma unroll
      for (int r = 0; r < 4; ++r) {
        int px = mt * 16 + quad * 4 + r;
        float relx = posx - (-0.5f + ((px / 10) + 0.5f) * 0.1f);
        float rely = posy - (-0.5f + ((px % 10) + 0.5f) * 0.1f);
        acc[mt][nt][r] = od + relx * wA + rely * wB;
      }
    }
  for (int kc = 0; kc < 16; ++kc) {
    int k0 = kc * 64;
    __syncthreads();
    for (int i = t; i < 896; i += 256) {
      int row = i >> 3, c8 = i & 7;
      half8 v = {};
      if (row < 100) v = *(const half8*)(scnh + ((size_t)n * 100 + row) * 1024 + k0 + c8 * 8);
      *(half8*)(act + row * 72 + c8 * 8) = v;
    }
    __syncthreads();
#pragma unroll
    for (int ks = 0; ks < 2; ++ks) {
      half8 bf0 = *(const half8*)(w1h + (size_t)(co0 + w * 32 + l16) * 1024 + k0 + ks * 32 + quad * 8);
      half8 bf1 = *(const half8*)(w1h + (size_t)(co0 + w * 32 + 16 + l16) * 1024 + k0 + ks * 32 + quad * 8);
#pragma unroll
      for (int mt = 0; mt < 7; ++mt) {
        half8 a = *(const half8*)(act + (mt * 16 + l16) * 72 + ks * 32 + quad * 8);
        acc[mt][0] = MFMA16(a, bf0, acc[mt][0]);
        acc[mt][1] = MFMA16(a, bf1, acc[mt][1]);
      }
    }
  }
#pragma unroll
  for (int mt = 0; mt < 7; ++mt)
#pragma unroll
    for (int nt = 0; nt < 2; ++nt) {
      int co = co0 + w * 32 + nt * 16 + l16;
#pragma unroll
      for (int r = 0; r < 4; ++r) {
        int px = mt * 16 + quad * 4 + r;
        if (px < 100)
          h1h[((size_t)n * 100 + px) * 1024 + co] = (f16)fmaxf(acc[mt][nt][r], 0.0f);
      }
    }
}

// ======================= classifier layer 2 (1024 -> 256), MFMA =======================
__global__ __launch_bounds__(256) void cls2_mfma_k(
    const f16* __restrict__ h1h, const f16* __restrict__ w2h16,
    const float* __restrict__ b2, f16* __restrict__ h2h) {
  __shared__ f16 act[64 * 72];
  int b = blockIdx.x;
  int ng = b & 1, mh = (b >> 1) & 1, n = b >> 2;
  int co0 = ng * 128, p0 = mh * 50;
  int t = threadIdx.x, lane = t & 63, w = t >> 6;
  int quad = lane >> 4, l16 = lane & 15;
  f32x4 acc[4][2] = {};
  for (int kc = 0; kc < 16; ++kc) {
    int k0 = kc * 64;
    __syncthreads();
    for (int i = t; i < 512; i += 256) {
      int row = i >> 3, c8 = i & 7;                // rows 0..63
      int gr = p0 + (row < 50 ? row : 49);         // clamp; garbage rows never stored
      *(half8*)(act + row * 72 + c8 * 8) =
          *(const half8*)(h1h + ((size_t)n * 100 + gr) * 1024 + k0 + c8 * 8);
    }
    __syncthreads();
#pragma unroll
    for (int ks = 0; ks < 2; ++ks) {
      half8 bf0 = *(const half8*)(w2h16 + (size_t)(co0 + w * 32 + l16) * 1024 + k0 + ks * 32 + quad * 8);
      half8 bf1 = *(const half8*)(w2h16 + (size_t)(co0 + w * 32 + 16 + l16) * 1024 + k0 + ks * 32 + quad * 8);
#pragma unroll
      for (int mt = 0; mt < 4; ++mt) {
        half8 a = *(const half8*)(act + (mt * 16 + l16) * 72 + ks * 32 + quad * 8);
        acc[mt][0] = MFMA16(a, bf0, acc[mt][0]);
        acc[mt][1] = MFMA16(a, bf1, acc[mt][1]);
      }
    }
  }
#pragma unroll
  for (int mt = 0; mt < 4; ++mt)
#pragma unroll
    for (int nt = 0; nt < 2; ++nt) {
      int co = co0 + w * 32 + nt * 16 + l16;
      float bb = b2[co];
#pragma unroll
      for (int r = 0; r < 4; ++r) {
        int pl = mt * 16 + quad * 4 + r;
        if (pl < 50)
          h2h[((size_t)n * 100 + p0 + pl) * 256 + co] = (f16)fmaxf(acc[mt][nt][r] + bb, 0.0f);
      }
    }
}

// ======================= classifier layer 3 (256 -> 1) =======================
__global__ void cls3_k(const f16* __restrict__ h2h, const float* __restrict__ w3,
                       const float* __restrict__ b3, float* __restrict__ out) {
  int n = blockIdx.x, t = threadIdx.x;
  if (t < 100) {
    float acc = b3[0];
    const f16* hp = &h2h[((size_t)n * 100 + t) * 256];
    for (int k = 0; k < 256; ++k) acc = fmaf((float)hp[k], w3[k], acc);
    out[n * 100 + t] = acc;
  }
}

// ======================= launch =======================
extern "C" void kernel_launch(void* const* d_in, const int* in_sizes, int n_in,
                              void* d_out, int out_size, void* d_ws, size_t ws_size,
                              hipStream_t stream) {
  const float* sc      = (const float*)d_in[0];
  const float* oc      = (const float*)d_in[1];
  const float* pos     = (const float*)d_in[2];
  const float* mlp_w1  = (const float*)d_in[3];
  const float* mlp_b1  = (const float*)d_in[4];
  const float* mlp_w2  = (const float*)d_in[5];
  const float* mlp_b2  = (const float*)d_in[6];
  const float* conv1_w = (const float*)d_in[7];
  const float* conv1_b = (const float*)d_in[8];
  const float* conv2_w = (const float*)d_in[9];
  const float* conv2_b = (const float*)d_in[10];
  const float* convt_w = (const float*)d_in[11];
  const float* convt_b = (const float*)d_in[12];
  const float* sa_w1   = (const float*)d_in[13];
  const float* sa_b1   = (const float*)d_in[14];
  const float* sa_w2   = (const float*)d_in[15];
  const float* sa_b2   = (const float*)d_in[16];
  const float* sa_w3   = (const float*)d_in[17];
  const float* sa_b3   = (const float*)d_in[18];
  const float* sa_w4   = (const float*)d_in[19];
  const float* sa_b4   = (const float*)d_in[20];
  const float* cls_w1  = (const float*)d_in[21];
  const float* cls_b1  = (const float*)d_in[22];
  const float* cls_w2  = (const float*)d_in[23];
  const float* cls_b2  = (const float*)d_in[24];
  const float* cls_w3  = (const float*)d_in[25];
  const float* cls_b3  = (const float*)d_in[26];

  float* ws = (float*)d_ws;
  // ---- workspace layout (float units) ----
  f16*   w1h   = (f16*)ws;                         // 589,824 f (conv1 B-frag)
  f16*   w2h   = (f16*)(ws + 589824);              // 2,359,296 f (conv2 B-frag; reused: h1h)
  f16*   mw2h  = (f16*)(ws + 2949120);             // 16,384 f
  f16*   saw2h = (f16*)(ws + 2965504);             // 4,096 f
  f16*   saw3h = (f16*)(ws + 2969600);             // 16,384 f
  f16*   saw4h = (f16*)(ws + 2985984);             // 65,536 f
  f16*   cw1h  = (f16*)(ws + 3051520);             // 524,288 f
  f16*   ctwh  = (f16*)(ws + 3575808);             // 1,048,576 f (B-frag layout)
  f16*   cw2h  = (f16*)(ws + 4624384);             // 131,072 f ([256][1024] fp16)
  float* big   = ws + 4886528;                     // 3,276,800 f (g1buf, g2buf)
  f16*   voxh  = (f16*)(ws + 8163328);             // 819,200 f (reused: f2h)
  f16*   f1h   = (f16*)(ws + 8982528);             // 819,200 f
  f16*   scnh  = (f16*)(ws + 9801728);             // 1,638,400 f (reused: h2h)
  float* obj   = ws + 11440128;                    // 16,384 f
  float* ocm   = ws + 11456512;                    // 64 f

  f16*   g1buf = (f16*)big;                        // conv1 out
  f16*   g2buf = (f16*)big;                        // conv2 out (g1buf dead after pool1)
  f16*   f2h   = voxh;                             // pool2 out (voxh dead after conv1)
  f16*   h1h   = w2h;                              // cls1 out (w2h dead after conv2)
  f16*   h2h   = scnh;                             // cls2 out (scnh dead after cls1)
  float* outp  = (float*)d_out;

  // ---- weight preps ----
  wfragprep_k<512, 256><<<512, 256, 0, stream>>>(conv1_w, w1h);
  wfragprep_k<1024, 512><<<1024, 256, 0, stream>>>(conv2_w, w2h);
  cvt16_k<<<32, 256, 0, stream>>>(mlp_w2, mw2h, 8192);
  cvt16_k<<<8, 256, 0, stream>>>(sa_w2, saw2h, 2048);
  cvt16_k<<<32, 256, 0, stream>>>(sa_w3, saw3h, 8192);
  cvt16_k<<<128, 256, 0, stream>>>(sa_w4, saw4h, 32768);
  cw1prep_k<<<4096, 256, 0, stream>>>(cls_w1, cw1h);
  ctprep_k<<<8192, 256, 0, stream>>>(convt_w, ctwh);
  cvt16_k<<<256, 256, 0, stream>>>(cls_w2, cw2h, 65536);

  hipMemsetAsync(obj, 0, (size_t)16384 * 4, stream);
  ocmean_k<<<32, 256, 0, stream>>>(oc, ocm);

  pointnet_lds_k<<<256, 256, 0, stream>>>(sc, mlp_w1, mlp_b1, mw2h, mlp_b2, voxh);

  convmfma_k<20, 20, 256, 512, 4><<<512, 256, 7 * 22 * 80, stream>>>(
      voxh, w1h, conv1_b, g1buf);
  pool1_k<<<3200, 256, 0, stream>>>(g1buf, f1h, scnh);
  convmfma_k<10, 10, 512, 1024, 2><<<512, 256, 7 * 12 * 80, stream>>>(
      f1h, w2h, conv2_b, g2buf);
  pool2_k<<<1600, 256, 0, stream>>>(g2buf, f2h);
  convt_mfma_k<<<512, 256, 0, stream>>>(f2h, ctwh, convt_b, scnh);

  sa_mfma_k<<<1024, 256, 0, stream>>>(oc, ocm, sa_w1, sa_b1, saw2h, sa_b2,
                                      saw3h, sa_b3, saw4h, sa_b4, obj);

  cls1_mfma_k<<<256, 256, 0, stream>>>(scnh, obj, pos, cls_w1, cw1h, cls_b1, h1h);
  cls2_mfma_k<<<128, 256, 0, stream>>>(h1h, cw2h, cls_b2, h2h);
  cls3_k<<<32, 128, 0, stream>>>(h2h, cls_w3, cls_b3, outp);
}